// Round 1
// baseline (3446.105 us; speedup 1.0000x reference)
//
#include <hip/hip_runtime.h>

#define EMB 300
#define HID 600
#define NL 5
#define BN_EPS 1e-5f

// ---------------- h0 = node_emb0[an] + node_emb1[ch] ----------------
__global__ void k_init_h0(const int* __restrict__ an, const int* __restrict__ ch,
                          const float* __restrict__ ne0, const float* __restrict__ ne1,
                          float* __restrict__ h0, int total) {
    int t = blockIdx.x * blockDim.x + threadIdx.x;
    if (t >= total) return;
    int i = t / EMB, f = t - i * EMB;
    h0[t] = ne0[an[i] * EMB + f] + ne1[ch[i] * EMB + f];
}

// ---------------- CSR build (by dst) ----------------
__global__ void k_hist(const int* __restrict__ dst, int* __restrict__ deg, int e) {
    int t = blockIdx.x * blockDim.x + threadIdx.x;
    if (t < e) atomicAdd(&deg[dst[t]], 1);
}

__global__ void k_scan(const int* __restrict__ deg, int* __restrict__ row_off, int n) {
    // single-block exclusive scan into row_off[0..n]
    __shared__ int sm[1024];
    __shared__ int carry_s;
    int tid = threadIdx.x;
    if (tid == 0) { carry_s = 0; row_off[0] = 0; }
    __syncthreads();
    for (int base = 0; base < n; base += 1024) {
        int i = base + tid;
        int v = (i < n) ? deg[i] : 0;
        sm[tid] = v;
        __syncthreads();
        for (int off = 1; off < 1024; off <<= 1) {
            int t = (tid >= off) ? sm[tid - off] : 0;
            __syncthreads();
            sm[tid] += t;
            __syncthreads();
        }
        int incl = sm[tid];
        int carry = carry_s;
        if (i < n) row_off[i + 1] = carry + incl;
        __syncthreads();
        if (tid == 1023) carry_s = carry + incl;
        __syncthreads();
    }
}

__global__ void k_copy_int(const int* __restrict__ a, int* __restrict__ b, int n) {
    int t = blockIdx.x * blockDim.x + threadIdx.x;
    if (t < n) b[t] = a[t];
}

__global__ void k_scatter(const int* __restrict__ dst, int* __restrict__ cursor,
                          int* __restrict__ edge_ids, int e) {
    int t = blockIdx.x * blockDim.x + threadIdx.x;
    if (t < e) { int p = atomicAdd(&cursor[dst[t]], 1); edge_ids[p] = t; }
}

// ---------------- aggregation: agg[v] = sum_{e in in(v)} feats[src_e] + ee0[bt_e] + ee1[bd_e] ----------------
__global__ void k_aggregate(const float* __restrict__ feats,
                            const float* __restrict__ e0, const float* __restrict__ e1,
                            const int* __restrict__ row_off, const int* __restrict__ edge_ids,
                            const int* __restrict__ src, const int* __restrict__ bt,
                            const int* __restrict__ bd, float* __restrict__ agg) {
    int v = blockIdx.x;
    int f = threadIdx.x;
    if (f >= EMB) return;
    int s = row_off[v], e = row_off[v + 1];
    float acc = 0.f;
    for (int j = s; j < e; ++j) {
        int eid = edge_ids[j];
        acc += feats[(size_t)src[eid] * EMB + f]
             + e0[bt[eid] * EMB + f] + e1[bd[eid] * EMB + f];
    }
    agg[(size_t)v * EMB + f] = acc;
}

// ---------------- GEMM: C = epilogue(A[MxK] * B[KxN] + bias) ----------------
// EPI 0: relu(x+bias)    (GEMM1)
// EPI 1: BN(x+bias) then relu  (GEMM2, l < NL-1)
// EPI 2: BN(x+bias)            (GEMM2, last layer)
#define GBM 64
#define GBN 64
#define GBK 16
#define GLD 68  // padded LDS stride (floats); 68*4 bytes keeps 16B alignment

template <int EPI>
__global__ __launch_bounds__(256)
void k_gemm(const float* __restrict__ A, const float* __restrict__ B,
            const float* __restrict__ bias, float* __restrict__ C,
            int M, int N, int K,
            const float* __restrict__ gamma, const float* __restrict__ beta,
            const float* __restrict__ mean, const float* __restrict__ var) {
    __shared__ __align__(16) float As[GBK][GLD];  // [k][m]
    __shared__ __align__(16) float Bs[GBK][GLD];  // [k][n]
    const int tid = threadIdx.x;
    const int bm = blockIdx.x * GBM;
    const int bn = blockIdx.y * GBN;
    const int tx = tid & 15, ty = tid >> 4;       // 16x16 thread grid, 4x4 per thread
    const int ar = tid >> 2, aq = tid & 3;        // A staging: row, quad-of-4-k
    const int bk = tid >> 4, bq = tid & 15;       // B staging: k, quad-of-4-n
    float acc[4][4] = {};
    for (int k0 = 0; k0 < K; k0 += GBK) {
        // K and N are multiples of 4 here, so each float4 is all-valid or all-invalid.
        float4 av = make_float4(0.f, 0.f, 0.f, 0.f);
        const int arow = bm + ar;
        const int ak = k0 + aq * 4;
        if (arow < M && ak < K)
            av = *(const float4*)(A + (size_t)arow * K + ak);
        float4 bv = make_float4(0.f, 0.f, 0.f, 0.f);
        const int brow = k0 + bk;
        const int bcol = bn + bq * 4;
        if (brow < K && bcol < N)
            bv = *(const float4*)(B + (size_t)brow * N + bcol);
        __syncthreads();
        As[aq * 4 + 0][ar] = av.x;
        As[aq * 4 + 1][ar] = av.y;
        As[aq * 4 + 2][ar] = av.z;
        As[aq * 4 + 3][ar] = av.w;
        *(float4*)&Bs[bk][bq * 4] = bv;
        __syncthreads();
#pragma unroll
        for (int k = 0; k < GBK; ++k) {
            float4 a4 = *(const float4*)&As[k][ty * 4];
            float4 b4 = *(const float4*)&Bs[k][tx * 4];
            float aa[4] = {a4.x, a4.y, a4.z, a4.w};
            float bb[4] = {b4.x, b4.y, b4.z, b4.w};
#pragma unroll
            for (int i = 0; i < 4; ++i)
#pragma unroll
                for (int j = 0; j < 4; ++j)
                    acc[i][j] = fmaf(aa[i], bb[j], acc[i][j]);
        }
    }
    const int c0 = bn + tx * 4;
    if (c0 >= N) return;
    float sc[4], sh[4];
#pragma unroll
    for (int j = 0; j < 4; ++j) {
        if (EPI == 0) {
            sc[j] = 1.f;
            sh[j] = bias[c0 + j];
        } else {
            float s = gamma[c0 + j] * rsqrtf(var[c0 + j] + BN_EPS);
            sc[j] = s;
            sh[j] = beta[c0 + j] + (bias[c0 + j] - mean[c0 + j]) * s;
        }
    }
#pragma unroll
    for (int i = 0; i < 4; ++i) {
        int r = bm + ty * 4 + i;
        if (r >= M) continue;
        float x0 = acc[i][0] * sc[0] + sh[0];
        float x1 = acc[i][1] * sc[1] + sh[1];
        float x2 = acc[i][2] * sc[2] + sh[2];
        float x3 = acc[i][3] * sc[3] + sh[3];
        if (EPI != 2) {
            x0 = fmaxf(x0, 0.f); x1 = fmaxf(x1, 0.f);
            x2 = fmaxf(x2, 0.f); x3 = fmaxf(x3, 0.f);
        }
        *(float4*)(C + (size_t)r * N + c0) = make_float4(x0, x1, x2, x3);
    }
}

// ---------------- per-graph pooling of one layer's feats ----------------
__global__ void k_pool(const float* __restrict__ feats, const int* __restrict__ gids,
                       float* __restrict__ out, int n_nodes, int l) {
    int g = blockIdx.x;
    // [s,e) = contiguous node range of graph g (gids sorted)
    int lo = 0, hi = n_nodes;
    while (lo < hi) { int mid = (lo + hi) >> 1; if (gids[mid] < g) lo = mid + 1; else hi = mid; }
    int s = lo;
    hi = n_nodes;
    while (lo < hi) { int mid = (lo + hi) >> 1; if (gids[mid] < g + 1) lo = mid + 1; else hi = mid; }
    int e = lo;
    float inv = 1.0f / (float)((e - s) > 0 ? (e - s) : 1);
    for (int f = threadIdx.x; f < EMB; f += blockDim.x) {
        float sum = 0.f;
        for (int v = s; v < e; ++v) sum += feats[(size_t)v * EMB + f];
        out[(size_t)g * (12 * EMB) + l * EMB + f] = sum * inv;            // avg block
        out[(size_t)g * (12 * EMB) + 6 * EMB + l * EMB + f] = sum;        // sum block
    }
}

extern "C" void kernel_launch(void* const* d_in, const int* in_sizes, int n_in,
                              void* d_out, int out_size, void* d_ws, size_t ws_size,
                              hipStream_t stream) {
    const int*   an  = (const int*)d_in[0];
    const int*   ch  = (const int*)d_in[1];
    const int*   bt  = (const int*)d_in[2];
    const int*   bd  = (const int*)d_in[3];
    const int*   src = (const int*)d_in[4];
    const int*   dst = (const int*)d_in[5];
    const int*   gid = (const int*)d_in[6];
    const float* ne0 = (const float*)d_in[8];
    const float* ne1 = (const float*)d_in[9];
    const float* ee0 = (const float*)d_in[10];
    const float* ee1 = (const float*)d_in[11];
    const float* W1  = (const float*)d_in[12];
    const float* b1  = (const float*)d_in[13];
    const float* W2  = (const float*)d_in[14];
    const float* b2  = (const float*)d_in[15];
    const float* bng = (const float*)d_in[16];
    const float* bnb = (const float*)d_in[17];
    const float* bnm = (const float*)d_in[18];
    const float* bnv = (const float*)d_in[19];

    const int N = in_sizes[0];
    const int E = in_sizes[2];
    const int G = out_size / (12 * EMB);

    char* ws = (char*)d_ws;
    size_t off = 0;
    auto alloc = [&](size_t bytes) -> void* {
        void* p = (void*)(ws + off);
        off += (bytes + 255) & ~(size_t)255;
        return p;
    };
    float* F0       = (float*)alloc((size_t)N * EMB * 4);
    float* F1       = (float*)alloc((size_t)N * EMB * 4);
    float* Hbuf     = (float*)alloc((size_t)N * HID * 4);
    int*   deg      = (int*)alloc((size_t)N * 4);
    int*   row_off  = (int*)alloc(((size_t)N + 1) * 4);
    int*   cursor   = (int*)alloc((size_t)N * 4);
    int*   edge_ids = (int*)alloc((size_t)E * 4);

    // h0
    const int total0 = N * EMB;
    k_init_h0<<<(total0 + 255) / 256, 256, 0, stream>>>(an, ch, ne0, ne1, F0, total0);

    // CSR by dst
    hipMemsetAsync(deg, 0, (size_t)N * 4, stream);
    k_hist<<<(E + 255) / 256, 256, 0, stream>>>(dst, deg, E);
    k_scan<<<1, 1024, 0, stream>>>(deg, row_off, N);
    k_copy_int<<<(N + 255) / 256, 256, 0, stream>>>(row_off, cursor, N);
    k_scatter<<<(E + 255) / 256, 256, 0, stream>>>(dst, cursor, edge_ids, E);

    float* cur = F0;
    float* oth = F1;
    for (int l = 0; l < NL; ++l) {
        k_pool<<<G, 256, 0, stream>>>(cur, gid, (float*)d_out, N, l);
        k_aggregate<<<N, 320, 0, stream>>>(cur,
                                           ee0 + (size_t)l * 6 * EMB,
                                           ee1 + (size_t)l * 3 * EMB,
                                           row_off, edge_ids, src, bt, bd, oth);
        dim3 g1((N + GBM - 1) / GBM, (HID + GBN - 1) / GBN);
        k_gemm<0><<<g1, 256, 0, stream>>>(oth, W1 + (size_t)l * EMB * HID, b1 + (size_t)l * HID,
                                          Hbuf, N, HID, EMB, nullptr, nullptr, nullptr, nullptr);
        dim3 g2((N + GBM - 1) / GBM, (EMB + GBN - 1) / GBN);
        if (l < NL - 1)
            k_gemm<1><<<g2, 256, 0, stream>>>(Hbuf, W2 + (size_t)l * HID * EMB, b2 + (size_t)l * EMB,
                                              oth, N, EMB, HID,
                                              bng + (size_t)l * EMB, bnb + (size_t)l * EMB,
                                              bnm + (size_t)l * EMB, bnv + (size_t)l * EMB);
        else
            k_gemm<2><<<g2, 256, 0, stream>>>(Hbuf, W2 + (size_t)l * HID * EMB, b2 + (size_t)l * EMB,
                                              oth, N, EMB, HID,
                                              bng + (size_t)l * EMB, bnb + (size_t)l * EMB,
                                              bnm + (size_t)l * EMB, bnv + (size_t)l * EMB);
        float* t = cur; cur = oth; oth = t;
    }
    k_pool<<<G, 256, 0, stream>>>(cur, gid, (float*)d_out, N, NL);
}

// Round 2
// 1143.136 us; speedup vs baseline: 3.0146x; 3.0146x over previous
//
#include <hip/hip_runtime.h>

#define EMB 300
#define HID 600
#define NL 5
#define BN_EPS 1e-5f

#define FS 320          // padded feature stride (300 -> 320)
#define HS 640          // padded hidden stride (600 -> 640)
#define W2ROWS 384      // padded n-rows for W2T (3 tiles of 128)

typedef __attribute__((ext_vector_type(8))) short short8;
typedef __attribute__((ext_vector_type(4))) float f32x4;
typedef __attribute__((ext_vector_type(4))) unsigned short us4;

__device__ __forceinline__ unsigned short f2bf(float x) {
    unsigned u = __float_as_uint(x);
    unsigned r = (u + 0x7FFFu + ((u >> 16) & 1u)) >> 16;   // RNE
    return (unsigned short)r;
}

#define GLDS16(gsrc, ldst)                                                     \
    __builtin_amdgcn_global_load_lds(                                          \
        (const __attribute__((address_space(1))) unsigned int*)(gsrc),         \
        (__attribute__((address_space(3))) unsigned int*)(ldst), 16, 0, 0)

// ---------------- h0 = node_emb0[an] + node_emb1[ch], stride FS, pad zeros ----------------
__global__ void k_init_h0(const int* __restrict__ an, const int* __restrict__ ch,
                          const float* __restrict__ ne0, const float* __restrict__ ne1,
                          float* __restrict__ h0, int total) {
    int t = blockIdx.x * blockDim.x + threadIdx.x;
    if (t >= total) return;
    int i = t / FS, f = t - i * FS;
    h0[t] = (f < EMB) ? (ne0[an[i] * EMB + f] + ne1[ch[i] * EMB + f]) : 0.f;
}

// ---------------- CSR build (by dst) + per-node categorical counts ----------------
__global__ void k_hist(const int* __restrict__ dst, const int* __restrict__ bt,
                       const int* __restrict__ bd, int* __restrict__ deg,
                       int* __restrict__ cbt, int* __restrict__ cbd, int e) {
    int t = blockIdx.x * blockDim.x + threadIdx.x;
    if (t >= e) return;
    int d = dst[t];
    atomicAdd(&deg[d], 1);
    atomicAdd(&cbt[d * 6 + bt[t]], 1);
    atomicAdd(&cbd[d * 3 + bd[t]], 1);
}

__global__ void k_scan(const int* __restrict__ deg, int* __restrict__ row_off, int n) {
    __shared__ int sm[1024];
    __shared__ int carry_s;
    int tid = threadIdx.x;
    if (tid == 0) { carry_s = 0; row_off[0] = 0; }
    __syncthreads();
    for (int base = 0; base < n; base += 1024) {
        int i = base + tid;
        int v = (i < n) ? deg[i] : 0;
        sm[tid] = v;
        __syncthreads();
        for (int off = 1; off < 1024; off <<= 1) {
            int t = (tid >= off) ? sm[tid - off] : 0;
            __syncthreads();
            sm[tid] += t;
            __syncthreads();
        }
        int incl = sm[tid];
        int carry = carry_s;
        if (i < n) row_off[i + 1] = carry + incl;
        __syncthreads();
        if (tid == 1023) carry_s = carry + incl;
        __syncthreads();
    }
}

__global__ void k_copy_int(const int* __restrict__ a, int* __restrict__ b, int n) {
    int t = blockIdx.x * blockDim.x + threadIdx.x;
    if (t < n) b[t] = a[t];
}

__global__ void k_scatter(const int* __restrict__ dst, const int* __restrict__ src,
                          int* __restrict__ cursor, int* __restrict__ srcs, int e) {
    int t = blockIdx.x * blockDim.x + threadIdx.x;
    if (t < e) { int p = atomicAdd(&cursor[dst[t]], 1); srcs[p] = src[t]; }
}

// ---------------- weight prep: transpose + pad + bf16 ----------------
// W1T[l][n][k] : n<HS rows, k<FS, from W1[l][k][n] ([300][600]); zeros in pad
__global__ void k_prep_w1(const float* __restrict__ W1, unsigned short* __restrict__ W1T, int total) {
    int t = blockIdx.x * blockDim.x + threadIdx.x;
    if (t >= total) return;
    int k = t % FS, n = (t / FS) % HS, l = t / (FS * HS);
    W1T[t] = (n < HID && k < EMB) ? f2bf(W1[l * (EMB * HID) + k * HID + n]) : 0;
}

// W2T[l][n][k] : n<W2ROWS rows, k<HS, from W2[l][k][n] ([600][300]); zeros in pad
__global__ void k_prep_w2(const float* __restrict__ W2, unsigned short* __restrict__ W2T, int total) {
    int t = blockIdx.x * blockDim.x + threadIdx.x;
    if (t >= total) return;
    int k = t % HS, n = (t / HS) % W2ROWS, l = t / (HS * W2ROWS);
    W2T[t] = (n < EMB && k < HID) ? f2bf(W2[l * (HID * EMB) + k * EMB + n]) : 0;
}

// b1p[l][HS] (zeros pad); scp/shp[l][FS]: BN folded scale/shift (zeros pad)
__global__ void k_prep_params(const float* __restrict__ b1, const float* __restrict__ b2,
                              const float* __restrict__ g, const float* __restrict__ be,
                              const float* __restrict__ mu, const float* __restrict__ va,
                              float* __restrict__ b1p, float* __restrict__ scp,
                              float* __restrict__ shp, int total) {
    int t = blockIdx.x * blockDim.x + threadIdx.x;
    if (t >= total) return;
    int n = t % HS, l = t / HS;
    b1p[t] = (n < HID) ? b1[l * HID + n] : 0.f;
    if (n < FS) {
        float sc = 0.f, sh = 0.f;
        if (n < EMB) {
            sc = g[l * EMB + n] * rsqrtf(va[l * EMB + n] + BN_EPS);
            sh = be[l * EMB + n] + (b2[l * EMB + n] - mu[l * EMB + n]) * sc;
        }
        scp[l * FS + n] = sc;
        shp[l * FS + n] = sh;
    }
}

// ---------------- aggregation: agg[v] = sum_e feats[src] + counts . edge_emb -> bf16 ----------------
__global__ __launch_bounds__(256)
void k_aggregate(const float* __restrict__ feats,   // [M_pad][FS]
                 const float* __restrict__ e0,      // [6][EMB]
                 const float* __restrict__ e1,      // [3][EMB]
                 const int* __restrict__ row_off, const int* __restrict__ srcs,
                 const int* __restrict__ cbt, const int* __restrict__ cbd,
                 unsigned short* __restrict__ agg,  // [M_pad][FS] bf16
                 int n) {
    int v = blockIdx.x * 4 + (threadIdx.x >> 6);
    if (v >= n) return;
    int lane = threadIdx.x & 63;
    int s = row_off[v], e = row_off[v + 1];
    float acc[5] = {0.f, 0.f, 0.f, 0.f, 0.f};
    for (int j = s; j < e; ++j) {
        const float* fr = feats + (size_t)srcs[j] * FS;
#pragma unroll
        for (int q = 0; q < 5; ++q) acc[q] += fr[lane + q * 64];
    }
#pragma unroll
    for (int t = 0; t < 6; ++t) {
        int c = cbt[v * 6 + t];
        if (c) {
            float fc = (float)c;
#pragma unroll
            for (int q = 0; q < 5; ++q) {
                int col = lane + q * 64;
                if (col < EMB) acc[q] += fc * e0[t * EMB + col];
            }
        }
    }
#pragma unroll
    for (int t = 0; t < 3; ++t) {
        int c = cbd[v * 3 + t];
        if (c) {
            float fc = (float)c;
#pragma unroll
            for (int q = 0; q < 5; ++q) {
                int col = lane + q * 64;
                if (col < EMB) acc[q] += fc * e1[t * EMB + col];
            }
        }
    }
    unsigned short* ar = agg + (size_t)v * FS;
#pragma unroll
    for (int q = 0; q < 5; ++q) ar[lane + q * 64] = f2bf(acc[q]);
}

// ---------------- bf16 MFMA GEMM, 128x128 tile, BK=32, 4 waves ----------------
// Computes C = A[M_pad x K] * B (B given transposed: Bt[n][k]).
// EPI 0: relu(x + p0[n]) -> bf16 out (stride ldc)
// EPI 1: x*p0[n] + p1[n], relu -> f32 out
// EPI 2: x*p0[n] + p1[n]       -> f32 out
template <int EPI>
__global__ __launch_bounds__(256)
void k_mm(const unsigned short* __restrict__ A, int lda,
          const unsigned short* __restrict__ Bt, int ldb,
          const float* __restrict__ p0, const float* __restrict__ p1,
          void* __restrict__ Cout, int ldc, int K, int Nlim) {
    __shared__ unsigned short As[128 * 32];
    __shared__ unsigned short Bs[128 * 32];
    const int tid = threadIdx.x;
    const int lane = tid & 63, wid = tid >> 6;
    const int wm = wid >> 1, wn = wid & 1;
    const size_t bm = (size_t)blockIdx.x * 128;
    const int bn = blockIdx.y * 128;
    const int lr = lane & 15, lk = lane >> 4;
    const int srow = lane >> 2;          // staging: row within 16-row chunk
    const int scol = (lane & 3) * 8;     // staging: k-element offset
    f32x4 acc[4][4] = {};                // acc[i = n-frag][j = m-frag] (transposed-D)

    for (int k0 = 0; k0 < K; k0 += 32) {
        __syncthreads();
        {
            const unsigned short* ga0 = A + (bm + (size_t)(wid * 16 + srow)) * lda + k0 + scol;
            GLDS16(ga0, &As[(wid * 16) * 32]);
            const unsigned short* ga1 = A + (bm + (size_t)((wid + 4) * 16 + srow)) * lda + k0 + scol;
            GLDS16(ga1, &As[((wid + 4) * 16) * 32]);
            const unsigned short* gb0 = Bt + (size_t)(bn + wid * 16 + srow) * ldb + k0 + scol;
            GLDS16(gb0, &Bs[(wid * 16) * 32]);
            const unsigned short* gb1 = Bt + (size_t)(bn + (wid + 4) * 16 + srow) * ldb + k0 + scol;
            GLDS16(gb1, &Bs[((wid + 4) * 16) * 32]);
        }
        __syncthreads();
        short8 a[4], b[4];
#pragma unroll
        for (int j = 0; j < 4; ++j)
            a[j] = *(const short8*)&As[(wm * 64 + j * 16 + lr) * 32 + lk * 8];
#pragma unroll
        for (int i = 0; i < 4; ++i)
            b[i] = *(const short8*)&Bs[(wn * 64 + i * 16 + lr) * 32 + lk * 8];
#pragma unroll
        for (int i = 0; i < 4; ++i)
#pragma unroll
            for (int j = 0; j < 4; ++j)
                acc[i][j] = __builtin_amdgcn_mfma_f32_16x16x32_bf16(b[i], a[j], acc[i][j], 0, 0, 0);
    }

    const int rgrp = (lane >> 4) * 4;
#pragma unroll
    for (int i = 0; i < 4; ++i) {
        const int n0 = bn + wn * 64 + i * 16 + rgrp;   // 4 consecutive n per lane
        if (EPI != 0 && n0 >= Nlim) continue;
        const f32x4 q0 = *(const f32x4*)&p0[n0];
        f32x4 q1 = {};
        if (EPI != 0) q1 = *(const f32x4*)&p1[n0];
#pragma unroll
        for (int j = 0; j < 4; ++j) {
            const size_t m = bm + (size_t)(wm * 64 + j * 16 + lr);
            if (EPI == 0) {
                us4 h;
#pragma unroll
                for (int p = 0; p < 4; ++p) {
                    float x = acc[i][j][p] + q0[p];
                    h[p] = f2bf(fmaxf(x, 0.f));
                }
                *(us4*)((unsigned short*)Cout + m * ldc + n0) = h;
            } else {
                f32x4 o;
#pragma unroll
                for (int p = 0; p < 4; ++p) {
                    float x = acc[i][j][p] * q0[p] + q1[p];
                    o[p] = (EPI == 1) ? fmaxf(x, 0.f) : x;
                }
                *(f32x4*)((float*)Cout + m * ldc + n0) = o;
            }
        }
    }
}

// ---------------- per-graph pooling (one wave per graph) ----------------
__global__ __launch_bounds__(256)
void k_pool(const float* __restrict__ feats, const int* __restrict__ gids,
            float* __restrict__ out, int n_nodes, int G, int l) {
    int g = blockIdx.x * 4 + (threadIdx.x >> 6);
    if (g >= G) return;
    int lane = threadIdx.x & 63;
    int lo = 0, hi = n_nodes;
    while (lo < hi) { int mid = (lo + hi) >> 1; if (gids[mid] < g) lo = mid + 1; else hi = mid; }
    int s = lo;
    hi = n_nodes;
    while (lo < hi) { int mid = (lo + hi) >> 1; if (gids[mid] < g + 1) lo = mid + 1; else hi = mid; }
    int e = lo;
    float acc[5] = {0.f, 0.f, 0.f, 0.f, 0.f};
    for (int v = s; v < e; ++v) {
        const float* fr = feats + (size_t)v * FS;
#pragma unroll
        for (int q = 0; q < 5; ++q) acc[q] += fr[lane + q * 64];
    }
    float inv = 1.0f / (float)((e - s) > 0 ? (e - s) : 1);
#pragma unroll
    for (int q = 0; q < 5; ++q) {
        int col = lane + q * 64;
        if (col < EMB) {
            out[(size_t)g * (12 * EMB) + l * EMB + col] = acc[q] * inv;
            out[(size_t)g * (12 * EMB) + 6 * EMB + l * EMB + col] = acc[q];
        }
    }
}

extern "C" void kernel_launch(void* const* d_in, const int* in_sizes, int n_in,
                              void* d_out, int out_size, void* d_ws, size_t ws_size,
                              hipStream_t stream) {
    const int*   an  = (const int*)d_in[0];
    const int*   ch  = (const int*)d_in[1];
    const int*   bt  = (const int*)d_in[2];
    const int*   bd  = (const int*)d_in[3];
    const int*   src = (const int*)d_in[4];
    const int*   dst = (const int*)d_in[5];
    const int*   gid = (const int*)d_in[6];
    const float* ne0 = (const float*)d_in[8];
    const float* ne1 = (const float*)d_in[9];
    const float* ee0 = (const float*)d_in[10];
    const float* ee1 = (const float*)d_in[11];
    const float* W1  = (const float*)d_in[12];
    const float* b1  = (const float*)d_in[13];
    const float* W2  = (const float*)d_in[14];
    const float* b2  = (const float*)d_in[15];
    const float* bng = (const float*)d_in[16];
    const float* bnb = (const float*)d_in[17];
    const float* bnm = (const float*)d_in[18];
    const float* bnv = (const float*)d_in[19];

    const int N = in_sizes[0];
    const int E = in_sizes[2];
    const int G = out_size / (12 * EMB);
    const int M_pad = ((N + 127) / 128) * 128;
    const int MT = M_pad / 128;

    char* ws = (char*)d_ws;
    size_t off = 0;
    auto alloc = [&](size_t bytes) -> void* {
        void* p = (void*)(ws + off);
        off += (bytes + 255) & ~(size_t)255;
        return p;
    };
    float*          F0   = (float*)alloc((size_t)M_pad * FS * 4);
    float*          F1   = (float*)alloc((size_t)M_pad * FS * 4);
    unsigned short* A1   = (unsigned short*)alloc((size_t)M_pad * FS * 2);
    unsigned short* Hb   = (unsigned short*)alloc((size_t)M_pad * HS * 2);
    unsigned short* W1T  = (unsigned short*)alloc((size_t)NL * HS * FS * 2);
    unsigned short* W2T  = (unsigned short*)alloc((size_t)NL * W2ROWS * HS * 2);
    float*          b1p  = (float*)alloc((size_t)NL * HS * 4);
    float*          scp  = (float*)alloc((size_t)NL * FS * 4);
    float*          shp  = (float*)alloc((size_t)NL * FS * 4);
    int*            deg  = (int*)alloc((size_t)N * 4);
    int*            roff = (int*)alloc(((size_t)N + 1) * 4);
    int*            curs = (int*)alloc((size_t)N * 4);
    int*            srcs = (int*)alloc((size_t)E * 4);
    int*            cbt  = (int*)alloc((size_t)N * 6 * 4);
    int*            cbd  = (int*)alloc((size_t)N * 3 * 4);

    // weight / param prep
    {
        int t1 = NL * HS * FS;
        k_prep_w1<<<(t1 + 255) / 256, 256, 0, stream>>>(W1, W1T, t1);
        int t2 = NL * W2ROWS * HS;
        k_prep_w2<<<(t2 + 255) / 256, 256, 0, stream>>>(W2, W2T, t2);
        int t3 = NL * HS;
        k_prep_params<<<(t3 + 255) / 256, 256, 0, stream>>>(b1, b2, bng, bnb, bnm, bnv,
                                                            b1p, scp, shp, t3);
    }

    // h0
    const int total0 = N * FS;
    k_init_h0<<<(total0 + 255) / 256, 256, 0, stream>>>(an, ch, ne0, ne1, F0, total0);

    // CSR by dst + categorical counts
    hipMemsetAsync(deg, 0, (size_t)N * 4, stream);
    hipMemsetAsync(cbt, 0, (size_t)N * 6 * 4, stream);
    hipMemsetAsync(cbd, 0, (size_t)N * 3 * 4, stream);
    k_hist<<<(E + 255) / 256, 256, 0, stream>>>(dst, bt, bd, deg, cbt, cbd, E);
    k_scan<<<1, 1024, 0, stream>>>(deg, roff, N);
    k_copy_int<<<(N + 255) / 256, 256, 0, stream>>>(roff, curs, N);
    k_scatter<<<(E + 255) / 256, 256, 0, stream>>>(dst, src, curs, srcs, E);

    float* cur = F0;
    float* oth = F1;
    for (int l = 0; l < NL; ++l) {
        k_pool<<<(G + 3) / 4, 256, 0, stream>>>(cur, gid, (float*)d_out, N, G, l);
        k_aggregate<<<(N + 3) / 4, 256, 0, stream>>>(cur,
                                                     ee0 + (size_t)l * 6 * EMB,
                                                     ee1 + (size_t)l * 3 * EMB,
                                                     roff, srcs, cbt, cbd, A1, N);
        dim3 g1(MT, HS / 128);
        k_mm<0><<<g1, 256, 0, stream>>>(A1, FS, W1T + (size_t)l * HS * FS, FS,
                                        b1p + (size_t)l * HS, nullptr, Hb, HS, FS, HS);
        dim3 g2(MT, W2ROWS / 128);
        if (l < NL - 1)
            k_mm<1><<<g2, 256, 0, stream>>>(Hb, HS, W2T + (size_t)l * W2ROWS * HS, HS,
                                            scp + (size_t)l * FS, shp + (size_t)l * FS,
                                            oth, FS, HS, FS);
        else
            k_mm<2><<<g2, 256, 0, stream>>>(Hb, HS, W2T + (size_t)l * W2ROWS * HS, HS,
                                            scp + (size_t)l * FS, shp + (size_t)l * FS,
                                            oth, FS, HS, FS);
        float* t = cur; cur = oth; oth = t;
    }
    k_pool<<<(G + 3) / 4, 256, 0, stream>>>(cur, gid, (float*)d_out, N, G, NL);
}

// Round 3
// 1011.226 us; speedup vs baseline: 3.4078x; 1.1304x over previous
//
#include <hip/hip_runtime.h>

#define EMB 300
#define HID 600
#define NL 5
#define BN_EPS 1e-5f

#define FS 320          // padded feature stride (300 -> 320)
#define HS 640          // padded hidden stride (600 -> 640)
#define W2ROWS 384      // padded n-rows for W2T (3 tiles of 128)

typedef __attribute__((ext_vector_type(8))) short short8;
typedef __attribute__((ext_vector_type(4))) float f32x4;
typedef __attribute__((ext_vector_type(4))) unsigned short us4;

__device__ __forceinline__ unsigned short f2bf(float x) {
    unsigned u = __float_as_uint(x);
    unsigned r = (u + 0x7FFFu + ((u >> 16) & 1u)) >> 16;   // RNE
    return (unsigned short)r;
}
__device__ __forceinline__ float bf2f(unsigned short h) {
    return __uint_as_float(((unsigned)h) << 16);
}

#define GLDS16(gsrc, ldst)                                                     \
    __builtin_amdgcn_global_load_lds(                                          \
        (const __attribute__((address_space(1))) unsigned int*)(gsrc),         \
        (__attribute__((address_space(3))) unsigned int*)(ldst), 16, 0, 0)

// ---------------- h0 = node_emb0[an] + node_emb1[ch]: fp32 + bf16 copies ----------------
__global__ void k_init_h0(const int* __restrict__ an, const int* __restrict__ ch,
                          const float* __restrict__ ne0, const float* __restrict__ ne1,
                          float* __restrict__ F, unsigned short* __restrict__ Fb, int n) {
    int t = blockIdx.x * blockDim.x + threadIdx.x;
    int i = t / (FS / 4), f4 = t - i * (FS / 4);
    if (i >= n) return;
    int f = f4 * 4;
    float4 v = make_float4(0.f, 0.f, 0.f, 0.f);
    if (f < EMB) {  // EMB=300 is a multiple of 4; rows are 16B-aligned
        const float4 a = *(const float4*)(ne0 + (size_t)an[i] * EMB + f);
        const float4 b = *(const float4*)(ne1 + (size_t)ch[i] * EMB + f);
        v = make_float4(a.x + b.x, a.y + b.y, a.z + b.z, a.w + b.w);
    }
    *(float4*)(F + (size_t)i * FS + f) = v;
    us4 h;
    h[0] = f2bf(v.x); h[1] = f2bf(v.y); h[2] = f2bf(v.z); h[3] = f2bf(v.w);
    *(us4*)(Fb + (size_t)i * FS + f) = h;
}

// ---------------- CSR build (by dst) + per-node categorical counts ----------------
__global__ void k_hist(const int* __restrict__ dst, const int* __restrict__ bt,
                       const int* __restrict__ bd, int* __restrict__ deg,
                       int* __restrict__ cbt, int* __restrict__ cbd, int e) {
    int t = blockIdx.x * blockDim.x + threadIdx.x;
    if (t >= e) return;
    int d = dst[t];
    atomicAdd(&deg[d], 1);
    atomicAdd(&cbt[d * 6 + bt[t]], 1);
    atomicAdd(&cbd[d * 3 + bd[t]], 1);
}

// ---- hierarchical scan: pass A (per-1024 block inclusive scan + block totals) ----
__global__ __launch_bounds__(256)
void k_scan_blk(const int* __restrict__ deg, int* __restrict__ incl,
                int* __restrict__ part, int n) {
    int tid = threadIdx.x;
    int base = blockIdx.x * 1024 + tid * 4;
    int v0 = (base + 0 < n) ? deg[base + 0] : 0;
    int v1 = (base + 1 < n) ? deg[base + 1] : 0;
    int v2 = (base + 2 < n) ? deg[base + 2] : 0;
    int v3 = (base + 3 < n) ? deg[base + 3] : 0;
    int ts = v0 + v1 + v2 + v3;
    int lane = tid & 63, w = tid >> 6;
    int x = ts;
#pragma unroll
    for (int off = 1; off < 64; off <<= 1) {
        int y = __shfl_up(x, off);
        if (lane >= off) x += y;
    }
    __shared__ int ws[4];
    if (lane == 63) ws[w] = x;
    __syncthreads();
    int woff = 0;
    for (int i = 0; i < w; ++i) woff += ws[i];
    int r = woff + x - ts;  // exclusive prefix for this thread
    r += v0; if (base + 0 < n) incl[base + 0] = r;
    r += v1; if (base + 1 < n) incl[base + 1] = r;
    r += v2; if (base + 2 < n) incl[base + 2] = r;
    r += v3; if (base + 3 < n) incl[base + 3] = r;
    if (tid == 255) part[blockIdx.x] = woff + x;  // block total
}

// ---- pass B: exclusive scan of block totals (single block, nb <= 1024) ----
__global__ __launch_bounds__(1024)
void k_scan_part(int* __restrict__ part, int nb) {
    int tid = threadIdx.x;
    int v = (tid < nb) ? part[tid] : 0;
    int lane = tid & 63, w = tid >> 6;
    int x = v;
#pragma unroll
    for (int off = 1; off < 64; off <<= 1) {
        int y = __shfl_up(x, off);
        if (lane >= off) x += y;
    }
    __shared__ int ws[16];
    if (lane == 63) ws[w] = x;
    __syncthreads();
    int woff = 0;
    for (int i = 0; i < w; ++i) woff += ws[i];
    if (tid < nb) part[tid] = woff + x - v;  // exclusive
}

// ---- pass C: row_off[i+1] = incl[i]+part; cursor[i] = row_off[i] ----
__global__ void k_scan_add(const int* __restrict__ incl, const int* __restrict__ part,
                           const int* __restrict__ deg, int* __restrict__ roff,
                           int* __restrict__ curs, int n) {
    int i = blockIdx.x * blockDim.x + threadIdx.x;
    if (i >= n) return;
    int inc = incl[i] + part[i >> 10];
    roff[i + 1] = inc;
    curs[i] = inc - deg[i];
    if (i == 0) roff[0] = 0;
}

__global__ void k_scatter(const int* __restrict__ dst, const int* __restrict__ src,
                          int* __restrict__ cursor, int* __restrict__ srcs, int e) {
    int t = blockIdx.x * blockDim.x + threadIdx.x;
    if (t < e) { int p = atomicAdd(&cursor[dst[t]], 1); srcs[p] = src[t]; }
}

// ---------------- weight prep: transpose + pad + bf16 ----------------
__global__ void k_prep_w1(const float* __restrict__ W1, unsigned short* __restrict__ W1T, int total) {
    int t = blockIdx.x * blockDim.x + threadIdx.x;
    if (t >= total) return;
    int k = t % FS, n = (t / FS) % HS, l = t / (FS * HS);
    W1T[t] = (n < HID && k < EMB) ? f2bf(W1[l * (EMB * HID) + k * HID + n]) : 0;
}

__global__ void k_prep_w2(const float* __restrict__ W2, unsigned short* __restrict__ W2T, int total) {
    int t = blockIdx.x * blockDim.x + threadIdx.x;
    if (t >= total) return;
    int k = t % HS, n = (t / HS) % W2ROWS, l = t / (HS * W2ROWS);
    W2T[t] = (n < EMB && k < HID) ? f2bf(W2[l * (HID * EMB) + k * EMB + n]) : 0;
}

__global__ void k_prep_params(const float* __restrict__ b1, const float* __restrict__ b2,
                              const float* __restrict__ g, const float* __restrict__ be,
                              const float* __restrict__ mu, const float* __restrict__ va,
                              float* __restrict__ b1p, float* __restrict__ scp,
                              float* __restrict__ shp, int total) {
    int t = blockIdx.x * blockDim.x + threadIdx.x;
    if (t >= total) return;
    int n = t % HS, l = t / HS;
    b1p[t] = (n < HID) ? b1[l * HID + n] : 0.f;
    if (n < FS) {
        float sc = 0.f, sh = 0.f;
        if (n < EMB) {
            sc = g[l * EMB + n] * rsqrtf(va[l * EMB + n] + BN_EPS);
            sh = be[l * EMB + n] + (b2[l * EMB + n] - mu[l * EMB + n]) * sc;
        }
        scp[l * FS + n] = sc;
        shp[l * FS + n] = sh;
    }
}

// ---------------- aggregation: gathers bf16 feats, sums fp32, writes bf16 ----------------
__global__ __launch_bounds__(256)
void k_aggregate(const unsigned short* __restrict__ fb,  // [M_pad][FS] bf16
                 const float* __restrict__ e0,           // [6][EMB]
                 const float* __restrict__ e1,           // [3][EMB]
                 const int* __restrict__ row_off, const int* __restrict__ srcs,
                 const int* __restrict__ cbt, const int* __restrict__ cbd,
                 unsigned short* __restrict__ agg,       // [M_pad][FS] bf16
                 int n) {
    int v = blockIdx.x * 4 + (threadIdx.x >> 6);
    if (v >= n) return;
    int lane = threadIdx.x & 63;
    int s = row_off[v], e = row_off[v + 1];
    float acc[5] = {0.f, 0.f, 0.f, 0.f, 0.f};
    int j = s;
    for (; j + 1 < e; j += 2) {  // unroll-2: two independent gather chains
        const unsigned short* r0 = fb + (size_t)srcs[j] * FS;
        const unsigned short* r1 = fb + (size_t)srcs[j + 1] * FS;
#pragma unroll
        for (int q = 0; q < 5; ++q)
            acc[q] += bf2f(r0[lane + q * 64]) + bf2f(r1[lane + q * 64]);
    }
    if (j < e) {
        const unsigned short* r0 = fb + (size_t)srcs[j] * FS;
#pragma unroll
        for (int q = 0; q < 5; ++q) acc[q] += bf2f(r0[lane + q * 64]);
    }
#pragma unroll
    for (int t = 0; t < 6; ++t) {
        int c = cbt[v * 6 + t];
        if (c) {
            float fc = (float)c;
#pragma unroll
            for (int q = 0; q < 5; ++q) {
                int col = lane + q * 64;
                if (col < EMB) acc[q] += fc * e0[t * EMB + col];
            }
        }
    }
#pragma unroll
    for (int t = 0; t < 3; ++t) {
        int c = cbd[v * 3 + t];
        if (c) {
            float fc = (float)c;
#pragma unroll
            for (int q = 0; q < 5; ++q) {
                int col = lane + q * 64;
                if (col < EMB) acc[q] += fc * e1[t * EMB + col];
            }
        }
    }
    unsigned short* ar = agg + (size_t)v * FS;
#pragma unroll
    for (int q = 0; q < 5; ++q) ar[lane + q * 64] = f2bf(acc[q]);
}

// ---------------- bf16 MFMA GEMM, 128x128 tile, BK=32, 4 waves, 2-phase dbuf ----------------
// EPI 0: relu(x + p0[n]) -> bf16 Cb
// EPI 1: x*p0[n] + p1[n], relu -> f32 Cf AND bf16 Cb
// EPI 2: x*p0[n] + p1[n]       -> f32 Cf only
template <int EPI>
__global__ __launch_bounds__(256)
void k_mm(const unsigned short* __restrict__ A, int lda,
          const unsigned short* __restrict__ Bt, int ldb,
          const float* __restrict__ p0, const float* __restrict__ p1,
          unsigned short* __restrict__ Cb, float* __restrict__ Cf,
          int ldc, int K, int Nlim) {
    __shared__ unsigned short As[2][128 * 32];
    __shared__ unsigned short Bs[2][128 * 32];
    const int tid = threadIdx.x;
    const int lane = tid & 63, wid = tid >> 6;
    const int wm = wid >> 1, wn = wid & 1;
    const size_t bm = (size_t)blockIdx.x * 128;
    const int bn = blockIdx.y * 128;
    const int lr = lane & 15, lk = lane >> 4;
    const int srow = lane >> 2;
    const int scol = (lane & 3) * 8;
    f32x4 acc[4][4] = {};  // acc[i = n-frag][j = m-frag]

    const unsigned short* gA  = A + (bm + (size_t)(wid * 16 + srow)) * lda + scol;
    const unsigned short* gA2 = A + (bm + (size_t)((wid + 4) * 16 + srow)) * lda + scol;
    const unsigned short* gB  = Bt + (size_t)(bn + wid * 16 + srow) * ldb + scol;
    const unsigned short* gB2 = Bt + (size_t)(bn + (wid + 4) * 16 + srow) * ldb + scol;

    auto STAGE = [&](int buf, int k0) {
        GLDS16(gA  + k0, &As[buf][(wid * 16) * 32]);
        GLDS16(gA2 + k0, &As[buf][((wid + 4) * 16) * 32]);
        GLDS16(gB  + k0, &Bs[buf][(wid * 16) * 32]);
        GLDS16(gB2 + k0, &Bs[buf][((wid + 4) * 16) * 32]);
    };

    const int nt = K >> 5;
    STAGE(0, 0);
    __syncthreads();
    int cur = 0;
    for (int t = 0; t < nt; ++t) {
        if (t + 1 < nt) STAGE(cur ^ 1, (t + 1) * 32);  // prefetch overlaps MFMA below
        short8 a[4], b[4];
#pragma unroll
        for (int j = 0; j < 4; ++j)
            a[j] = *(const short8*)&As[cur][(wm * 64 + j * 16 + lr) * 32 + lk * 8];
#pragma unroll
        for (int i = 0; i < 4; ++i)
            b[i] = *(const short8*)&Bs[cur][(wn * 64 + i * 16 + lr) * 32 + lk * 8];
#pragma unroll
        for (int i = 0; i < 4; ++i)
#pragma unroll
            for (int j = 0; j < 4; ++j)
                acc[i][j] = __builtin_amdgcn_mfma_f32_16x16x32_bf16(b[i], a[j], acc[i][j], 0, 0, 0);
        __syncthreads();  // implies vmcnt(0) drain: prefetched tile is ready
        cur ^= 1;
    }

    const int rgrp = (lane >> 4) * 4;
#pragma unroll
    for (int i = 0; i < 4; ++i) {
        const int n0 = bn + wn * 64 + i * 16 + rgrp;   // 4 consecutive n per lane
        if (EPI != 0 && n0 >= Nlim) continue;
        const f32x4 q0 = *(const f32x4*)&p0[n0];
        f32x4 q1 = {};
        if (EPI != 0) q1 = *(const f32x4*)&p1[n0];
#pragma unroll
        for (int j = 0; j < 4; ++j) {
            const size_t m = bm + (size_t)(wm * 64 + j * 16 + lr);
            if (EPI == 0) {
                us4 h;
#pragma unroll
                for (int p = 0; p < 4; ++p)
                    h[p] = f2bf(fmaxf(acc[i][j][p] + q0[p], 0.f));
                *(us4*)(Cb + m * ldc + n0) = h;
            } else {
                f32x4 o;
                us4 h;
#pragma unroll
                for (int p = 0; p < 4; ++p) {
                    float x = acc[i][j][p] * q0[p] + q1[p];
                    if (EPI == 1) x = fmaxf(x, 0.f);
                    o[p] = x;
                    h[p] = f2bf(x);
                }
                *(f32x4*)(Cf + m * ldc + n0) = o;
                if (EPI == 1) *(us4*)(Cb + m * ldc + n0) = h;
            }
        }
    }
}

// ---------------- per-graph pooling (one wave per graph, fp32 feats) ----------------
__global__ __launch_bounds__(256)
void k_pool(const float* __restrict__ feats, const int* __restrict__ gids,
            float* __restrict__ out, int n_nodes, int G, int l) {
    int g = blockIdx.x * 4 + (threadIdx.x >> 6);
    if (g >= G) return;
    int lane = threadIdx.x & 63;
    int lo = 0, hi = n_nodes;
    while (lo < hi) { int mid = (lo + hi) >> 1; if (gids[mid] < g) lo = mid + 1; else hi = mid; }
    int s = lo;
    hi = n_nodes;
    while (lo < hi) { int mid = (lo + hi) >> 1; if (gids[mid] < g + 1) lo = mid + 1; else hi = mid; }
    int e = lo;
    float acc[5] = {0.f, 0.f, 0.f, 0.f, 0.f};
    int v = s;
    for (; v + 1 < e; v += 2) {
        const float* r0 = feats + (size_t)v * FS;
        const float* r1 = r0 + FS;
#pragma unroll
        for (int q = 0; q < 5; ++q) acc[q] += r0[lane + q * 64] + r1[lane + q * 64];
    }
    if (v < e) {
        const float* r0 = feats + (size_t)v * FS;
#pragma unroll
        for (int q = 0; q < 5; ++q) acc[q] += r0[lane + q * 64];
    }
    float inv = 1.0f / (float)((e - s) > 0 ? (e - s) : 1);
#pragma unroll
    for (int q = 0; q < 5; ++q) {
        int col = lane + q * 64;
        if (col < EMB) {
            out[(size_t)g * (12 * EMB) + l * EMB + col] = acc[q] * inv;
            out[(size_t)g * (12 * EMB) + 6 * EMB + l * EMB + col] = acc[q];
        }
    }
}

extern "C" void kernel_launch(void* const* d_in, const int* in_sizes, int n_in,
                              void* d_out, int out_size, void* d_ws, size_t ws_size,
                              hipStream_t stream) {
    const int*   an  = (const int*)d_in[0];
    const int*   ch  = (const int*)d_in[1];
    const int*   bt  = (const int*)d_in[2];
    const int*   bd  = (const int*)d_in[3];
    const int*   src = (const int*)d_in[4];
    const int*   dst = (const int*)d_in[5];
    const int*   gid = (const int*)d_in[6];
    const float* ne0 = (const float*)d_in[8];
    const float* ne1 = (const float*)d_in[9];
    const float* ee0 = (const float*)d_in[10];
    const float* ee1 = (const float*)d_in[11];
    const float* W1  = (const float*)d_in[12];
    const float* b1  = (const float*)d_in[13];
    const float* W2  = (const float*)d_in[14];
    const float* b2  = (const float*)d_in[15];
    const float* bng = (const float*)d_in[16];
    const float* bnb = (const float*)d_in[17];
    const float* bnm = (const float*)d_in[18];
    const float* bnv = (const float*)d_in[19];

    const int N = in_sizes[0];
    const int E = in_sizes[2];
    const int G = out_size / (12 * EMB);
    const int M_pad = ((N + 127) / 128) * 128;
    const int MT = M_pad / 128;
    const int nb = (N + 1023) / 1024;

    char* ws = (char*)d_ws;
    size_t off = 0;
    auto alloc = [&](size_t bytes) -> void* {
        void* p = (void*)(ws + off);
        off += (bytes + 255) & ~(size_t)255;
        return p;
    };
    float*          F    = (float*)alloc((size_t)M_pad * FS * 4);           // fp32 feats (pool)
    unsigned short* Fb0  = (unsigned short*)alloc((size_t)M_pad * FS * 2);  // bf16 feats ping
    unsigned short* Fb1  = (unsigned short*)alloc((size_t)M_pad * FS * 2);  // bf16 feats pong
    unsigned short* A1   = (unsigned short*)alloc((size_t)M_pad * FS * 2);  // agg (GEMM1 A)
    unsigned short* Hb   = (unsigned short*)alloc((size_t)M_pad * HS * 2);  // hidden (GEMM2 A)
    unsigned short* W1T  = (unsigned short*)alloc((size_t)NL * HS * FS * 2);
    unsigned short* W2T  = (unsigned short*)alloc((size_t)NL * W2ROWS * HS * 2);
    float*          b1p  = (float*)alloc((size_t)NL * HS * 4);
    float*          scp  = (float*)alloc((size_t)NL * FS * 4);
    float*          shp  = (float*)alloc((size_t)NL * FS * 4);
    int*            deg  = (int*)alloc((size_t)N * 4);
    int*            roff = (int*)alloc(((size_t)N + 1) * 4);
    int*            curs = (int*)alloc((size_t)N * 4);
    int*            srcs = (int*)alloc((size_t)E * 4);
    int*            cbt  = (int*)alloc((size_t)N * 6 * 4);
    int*            cbd  = (int*)alloc((size_t)N * 3 * 4);
    int*            incl = (int*)alloc((size_t)N * 4);
    int*            part = (int*)alloc((size_t)1024 * 4);

    // weight / param prep
    {
        int t1 = NL * HS * FS;
        k_prep_w1<<<(t1 + 255) / 256, 256, 0, stream>>>(W1, W1T, t1);
        int t2 = NL * W2ROWS * HS;
        k_prep_w2<<<(t2 + 255) / 256, 256, 0, stream>>>(W2, W2T, t2);
        int t3 = NL * HS;
        k_prep_params<<<(t3 + 255) / 256, 256, 0, stream>>>(b1, b2, bng, bnb, bnm, bnv,
                                                            b1p, scp, shp, t3);
    }

    // h0 (fp32 + bf16)
    {
        int tt = N * (FS / 4);
        k_init_h0<<<(tt + 255) / 256, 256, 0, stream>>>(an, ch, ne0, ne1, F, Fb0, N);
    }

    // CSR by dst + categorical counts (hierarchical scan)
    hipMemsetAsync(deg, 0, (size_t)N * 4, stream);
    hipMemsetAsync(cbt, 0, (size_t)N * 6 * 4, stream);
    hipMemsetAsync(cbd, 0, (size_t)N * 3 * 4, stream);
    k_hist<<<(E + 255) / 256, 256, 0, stream>>>(dst, bt, bd, deg, cbt, cbd, E);
    k_scan_blk<<<nb, 256, 0, stream>>>(deg, incl, part, N);
    k_scan_part<<<1, 1024, 0, stream>>>(part, nb);
    k_scan_add<<<(N + 255) / 256, 256, 0, stream>>>(incl, part, deg, roff, curs, N);
    k_scatter<<<(E + 255) / 256, 256, 0, stream>>>(dst, src, curs, srcs, E);

    unsigned short* Fbc = Fb0;
    unsigned short* Fbo = Fb1;
    for (int l = 0; l < NL; ++l) {
        k_pool<<<(G + 3) / 4, 256, 0, stream>>>(F, gid, (float*)d_out, N, G, l);
        k_aggregate<<<(N + 3) / 4, 256, 0, stream>>>(Fbc,
                                                     ee0 + (size_t)l * 6 * EMB,
                                                     ee1 + (size_t)l * 3 * EMB,
                                                     roff, srcs, cbt, cbd, A1, N);
        dim3 g1(MT, HS / 128);
        k_mm<0><<<g1, 256, 0, stream>>>(A1, FS, W1T + (size_t)l * HS * FS, FS,
                                        b1p + (size_t)l * HS, nullptr, Hb, nullptr, HS, FS, HS);
        dim3 g2(MT, W2ROWS / 128);
        if (l < NL - 1)
            k_mm<1><<<g2, 256, 0, stream>>>(Hb, HS, W2T + (size_t)l * W2ROWS * HS, HS,
                                            scp + (size_t)l * FS, shp + (size_t)l * FS,
                                            Fbo, F, FS, HS, FS);
        else
            k_mm<2><<<g2, 256, 0, stream>>>(Hb, HS, W2T + (size_t)l * W2ROWS * HS, HS,
                                            scp + (size_t)l * FS, shp + (size_t)l * FS,
                                            nullptr, F, FS, HS, FS);
        unsigned short* t = Fbc; Fbc = Fbo; Fbo = t;
    }
    k_pool<<<(G + 3) / 4, 256, 0, stream>>>(F, gid, (float*)d_out, N, G, NL);
}

// Round 4
// 950.033 us; speedup vs baseline: 3.6274x; 1.0644x over previous
//
#include <hip/hip_runtime.h>

#define EMB 300
#define HID 600
#define NL 5
#define BN_EPS 1e-5f

#define FS 320          // padded feature stride (300 -> 320)
#define HS 640          // padded hidden stride (600 -> 640)
#define W2ROWS 384      // padded n-rows for W2T (3 tiles of 128)

typedef __attribute__((ext_vector_type(8))) short short8;
typedef __attribute__((ext_vector_type(4))) float f32x4;
typedef __attribute__((ext_vector_type(4))) unsigned short us4;

__device__ __forceinline__ unsigned short f2bf(float x) {
    unsigned u = __float_as_uint(x);
    unsigned r = (u + 0x7FFFu + ((u >> 16) & 1u)) >> 16;   // RNE
    return (unsigned short)r;
}
__device__ __forceinline__ float bf2f(unsigned short h) {
    return __uint_as_float(((unsigned)h) << 16);
}

#define GLDS16(gsrc, ldst)                                                     \
    __builtin_amdgcn_global_load_lds(                                          \
        (const __attribute__((address_space(1))) unsigned int*)(gsrc),         \
        (__attribute__((address_space(3))) unsigned int*)(ldst), 16, 0, 0)

// ---------------- h0 = node_emb0[an] + node_emb1[ch] -> bf16, stride FS ----------------
__global__ void k_init_h0(const int* __restrict__ an, const int* __restrict__ ch,
                          const float* __restrict__ ne0, const float* __restrict__ ne1,
                          unsigned short* __restrict__ Fb, int n) {
    int t = blockIdx.x * blockDim.x + threadIdx.x;
    int i = t / (FS / 4), f4 = t - i * (FS / 4);
    if (i >= n) return;
    int f = f4 * 4;
    us4 h = {0, 0, 0, 0};
    if (f < EMB) {  // EMB=300 is a multiple of 4; rows are 16B-aligned
        const float4 a = *(const float4*)(ne0 + (size_t)an[i] * EMB + f);
        const float4 b = *(const float4*)(ne1 + (size_t)ch[i] * EMB + f);
        h[0] = f2bf(a.x + b.x); h[1] = f2bf(a.y + b.y);
        h[2] = f2bf(a.z + b.z); h[3] = f2bf(a.w + b.w);
    }
    *(us4*)(Fb + (size_t)i * FS + f) = h;
}

// ---------------- CSR build (by dst) + per-node categorical counts ----------------
__global__ void k_hist(const int* __restrict__ dst, const int* __restrict__ bt,
                       const int* __restrict__ bd, int* __restrict__ deg,
                       int* __restrict__ cbt, int* __restrict__ cbd, int e) {
    int t = blockIdx.x * blockDim.x + threadIdx.x;
    if (t >= e) return;
    int d = dst[t];
    atomicAdd(&deg[d], 1);
    atomicAdd(&cbt[d * 6 + bt[t]], 1);
    atomicAdd(&cbd[d * 3 + bd[t]], 1);
}

// ---- hierarchical scan: pass A (per-1024 block inclusive scan + block totals) ----
__global__ __launch_bounds__(256)
void k_scan_blk(const int* __restrict__ deg, int* __restrict__ incl,
                int* __restrict__ part, int n) {
    int tid = threadIdx.x;
    int base = blockIdx.x * 1024 + tid * 4;
    int v0 = (base + 0 < n) ? deg[base + 0] : 0;
    int v1 = (base + 1 < n) ? deg[base + 1] : 0;
    int v2 = (base + 2 < n) ? deg[base + 2] : 0;
    int v3 = (base + 3 < n) ? deg[base + 3] : 0;
    int ts = v0 + v1 + v2 + v3;
    int lane = tid & 63, w = tid >> 6;
    int x = ts;
#pragma unroll
    for (int off = 1; off < 64; off <<= 1) {
        int y = __shfl_up(x, off);
        if (lane >= off) x += y;
    }
    __shared__ int ws[4];
    if (lane == 63) ws[w] = x;
    __syncthreads();
    int woff = 0;
    for (int i = 0; i < w; ++i) woff += ws[i];
    int r = woff + x - ts;  // exclusive prefix for this thread
    r += v0; if (base + 0 < n) incl[base + 0] = r;
    r += v1; if (base + 1 < n) incl[base + 1] = r;
    r += v2; if (base + 2 < n) incl[base + 2] = r;
    r += v3; if (base + 3 < n) incl[base + 3] = r;
    if (tid == 255) part[blockIdx.x] = woff + x;  // block total
}

// ---- pass B: exclusive scan of block totals (single block, nb <= 1024) ----
__global__ __launch_bounds__(1024)
void k_scan_part(int* __restrict__ part, int nb) {
    int tid = threadIdx.x;
    int v = (tid < nb) ? part[tid] : 0;
    int lane = tid & 63, w = tid >> 6;
    int x = v;
#pragma unroll
    for (int off = 1; off < 64; off <<= 1) {
        int y = __shfl_up(x, off);
        if (lane >= off) x += y;
    }
    __shared__ int ws[16];
    if (lane == 63) ws[w] = x;
    __syncthreads();
    int woff = 0;
    for (int i = 0; i < w; ++i) woff += ws[i];
    if (tid < nb) part[tid] = woff + x - v;  // exclusive
}

// ---- pass C: row_off[i+1] = incl[i]+part; cursor[i] = row_off[i] ----
__global__ void k_scan_add(const int* __restrict__ incl, const int* __restrict__ part,
                           const int* __restrict__ deg, int* __restrict__ roff,
                           int* __restrict__ curs, int n) {
    int i = blockIdx.x * blockDim.x + threadIdx.x;
    if (i >= n) return;
    int inc = incl[i] + part[i >> 10];
    roff[i + 1] = inc;
    curs[i] = inc - deg[i];
    if (i == 0) roff[0] = 0;
}

__global__ void k_scatter(const int* __restrict__ dst, const int* __restrict__ src,
                          int* __restrict__ cursor, int* __restrict__ srcs, int e) {
    int t = blockIdx.x * blockDim.x + threadIdx.x;
    if (t < e) { int p = atomicAdd(&cursor[dst[t]], 1); srcs[p] = src[t]; }
}

// ---------------- weight prep: transpose + pad + bf16 ----------------
__global__ void k_prep_w1(const float* __restrict__ W1, unsigned short* __restrict__ W1T, int total) {
    int t = blockIdx.x * blockDim.x + threadIdx.x;
    if (t >= total) return;
    int k = t % FS, n = (t / FS) % HS, l = t / (FS * HS);
    W1T[t] = (n < HID && k < EMB) ? f2bf(W1[l * (EMB * HID) + k * HID + n]) : 0;
}

__global__ void k_prep_w2(const float* __restrict__ W2, unsigned short* __restrict__ W2T, int total) {
    int t = blockIdx.x * blockDim.x + threadIdx.x;
    if (t >= total) return;
    int k = t % HS, n = (t / HS) % W2ROWS, l = t / (HS * W2ROWS);
    W2T[t] = (n < EMB && k < HID) ? f2bf(W2[l * (HID * EMB) + k * EMB + n]) : 0;
}

__global__ void k_prep_params(const float* __restrict__ b1, const float* __restrict__ b2,
                              const float* __restrict__ g, const float* __restrict__ be,
                              const float* __restrict__ mu, const float* __restrict__ va,
                              float* __restrict__ b1p, float* __restrict__ scp,
                              float* __restrict__ shp, int total) {
    int t = blockIdx.x * blockDim.x + threadIdx.x;
    if (t >= total) return;
    int n = t % HS, l = t / HS;
    b1p[t] = (n < HID) ? b1[l * HID + n] : 0.f;
    if (n < FS) {
        float sc = 0.f, sh = 0.f;
        if (n < EMB) {
            sc = g[l * EMB + n] * rsqrtf(va[l * EMB + n] + BN_EPS);
            sh = be[l * EMB + n] + (b2[l * EMB + n] - mu[l * EMB + n]) * sc;
        }
        scp[l * FS + n] = sc;
        shp[l * FS + n] = sh;
    }
}

// ---------------- aggregation: gathers bf16 feats, sums fp32, writes bf16 ----------------
__global__ __launch_bounds__(256)
void k_aggregate(const unsigned short* __restrict__ fb,  // [M_pad][FS] bf16
                 const float* __restrict__ e0,           // [6][EMB]
                 const float* __restrict__ e1,           // [3][EMB]
                 const int* __restrict__ row_off, const int* __restrict__ srcs,
                 const int* __restrict__ cbt, const int* __restrict__ cbd,
                 unsigned short* __restrict__ agg,       // [M_pad][FS] bf16
                 int n) {
    int v = blockIdx.x * 4 + (threadIdx.x >> 6);
    if (v >= n) return;
    int lane = threadIdx.x & 63;
    int s = row_off[v], e = row_off[v + 1];
    float acc[5] = {0.f, 0.f, 0.f, 0.f, 0.f};
    int j = s;
    for (; j + 1 < e; j += 2) {  // unroll-2: two independent gather chains
        const unsigned short* r0 = fb + (size_t)srcs[j] * FS;
        const unsigned short* r1 = fb + (size_t)srcs[j + 1] * FS;
#pragma unroll
        for (int q = 0; q < 5; ++q)
            acc[q] += bf2f(r0[lane + q * 64]) + bf2f(r1[lane + q * 64]);
    }
    if (j < e) {
        const unsigned short* r0 = fb + (size_t)srcs[j] * FS;
#pragma unroll
        for (int q = 0; q < 5; ++q) acc[q] += bf2f(r0[lane + q * 64]);
    }
#pragma unroll
    for (int t = 0; t < 6; ++t) {
        int c = cbt[v * 6 + t];
        if (c) {
            float fc = (float)c;
#pragma unroll
            for (int q = 0; q < 5; ++q) {
                int col = lane + q * 64;
                if (col < EMB) acc[q] += fc * e0[t * EMB + col];
            }
        }
    }
#pragma unroll
    for (int t = 0; t < 3; ++t) {
        int c = cbd[v * 3 + t];
        if (c) {
            float fc = (float)c;
#pragma unroll
            for (int q = 0; q < 5; ++q) {
                int col = lane + q * 64;
                if (col < EMB) acc[q] += fc * e1[t * EMB + col];
            }
        }
    }
    unsigned short* ar = agg + (size_t)v * FS;
#pragma unroll
    for (int q = 0; q < 5; ++q) ar[lane + q * 64] = f2bf(acc[q]);
}

// ---------------- bf16 MFMA GEMM, 128x128 tile, BK=32, 4 waves ----------------
// 4-buffer LDS pipeline, counted vmcnt (loads for t+1,t+2 stay in flight across
// barriers), raw s_barrier (no vmcnt(0) drain), setprio around MFMA cluster.
// EPI 0: relu(x + p0[n])       -> bf16
// EPI 1: x*p0[n] + p1[n], relu -> bf16
// EPI 2: x*p0[n] + p1[n]       -> bf16
template <int EPI>
__global__ __launch_bounds__(256)
void k_mm(const unsigned short* __restrict__ A, int lda,
          const unsigned short* __restrict__ Bt, int ldb,
          const float* __restrict__ p0, const float* __restrict__ p1,
          unsigned short* __restrict__ Cb, int ldc, int K, int Nlim) {
    __shared__ unsigned short As[4][128 * 32];
    __shared__ unsigned short Bs[4][128 * 32];
    const int tid = threadIdx.x;
    const int lane = tid & 63, wid = tid >> 6;
    const int wm = wid >> 1, wn = wid & 1;
    const size_t bm = (size_t)blockIdx.x * 128;
    const int bn = blockIdx.y * 128;
    const int lr = lane & 15, lk = lane >> 4;
    const int srow = lane >> 2;          // staging: row within 16-row chunk
    const int scol = (lane & 3) * 8;     // staging: k-element offset
    f32x4 acc[4][4] = {};                // acc[i = n-frag][j = m-frag]

    const unsigned short* gA  = A + (bm + (size_t)(wid * 16 + srow)) * lda + scol;
    const unsigned short* gA2 = A + (bm + (size_t)((wid + 4) * 16 + srow)) * lda + scol;
    const unsigned short* gB  = Bt + (size_t)(bn + wid * 16 + srow) * ldb + scol;
    const unsigned short* gB2 = Bt + (size_t)(bn + (wid + 4) * 16 + srow) * ldb + scol;

    auto STAGE = [&](int buf, int k0) {   // 4 loads per wave
        GLDS16(gA  + k0, &As[buf][(wid * 16) * 32]);
        GLDS16(gA2 + k0, &As[buf][((wid + 4) * 16) * 32]);
        GLDS16(gB  + k0, &Bs[buf][(wid * 16) * 32]);
        GLDS16(gB2 + k0, &Bs[buf][((wid + 4) * 16) * 32]);
    };

    const int nt = K >> 5;
    STAGE(0, 0);
    if (nt > 1) STAGE(1, 32);
    if (nt > 2) STAGE(2, 64);

    for (int t = 0; t < nt; ++t) {
        // wait only for tile t's loads: (stages in flight after t) * 4 loads
        if (t + 2 < nt)      asm volatile("s_waitcnt vmcnt(8)" ::: "memory");
        else if (t + 1 < nt) asm volatile("s_waitcnt vmcnt(4)" ::: "memory");
        else                 asm volatile("s_waitcnt vmcnt(0)" ::: "memory");
        __builtin_amdgcn_s_barrier();
        const int cur = t & 3;
        short8 a[4], b[4];
#pragma unroll
        for (int j = 0; j < 4; ++j)
            a[j] = *(const short8*)&As[cur][(wm * 64 + j * 16 + lr) * 32 + lk * 8];
#pragma unroll
        for (int i = 0; i < 4; ++i)
            b[i] = *(const short8*)&Bs[cur][(wn * 64 + i * 16 + lr) * 32 + lk * 8];
        if (t + 3 < nt) STAGE((t + 3) & 3, (t + 3) * 32);  // overwrites buf[(t-1)&3]: readers retired pre-barrier
        __builtin_amdgcn_s_setprio(1);
#pragma unroll
        for (int i = 0; i < 4; ++i)
#pragma unroll
            for (int j = 0; j < 4; ++j)
                acc[i][j] = __builtin_amdgcn_mfma_f32_16x16x32_bf16(b[i], a[j], acc[i][j], 0, 0, 0);
        __builtin_amdgcn_s_setprio(0);
    }

    const int rgrp = (lane >> 4) * 4;
#pragma unroll
    for (int i = 0; i < 4; ++i) {
        const int n0 = bn + wn * 64 + i * 16 + rgrp;   // 4 consecutive n per lane
        if (EPI != 0 && n0 >= Nlim) continue;
        const f32x4 q0 = *(const f32x4*)&p0[n0];
        f32x4 q1 = {};
        if (EPI != 0) q1 = *(const f32x4*)&p1[n0];
#pragma unroll
        for (int j = 0; j < 4; ++j) {
            const size_t m = bm + (size_t)(wm * 64 + j * 16 + lr);
            us4 h;
#pragma unroll
            for (int p = 0; p < 4; ++p) {
                float x = (EPI == 0) ? (acc[i][j][p] + q0[p]) : (acc[i][j][p] * q0[p] + q1[p]);
                if (EPI != 2) x = fmaxf(x, 0.f);
                h[p] = f2bf(x);
            }
            *(us4*)(Cb + m * ldc + n0) = h;
        }
    }
}

// ---------------- per-graph pooling (one wave per graph, bf16 feats) ----------------
__global__ __launch_bounds__(256)
void k_pool(const unsigned short* __restrict__ feats, const int* __restrict__ gids,
            float* __restrict__ out, int n_nodes, int G, int l) {
    int g = blockIdx.x * 4 + (threadIdx.x >> 6);
    if (g >= G) return;
    int lane = threadIdx.x & 63;
    int lo = 0, hi = n_nodes;
    while (lo < hi) { int mid = (lo + hi) >> 1; if (gids[mid] < g) lo = mid + 1; else hi = mid; }
    int s = lo;
    hi = n_nodes;
    while (lo < hi) { int mid = (lo + hi) >> 1; if (gids[mid] < g + 1) lo = mid + 1; else hi = mid; }
    int e = lo;
    float acc[5] = {0.f, 0.f, 0.f, 0.f, 0.f};
    int v = s;
    for (; v + 1 < e; v += 2) {
        const unsigned short* r0 = feats + (size_t)v * FS;
        const unsigned short* r1 = r0 + FS;
#pragma unroll
        for (int q = 0; q < 5; ++q)
            acc[q] += bf2f(r0[lane + q * 64]) + bf2f(r1[lane + q * 64]);
    }
    if (v < e) {
        const unsigned short* r0 = feats + (size_t)v * FS;
#pragma unroll
        for (int q = 0; q < 5; ++q) acc[q] += bf2f(r0[lane + q * 64]);
    }
    float inv = 1.0f / (float)((e - s) > 0 ? (e - s) : 1);
#pragma unroll
    for (int q = 0; q < 5; ++q) {
        int col = lane + q * 64;
        if (col < EMB) {
            out[(size_t)g * (12 * EMB) + l * EMB + col] = acc[q] * inv;
            out[(size_t)g * (12 * EMB) + 6 * EMB + l * EMB + col] = acc[q];
        }
    }
}

extern "C" void kernel_launch(void* const* d_in, const int* in_sizes, int n_in,
                              void* d_out, int out_size, void* d_ws, size_t ws_size,
                              hipStream_t stream) {
    const int*   an  = (const int*)d_in[0];
    const int*   ch  = (const int*)d_in[1];
    const int*   bt  = (const int*)d_in[2];
    const int*   bd  = (const int*)d_in[3];
    const int*   src = (const int*)d_in[4];
    const int*   dst = (const int*)d_in[5];
    const int*   gid = (const int*)d_in[6];
    const float* ne0 = (const float*)d_in[8];
    const float* ne1 = (const float*)d_in[9];
    const float* ee0 = (const float*)d_in[10];
    const float* ee1 = (const float*)d_in[11];
    const float* W1  = (const float*)d_in[12];
    const float* b1  = (const float*)d_in[13];
    const float* W2  = (const float*)d_in[14];
    const float* b2  = (const float*)d_in[15];
    const float* bng = (const float*)d_in[16];
    const float* bnb = (const float*)d_in[17];
    const float* bnm = (const float*)d_in[18];
    const float* bnv = (const float*)d_in[19];

    const int N = in_sizes[0];
    const int E = in_sizes[2];
    const int G = out_size / (12 * EMB);
    const int M_pad = ((N + 127) / 128) * 128;
    const int MT = M_pad / 128;
    const int nb = (N + 1023) / 1024;

    char* ws = (char*)d_ws;
    size_t off = 0;
    auto alloc = [&](size_t bytes) -> void* {
        void* p = (void*)(ws + off);
        off += (bytes + 255) & ~(size_t)255;
        return p;
    };
    unsigned short* Fb0  = (unsigned short*)alloc((size_t)M_pad * FS * 2);  // bf16 feats ping
    unsigned short* Fb1  = (unsigned short*)alloc((size_t)M_pad * FS * 2);  // bf16 feats pong
    unsigned short* A1   = (unsigned short*)alloc((size_t)M_pad * FS * 2);  // agg (GEMM1 A)
    unsigned short* Hb   = (unsigned short*)alloc((size_t)M_pad * HS * 2);  // hidden (GEMM2 A)
    unsigned short* W1T  = (unsigned short*)alloc((size_t)NL * HS * FS * 2);
    unsigned short* W2T  = (unsigned short*)alloc((size_t)NL * W2ROWS * HS * 2);
    float*          b1p  = (float*)alloc((size_t)NL * HS * 4);
    float*          scp  = (float*)alloc((size_t)NL * FS * 4);
    float*          shp  = (float*)alloc((size_t)NL * FS * 4);
    int*            deg  = (int*)alloc((size_t)N * 4);
    int*            roff = (int*)alloc(((size_t)N + 1) * 4);
    int*            curs = (int*)alloc((size_t)N * 4);
    int*            srcs = (int*)alloc((size_t)E * 4);
    int*            cbt  = (int*)alloc((size_t)N * 6 * 4);
    int*            cbd  = (int*)alloc((size_t)N * 3 * 4);
    int*            incl = (int*)alloc((size_t)N * 4);
    int*            part = (int*)alloc((size_t)1024 * 4);

    // weight / param prep
    {
        int t1 = NL * HS * FS;
        k_prep_w1<<<(t1 + 255) / 256, 256, 0, stream>>>(W1, W1T, t1);
        int t2 = NL * W2ROWS * HS;
        k_prep_w2<<<(t2 + 255) / 256, 256, 0, stream>>>(W2, W2T, t2);
        int t3 = NL * HS;
        k_prep_params<<<(t3 + 255) / 256, 256, 0, stream>>>(b1, b2, bng, bnb, bnm, bnv,
                                                            b1p, scp, shp, t3);
    }

    // h0 (bf16)
    {
        int tt = N * (FS / 4);
        k_init_h0<<<(tt + 255) / 256, 256, 0, stream>>>(an, ch, ne0, ne1, Fb0, N);
    }

    // CSR by dst + categorical counts (hierarchical scan)
    hipMemsetAsync(deg, 0, (size_t)N * 4, stream);
    hipMemsetAsync(cbt, 0, (size_t)N * 6 * 4, stream);
    hipMemsetAsync(cbd, 0, (size_t)N * 3 * 4, stream);
    k_hist<<<(E + 255) / 256, 256, 0, stream>>>(dst, bt, bd, deg, cbt, cbd, E);
    k_scan_blk<<<nb, 256, 0, stream>>>(deg, incl, part, N);
    k_scan_part<<<1, 1024, 0, stream>>>(part, nb);
    k_scan_add<<<(N + 255) / 256, 256, 0, stream>>>(incl, part, deg, roff, curs, N);
    k_scatter<<<(E + 255) / 256, 256, 0, stream>>>(dst, src, curs, srcs, E);

    unsigned short* Fbc = Fb0;
    unsigned short* Fbo = Fb1;
    for (int l = 0; l < NL; ++l) {
        k_pool<<<(G + 3) / 4, 256, 0, stream>>>(Fbc, gid, (float*)d_out, N, G, l);
        k_aggregate<<<(N + 3) / 4, 256, 0, stream>>>(Fbc,
                                                     ee0 + (size_t)l * 6 * EMB,
                                                     ee1 + (size_t)l * 3 * EMB,
                                                     roff, srcs, cbt, cbd, A1, N);
        dim3 g1(MT, HS / 128);
        k_mm<0><<<g1, 256, 0, stream>>>(A1, FS, W1T + (size_t)l * HS * FS, FS,
                                        b1p + (size_t)l * HS, nullptr, Hb, HS, FS, HS);
        dim3 g2(MT, W2ROWS / 128);
        if (l < NL - 1)
            k_mm<1><<<g2, 256, 0, stream>>>(Hb, HS, W2T + (size_t)l * W2ROWS * HS, HS,
                                            scp + (size_t)l * FS, shp + (size_t)l * FS,
                                            Fbo, FS, HS, FS);
        else
            k_mm<2><<<g2, 256, 0, stream>>>(Hb, HS, W2T + (size_t)l * W2ROWS * HS, HS,
                                            scp + (size_t)l * FS, shp + (size_t)l * FS,
                                            Fbo, FS, HS, FS);
        unsigned short* t = Fbc; Fbc = Fbo; Fbo = t;
    }
    k_pool<<<(G + 3) / 4, 256, 0, stream>>>(Fbc, gid, (float*)d_out, N, G, NL);
}

// Round 5
// 876.665 us; speedup vs baseline: 3.9309x; 1.0837x over previous
//
#include <hip/hip_runtime.h>

#define EMB 300
#define HID 600
#define NL 5
#define BN_EPS 1e-5f

#define FS 320          // padded feature stride (300 -> 320)
#define HS 640          // padded hidden stride (600 -> 640)
#define W2ROWS 384      // padded n-rows for W2T (3 tiles of 128)

typedef __attribute__((ext_vector_type(8))) short short8;
typedef __attribute__((ext_vector_type(4))) float f32x4;
typedef __attribute__((ext_vector_type(4))) unsigned short us4;

__device__ __forceinline__ unsigned short f2bf(float x) {
    unsigned u = __float_as_uint(x);
    unsigned r = (u + 0x7FFFu + ((u >> 16) & 1u)) >> 16;   // RNE
    return (unsigned short)r;
}
__device__ __forceinline__ float bf2f(unsigned short h) {
    return __uint_as_float(((unsigned)h) << 16);
}

#define GLDS16(gsrc, ldst)                                                     \
    __builtin_amdgcn_global_load_lds(                                          \
        (const __attribute__((address_space(1))) unsigned int*)(gsrc),         \
        (__attribute__((address_space(3))) unsigned int*)(ldst), 16, 0, 0)

// ---------------- h0 = node_emb0[an] + node_emb1[ch] -> bf16, stride FS ----------------
__global__ void k_init_h0(const int* __restrict__ an, const int* __restrict__ ch,
                          const float* __restrict__ ne0, const float* __restrict__ ne1,
                          unsigned short* __restrict__ Fb, int n) {
    int t = blockIdx.x * blockDim.x + threadIdx.x;
    int i = t / (FS / 4), f4 = t - i * (FS / 4);
    if (i >= n) return;
    int f = f4 * 4;
    us4 h = {0, 0, 0, 0};
    if (f < EMB) {  // EMB=300 is a multiple of 4; rows are 16B-aligned
        const float4 a = *(const float4*)(ne0 + (size_t)an[i] * EMB + f);
        const float4 b = *(const float4*)(ne1 + (size_t)ch[i] * EMB + f);
        h[0] = f2bf(a.x + b.x); h[1] = f2bf(a.y + b.y);
        h[2] = f2bf(a.z + b.z); h[3] = f2bf(a.w + b.w);
    }
    *(us4*)(Fb + (size_t)i * FS + f) = h;
}

// ---------------- CSR build (by dst) + per-node categorical counts ----------------
__global__ void k_hist(const int* __restrict__ dst, const int* __restrict__ bt,
                       const int* __restrict__ bd, int* __restrict__ deg,
                       int* __restrict__ cbt, int* __restrict__ cbd, int e) {
    int t = blockIdx.x * blockDim.x + threadIdx.x;
    if (t >= e) return;
    int d = dst[t];
    atomicAdd(&deg[d], 1);
    atomicAdd(&cbt[d * 6 + bt[t]], 1);
    atomicAdd(&cbd[d * 3 + bd[t]], 1);
}

// ---- hierarchical scan: pass A (per-1024 block inclusive scan + block totals) ----
__global__ __launch_bounds__(256)
void k_scan_blk(const int* __restrict__ deg, int* __restrict__ incl,
                int* __restrict__ part, int n) {
    int tid = threadIdx.x;
    int base = blockIdx.x * 1024 + tid * 4;
    int v0 = (base + 0 < n) ? deg[base + 0] : 0;
    int v1 = (base + 1 < n) ? deg[base + 1] : 0;
    int v2 = (base + 2 < n) ? deg[base + 2] : 0;
    int v3 = (base + 3 < n) ? deg[base + 3] : 0;
    int ts = v0 + v1 + v2 + v3;
    int lane = tid & 63, w = tid >> 6;
    int x = ts;
#pragma unroll
    for (int off = 1; off < 64; off <<= 1) {
        int y = __shfl_up(x, off);
        if (lane >= off) x += y;
    }
    __shared__ int ws[4];
    if (lane == 63) ws[w] = x;
    __syncthreads();
    int woff = 0;
    for (int i = 0; i < w; ++i) woff += ws[i];
    int r = woff + x - ts;  // exclusive prefix for this thread
    r += v0; if (base + 0 < n) incl[base + 0] = r;
    r += v1; if (base + 1 < n) incl[base + 1] = r;
    r += v2; if (base + 2 < n) incl[base + 2] = r;
    r += v3; if (base + 3 < n) incl[base + 3] = r;
    if (tid == 255) part[blockIdx.x] = woff + x;  // block total
}

// ---- pass B: exclusive scan of block totals (single block, nb <= 1024) ----
__global__ __launch_bounds__(1024)
void k_scan_part(int* __restrict__ part, int nb) {
    int tid = threadIdx.x;
    int v = (tid < nb) ? part[tid] : 0;
    int lane = tid & 63, w = tid >> 6;
    int x = v;
#pragma unroll
    for (int off = 1; off < 64; off <<= 1) {
        int y = __shfl_up(x, off);
        if (lane >= off) x += y;
    }
    __shared__ int ws[16];
    if (lane == 63) ws[w] = x;
    __syncthreads();
    int woff = 0;
    for (int i = 0; i < w; ++i) woff += ws[i];
    if (tid < nb) part[tid] = woff + x - v;  // exclusive
}

// ---- pass C: row_off[i+1] = incl[i]+part; cursor[i] = row_off[i] ----
__global__ void k_scan_add(const int* __restrict__ incl, const int* __restrict__ part,
                           const int* __restrict__ deg, int* __restrict__ roff,
                           int* __restrict__ curs, int n) {
    int i = blockIdx.x * blockDim.x + threadIdx.x;
    if (i >= n) return;
    int inc = incl[i] + part[i >> 10];
    roff[i + 1] = inc;
    curs[i] = inc - deg[i];
    if (i == 0) roff[0] = 0;
}

__global__ void k_scatter(const int* __restrict__ dst, const int* __restrict__ src,
                          int* __restrict__ cursor, int* __restrict__ srcs, int e) {
    int t = blockIdx.x * blockDim.x + threadIdx.x;
    if (t < e) { int p = atomicAdd(&cursor[dst[t]], 1); srcs[p] = src[t]; }
}

// ---------------- weight prep: transpose + pad + bf16 ----------------
__global__ void k_prep_w1(const float* __restrict__ W1, unsigned short* __restrict__ W1T, int total) {
    int t = blockIdx.x * blockDim.x + threadIdx.x;
    if (t >= total) return;
    int k = t % FS, n = (t / FS) % HS, l = t / (FS * HS);
    W1T[t] = (n < HID && k < EMB) ? f2bf(W1[l * (EMB * HID) + k * HID + n]) : 0;
}

__global__ void k_prep_w2(const float* __restrict__ W2, unsigned short* __restrict__ W2T, int total) {
    int t = blockIdx.x * blockDim.x + threadIdx.x;
    if (t >= total) return;
    int k = t % HS, n = (t / HS) % W2ROWS, l = t / (HS * W2ROWS);
    W2T[t] = (n < EMB && k < HID) ? f2bf(W2[l * (HID * EMB) + k * EMB + n]) : 0;
}

__global__ void k_prep_params(const float* __restrict__ b1, const float* __restrict__ b2,
                              const float* __restrict__ g, const float* __restrict__ be,
                              const float* __restrict__ mu, const float* __restrict__ va,
                              float* __restrict__ b1p, float* __restrict__ scp,
                              float* __restrict__ shp, int total) {
    int t = blockIdx.x * blockDim.x + threadIdx.x;
    if (t >= total) return;
    int n = t % HS, l = t / HS;
    b1p[t] = (n < HID) ? b1[l * HID + n] : 0.f;
    if (n < FS) {
        float sc = 0.f, sh = 0.f;
        if (n < EMB) {
            sc = g[l * EMB + n] * rsqrtf(va[l * EMB + n] + BN_EPS);
            sh = be[l * EMB + n] + (b2[l * EMB + n] - mu[l * EMB + n]) * sc;
        }
        scp[l * FS + n] = sc;
        shp[l * FS + n] = sh;
    }
}

// ---------------- aggregation: vectorized us4 gather, fp32 accum, bf16 out ----------------
// lane l owns cols [4l,4l+4) (<256); lanes 0..15 additionally own cols [256+4l,256+4l+4)
__global__ __launch_bounds__(256)
void k_aggregate(const unsigned short* __restrict__ fb,  // [M_pad][FS] bf16
                 const float* __restrict__ e0,           // [6][EMB]
                 const float* __restrict__ e1,           // [3][EMB]
                 const int* __restrict__ row_off, const int* __restrict__ srcs,
                 const int* __restrict__ cbt, const int* __restrict__ cbd,
                 unsigned short* __restrict__ agg,       // [M_pad][FS] bf16
                 int n) {
    int v = blockIdx.x * 4 + (threadIdx.x >> 6);
    if (v >= n) return;
    int lane = threadIdx.x & 63;
    int s = row_off[v], e = row_off[v + 1];
    float aA[4] = {0.f, 0.f, 0.f, 0.f};
    float aB[4] = {0.f, 0.f, 0.f, 0.f};
    int j = s;
    for (; j + 1 < e; j += 2) {  // two independent gather chains
        const us4* r0 = (const us4*)(fb + (size_t)srcs[j] * FS);
        const us4* r1 = (const us4*)(fb + (size_t)srcs[j + 1] * FS);
        us4 x0 = r0[lane], x1 = r1[lane];
#pragma unroll
        for (int c = 0; c < 4; ++c) aA[c] += bf2f(x0[c]) + bf2f(x1[c]);
        if (lane < 16) {
            us4 y0 = r0[64 + lane], y1 = r1[64 + lane];
#pragma unroll
            for (int c = 0; c < 4; ++c) aB[c] += bf2f(y0[c]) + bf2f(y1[c]);
        }
    }
    if (j < e) {
        const us4* r0 = (const us4*)(fb + (size_t)srcs[j] * FS);
        us4 x0 = r0[lane];
#pragma unroll
        for (int c = 0; c < 4; ++c) aA[c] += bf2f(x0[c]);
        if (lane < 16) {
            us4 y0 = r0[64 + lane];
#pragma unroll
            for (int c = 0; c < 4; ++c) aB[c] += bf2f(y0[c]);
        }
    }
#pragma unroll
    for (int t = 0; t < 6; ++t) {
        int c = cbt[v * 6 + t];
        if (c) {
            float fc = (float)c;
            f32x4 ea = *(const f32x4*)(e0 + t * EMB + 4 * lane);        // cols < 256 < EMB
#pragma unroll
            for (int q = 0; q < 4; ++q) aA[q] += fc * ea[q];
            if (lane < 11) {                                            // cols 256..299 valid
                f32x4 eb = *(const f32x4*)(e0 + t * EMB + 256 + 4 * lane);
#pragma unroll
                for (int q = 0; q < 4; ++q) aB[q] += fc * eb[q];
            }
        }
    }
#pragma unroll
    for (int t = 0; t < 3; ++t) {
        int c = cbd[v * 3 + t];
        if (c) {
            float fc = (float)c;
            f32x4 ea = *(const f32x4*)(e1 + t * EMB + 4 * lane);
#pragma unroll
            for (int q = 0; q < 4; ++q) aA[q] += fc * ea[q];
            if (lane < 11) {
                f32x4 eb = *(const f32x4*)(e1 + t * EMB + 256 + 4 * lane);
#pragma unroll
                for (int q = 0; q < 4; ++q) aB[q] += fc * eb[q];
            }
        }
    }
    us4* ar = (us4*)(agg + (size_t)v * FS);
    us4 h;
#pragma unroll
    for (int c = 0; c < 4; ++c) h[c] = f2bf(aA[c]);
    ar[lane] = h;
    if (lane < 16) {  // lanes >= 11 hold zeros (feats pad is zero) -> pad stays zero
        us4 hb;
#pragma unroll
        for (int c = 0; c < 4; ++c) hb[c] = f2bf(aB[c]);
        ar[64 + lane] = hb;
    }
}

// ---------------- bf16 MFMA GEMM, 128x128 tile, BK=32, 4 waves ----------------
// 3-buffer LDS ring (48 KB -> 3 blocks/CU), counted vmcnt (next stage stays in
// flight across barriers), raw s_barrier, setprio around MFMA cluster.
// 1-D grid with XCD-chunked decode: a panel's NT column-blocks land on
// consecutive slots of the SAME XCD (d%8 round-robin) -> A-panel is L2-resident.
// EPI 0: relu(x + p0[n])       -> bf16
// EPI 1: x*p0[n] + p1[n], relu -> bf16
// EPI 2: x*p0[n] + p1[n]       -> bf16
template <int EPI>
__global__ __launch_bounds__(256)
void k_mm(const unsigned short* __restrict__ A, int lda,
          const unsigned short* __restrict__ Bt, int ldb,
          const float* __restrict__ p0, const float* __restrict__ p1,
          unsigned short* __restrict__ Cb, int ldc, int K, int Nlim,
          int MT, int NT) {
    // XCD-chunked decode
    const int d = blockIdx.x;
    const int xcd = d & 7, slot = d >> 3;
    const int pi = slot / NT, in = slot - pi * NT;
    const int im = pi * 8 + xcd;
    if (im >= MT) return;

    __shared__ unsigned short As[3][128 * 32];
    __shared__ unsigned short Bs[3][128 * 32];
    const int tid = threadIdx.x;
    const int lane = tid & 63, wid = tid >> 6;
    const int wm = wid >> 1, wn = wid & 1;
    const size_t bm = (size_t)im * 128;
    const int bn = in * 128;
    const int lr = lane & 15, lk = lane >> 4;
    const int srow = lane >> 2;          // staging: row within 16-row chunk
    const int scol = (lane & 3) * 8;     // staging: k-element offset
    f32x4 acc[4][4] = {};                // acc[i = n-frag][j = m-frag]

    const unsigned short* gA  = A + (bm + (size_t)(wid * 16 + srow)) * lda + scol;
    const unsigned short* gA2 = A + (bm + (size_t)((wid + 4) * 16 + srow)) * lda + scol;
    const unsigned short* gB  = Bt + (size_t)(bn + wid * 16 + srow) * ldb + scol;
    const unsigned short* gB2 = Bt + (size_t)(bn + (wid + 4) * 16 + srow) * ldb + scol;

    auto STAGE = [&](int buf, int k0) {   // 4 loads per wave
        GLDS16(gA  + k0, &As[buf][(wid * 16) * 32]);
        GLDS16(gA2 + k0, &As[buf][((wid + 4) * 16) * 32]);
        GLDS16(gB  + k0, &Bs[buf][(wid * 16) * 32]);
        GLDS16(gB2 + k0, &Bs[buf][((wid + 4) * 16) * 32]);
    };

    const int nt = K >> 5;
    STAGE(0, 0);
    if (nt > 1) STAGE(1, 32);

    for (int t = 0; t < nt; ++t) {
        // complete tile t's 4 loads; keep tile t+1's 4 in flight
        if (t + 1 < nt) asm volatile("s_waitcnt vmcnt(4)" ::: "memory");
        else            asm volatile("s_waitcnt vmcnt(0)" ::: "memory");
        __builtin_amdgcn_s_barrier();
        const int cur = t % 3;
        short8 a[4], b[4];
#pragma unroll
        for (int j = 0; j < 4; ++j)
            a[j] = *(const short8*)&As[cur][(wm * 64 + j * 16 + lr) * 32 + lk * 8];
#pragma unroll
        for (int i = 0; i < 4; ++i)
            b[i] = *(const short8*)&Bs[cur][(wn * 64 + i * 16 + lr) * 32 + lk * 8];
        // overwrites buf[(t-1)%3]: its readers' ds_reads completed before barrier t
        if (t + 2 < nt) STAGE((t + 2) % 3, (t + 2) * 32);
        __builtin_amdgcn_s_setprio(1);
#pragma unroll
        for (int i = 0; i < 4; ++i)
#pragma unroll
            for (int j = 0; j < 4; ++j)
                acc[i][j] = __builtin_amdgcn_mfma_f32_16x16x32_bf16(b[i], a[j], acc[i][j], 0, 0, 0);
        __builtin_amdgcn_s_setprio(0);
    }

    const int rgrp = (lane >> 4) * 4;
#pragma unroll
    for (int i = 0; i < 4; ++i) {
        const int n0 = bn + wn * 64 + i * 16 + rgrp;   // 4 consecutive n per lane
        if (EPI != 0 && n0 >= Nlim) continue;
        const f32x4 q0 = *(const f32x4*)&p0[n0];
        f32x4 q1 = {};
        if (EPI != 0) q1 = *(const f32x4*)&p1[n0];
#pragma unroll
        for (int j = 0; j < 4; ++j) {
            const size_t m = bm + (size_t)(wm * 64 + j * 16 + lr);
            us4 h;
#pragma unroll
            for (int p = 0; p < 4; ++p) {
                float x = (EPI == 0) ? (acc[i][j][p] + q0[p]) : (acc[i][j][p] * q0[p] + q1[p]);
                if (EPI != 2) x = fmaxf(x, 0.f);
                h[p] = f2bf(x);
            }
            *(us4*)(Cb + m * ldc + n0) = h;
        }
    }
}

// ---------------- per-graph pooling (one wave per graph, bf16 feats, us4 loads) ----------------
__global__ __launch_bounds__(256)
void k_pool(const unsigned short* __restrict__ feats, const int* __restrict__ gids,
            float* __restrict__ out, int n_nodes, int G, int l) {
    int g = blockIdx.x * 4 + (threadIdx.x >> 6);
    if (g >= G) return;
    int lane = threadIdx.x & 63;
    int lo = 0, hi = n_nodes;
    while (lo < hi) { int mid = (lo + hi) >> 1; if (gids[mid] < g) lo = mid + 1; else hi = mid; }
    int s = lo;
    hi = n_nodes;
    while (lo < hi) { int mid = (lo + hi) >> 1; if (gids[mid] < g + 1) lo = mid + 1; else hi = mid; }
    int e = lo;
    float aA[4] = {0.f, 0.f, 0.f, 0.f};
    float aB[4] = {0.f, 0.f, 0.f, 0.f};
    int v = s;
    for (; v + 1 < e; v += 2) {
        const us4* r0 = (const us4*)(feats + (size_t)v * FS);
        const us4* r1 = (const us4*)(feats + (size_t)(v + 1) * FS);
        us4 x0 = r0[lane], x1 = r1[lane];
#pragma unroll
        for (int c = 0; c < 4; ++c) aA[c] += bf2f(x0[c]) + bf2f(x1[c]);
        if (lane < 11) {
            us4 y0 = r0[64 + lane], y1 = r1[64 + lane];
#pragma unroll
            for (int c = 0; c < 4; ++c) aB[c] += bf2f(y0[c]) + bf2f(y1[c]);
        }
    }
    if (v < e) {
        const us4* r0 = (const us4*)(feats + (size_t)v * FS);
        us4 x0 = r0[lane];
#pragma unroll
        for (int c = 0; c < 4; ++c) aA[c] += bf2f(x0[c]);
        if (lane < 11) {
            us4 y0 = r0[64 + lane];
#pragma unroll
            for (int c = 0; c < 4; ++c) aB[c] += bf2f(y0[c]);
        }
    }
    float inv = 1.0f / (float)((e - s) > 0 ? (e - s) : 1);
    float* oavg = out + (size_t)g * (12 * EMB) + l * EMB;
    float* osum = oavg + 6 * EMB;
    f32x4 va, vs;
#pragma unroll
    for (int c = 0; c < 4; ++c) { vs[c] = aA[c]; va[c] = aA[c] * inv; }
    *(f32x4*)(oavg + 4 * lane) = va;   // cols 0..255, 16B-aligned
    *(f32x4*)(osum + 4 * lane) = vs;
    if (lane < 11) {                    // cols 256..299
#pragma unroll
        for (int c = 0; c < 4; ++c) { vs[c] = aB[c]; va[c] = aB[c] * inv; }
        *(f32x4*)(oavg + 256 + 4 * lane) = va;
        *(f32x4*)(osum + 256 + 4 * lane) = vs;
    }
}

extern "C" void kernel_launch(void* const* d_in, const int* in_sizes, int n_in,
                              void* d_out, int out_size, void* d_ws, size_t ws_size,
                              hipStream_t stream) {
    const int*   an  = (const int*)d_in[0];
    const int*   ch  = (const int*)d_in[1];
    const int*   bt  = (const int*)d_in[2];
    const int*   bd  = (const int*)d_in[3];
    const int*   src = (const int*)d_in[4];
    const int*   dst = (const int*)d_in[5];
    const int*   gid = (const int*)d_in[6];
    const float* ne0 = (const float*)d_in[8];
    const float* ne1 = (const float*)d_in[9];
    const float* ee0 = (const float*)d_in[10];
    const float* ee1 = (const float*)d_in[11];
    const float* W1  = (const float*)d_in[12];
    const float* b1  = (const float*)d_in[13];
    const float* W2  = (const float*)d_in[14];
    const float* b2  = (const float*)d_in[15];
    const float* bng = (const float*)d_in[16];
    const float* bnb = (const float*)d_in[17];
    const float* bnm = (const float*)d_in[18];
    const float* bnv = (const float*)d_in[19];

    const int N = in_sizes[0];
    const int E = in_sizes[2];
    const int G = out_size / (12 * EMB);
    const int M_pad = ((N + 127) / 128) * 128;
    const int MT = M_pad / 128;
    const int MT8 = ((MT + 7) / 8) * 8;     // panels padded to multiple of 8
    const int nb = (N + 1023) / 1024;

    char* ws = (char*)d_ws;
    size_t off = 0;
    auto alloc = [&](size_t bytes) -> void* {
        void* p = (void*)(ws + off);
        off += (bytes + 255) & ~(size_t)255;
        return p;
    };
    unsigned short* Fb0  = (unsigned short*)alloc((size_t)M_pad * FS * 2);  // bf16 feats ping
    unsigned short* Fb1  = (unsigned short*)alloc((size_t)M_pad * FS * 2);  // bf16 feats pong
    unsigned short* A1   = (unsigned short*)alloc((size_t)M_pad * FS * 2);  // agg (GEMM1 A)
    unsigned short* Hb   = (unsigned short*)alloc((size_t)M_pad * HS * 2);  // hidden (GEMM2 A)
    unsigned short* W1T  = (unsigned short*)alloc((size_t)NL * HS * FS * 2);
    unsigned short* W2T  = (unsigned short*)alloc((size_t)NL * W2ROWS * HS * 2);
    float*          b1p  = (float*)alloc((size_t)NL * HS * 4);
    float*          scp  = (float*)alloc((size_t)NL * FS * 4);
    float*          shp  = (float*)alloc((size_t)NL * FS * 4);
    int*            deg  = (int*)alloc((size_t)N * 4);
    int*            roff = (int*)alloc(((size_t)N + 1) * 4);
    int*            curs = (int*)alloc((size_t)N * 4);
    int*            srcs = (int*)alloc((size_t)E * 4);
    int*            cbt  = (int*)alloc((size_t)N * 6 * 4);
    int*            cbd  = (int*)alloc((size_t)N * 3 * 4);
    int*            incl = (int*)alloc((size_t)N * 4);
    int*            part = (int*)alloc((size_t)1024 * 4);

    // weight / param prep
    {
        int t1 = NL * HS * FS;
        k_prep_w1<<<(t1 + 255) / 256, 256, 0, stream>>>(W1, W1T, t1);
        int t2 = NL * W2ROWS * HS;
        k_prep_w2<<<(t2 + 255) / 256, 256, 0, stream>>>(W2, W2T, t2);
        int t3 = NL * HS;
        k_prep_params<<<(t3 + 255) / 256, 256, 0, stream>>>(b1, b2, bng, bnb, bnm, bnv,
                                                            b1p, scp, shp, t3);
    }

    // h0 (bf16)
    {
        int tt = N * (FS / 4);
        k_init_h0<<<(tt + 255) / 256, 256, 0, stream>>>(an, ch, ne0, ne1, Fb0, N);
    }

    // CSR by dst + categorical counts (hierarchical scan)
    hipMemsetAsync(deg, 0, (size_t)N * 4, stream);
    hipMemsetAsync(cbt, 0, (size_t)N * 6 * 4, stream);
    hipMemsetAsync(cbd, 0, (size_t)N * 3 * 4, stream);
    k_hist<<<(E + 255) / 256, 256, 0, stream>>>(dst, bt, bd, deg, cbt, cbd, E);
    k_scan_blk<<<nb, 256, 0, stream>>>(deg, incl, part, N);
    k_scan_part<<<1, 1024, 0, stream>>>(part, nb);
    k_scan_add<<<(N + 255) / 256, 256, 0, stream>>>(incl, part, deg, roff, curs, N);
    k_scatter<<<(E + 255) / 256, 256, 0, stream>>>(dst, src, curs, srcs, E);

    const int NT1 = HS / 128;       // 5
    const int NT2 = W2ROWS / 128;   // 3

    unsigned short* Fbc = Fb0;
    unsigned short* Fbo = Fb1;
    for (int l = 0; l < NL; ++l) {
        k_pool<<<(G + 3) / 4, 256, 0, stream>>>(Fbc, gid, (float*)d_out, N, G, l);
        k_aggregate<<<(N + 3) / 4, 256, 0, stream>>>(Fbc,
                                                     ee0 + (size_t)l * 6 * EMB,
                                                     ee1 + (size_t)l * 3 * EMB,
                                                     roff, srcs, cbt, cbd, A1, N);
        k_mm<0><<<MT8 * NT1, 256, 0, stream>>>(A1, FS, W1T + (size_t)l * HS * FS, FS,
                                               b1p + (size_t)l * HS, nullptr, Hb, HS,
                                               FS, HS, MT, NT1);
        if (l < NL - 1)
            k_mm<1><<<MT8 * NT2, 256, 0, stream>>>(Hb, HS, W2T + (size_t)l * W2ROWS * HS, HS,
                                                   scp + (size_t)l * FS, shp + (size_t)l * FS,
                                                   Fbo, FS, HS, FS, MT, NT2);
        else
            k_mm<2><<<MT8 * NT2, 256, 0, stream>>>(Hb, HS, W2T + (size_t)l * W2ROWS * HS, HS,
                                                   scp + (size_t)l * FS, shp + (size_t)l * FS,
                                                   Fbo, FS, HS, FS, MT, NT2);
        unsigned short* t = Fbc; Fbc = Fbo; Fbo = t;
    }
    k_pool<<<(G + 3) / 4, 256, 0, stream>>>(Fbc, gid, (float*)d_out, N, G, NL);
}

// Round 6
// 855.190 us; speedup vs baseline: 4.0296x; 1.0251x over previous
//
#include <hip/hip_runtime.h>

#define EMB 300
#define HID 600
#define NL 5
#define BN_EPS 1e-5f

#define FS 320          // padded feature stride (300 -> 320)
#define HS 640          // padded hidden stride (600 -> 640)
#define W2ROWS 384      // padded n-rows for W2T (3 tiles of 128)

typedef __attribute__((ext_vector_type(8))) short short8;
typedef __attribute__((ext_vector_type(4))) float f32x4;
typedef __attribute__((ext_vector_type(4))) unsigned short us4;

__device__ __forceinline__ unsigned short f2bf(float x) {
    unsigned u = __float_as_uint(x);
    unsigned r = (u + 0x7FFFu + ((u >> 16) & 1u)) >> 16;   // RNE
    return (unsigned short)r;
}
__device__ __forceinline__ float bf2f(unsigned short h) {
    return __uint_as_float(((unsigned)h) << 16);
}

#define GLDS16(gsrc, ldst)                                                     \
    __builtin_amdgcn_global_load_lds(                                          \
        (const __attribute__((address_space(1))) unsigned int*)(gsrc),         \
        (__attribute__((address_space(3))) unsigned int*)(ldst), 16, 0, 0)

// ---------------- h0 = node_emb0[an] + node_emb1[ch] -> bf16, stride FS ----------------
__global__ void k_init_h0(const int* __restrict__ an, const int* __restrict__ ch,
                          const float* __restrict__ ne0, const float* __restrict__ ne1,
                          unsigned short* __restrict__ Fb, int n) {
    int t = blockIdx.x * blockDim.x + threadIdx.x;
    int i = t / (FS / 4), f4 = t - i * (FS / 4);
    if (i >= n) return;
    int f = f4 * 4;
    us4 h = {0, 0, 0, 0};
    if (f < EMB) {  // EMB=300 is a multiple of 4; rows are 16B-aligned
        const float4 a = *(const float4*)(ne0 + (size_t)an[i] * EMB + f);
        const float4 b = *(const float4*)(ne1 + (size_t)ch[i] * EMB + f);
        h[0] = f2bf(a.x + b.x); h[1] = f2bf(a.y + b.y);
        h[2] = f2bf(a.z + b.z); h[3] = f2bf(a.w + b.w);
    }
    *(us4*)(Fb + (size_t)i * FS + f) = h;
}

// ---------------- CSR build (by dst) + per-node categorical counts ----------------
__global__ void k_hist(const int* __restrict__ dst, const int* __restrict__ bt,
                       const int* __restrict__ bd, int* __restrict__ deg,
                       int* __restrict__ cbt, int* __restrict__ cbd, int e) {
    int t = blockIdx.x * blockDim.x + threadIdx.x;
    if (t >= e) return;
    int d = dst[t];
    atomicAdd(&deg[d], 1);
    atomicAdd(&cbt[d * 6 + bt[t]], 1);
    atomicAdd(&cbd[d * 3 + bd[t]], 1);
}

// ---- hierarchical scan: pass A (per-1024 block inclusive scan + block totals) ----
__global__ __launch_bounds__(256)
void k_scan_blk(const int* __restrict__ deg, int* __restrict__ incl,
                int* __restrict__ part, int n) {
    int tid = threadIdx.x;
    int base = blockIdx.x * 1024 + tid * 4;
    int v0 = (base + 0 < n) ? deg[base + 0] : 0;
    int v1 = (base + 1 < n) ? deg[base + 1] : 0;
    int v2 = (base + 2 < n) ? deg[base + 2] : 0;
    int v3 = (base + 3 < n) ? deg[base + 3] : 0;
    int ts = v0 + v1 + v2 + v3;
    int lane = tid & 63, w = tid >> 6;
    int x = ts;
#pragma unroll
    for (int off = 1; off < 64; off <<= 1) {
        int y = __shfl_up(x, off);
        if (lane >= off) x += y;
    }
    __shared__ int ws[4];
    if (lane == 63) ws[w] = x;
    __syncthreads();
    int woff = 0;
    for (int i = 0; i < w; ++i) woff += ws[i];
    int r = woff + x - ts;  // exclusive prefix for this thread
    r += v0; if (base + 0 < n) incl[base + 0] = r;
    r += v1; if (base + 1 < n) incl[base + 1] = r;
    r += v2; if (base + 2 < n) incl[base + 2] = r;
    r += v3; if (base + 3 < n) incl[base + 3] = r;
    if (tid == 255) part[blockIdx.x] = woff + x;  // block total
}

// ---- pass B: exclusive scan of block totals (single block, nb <= 1024) ----
__global__ __launch_bounds__(1024)
void k_scan_part(int* __restrict__ part, int nb) {
    int tid = threadIdx.x;
    int v = (tid < nb) ? part[tid] : 0;
    int lane = tid & 63, w = tid >> 6;
    int x = v;
#pragma unroll
    for (int off = 1; off < 64; off <<= 1) {
        int y = __shfl_up(x, off);
        if (lane >= off) x += y;
    }
    __shared__ int ws[16];
    if (lane == 63) ws[w] = x;
    __syncthreads();
    int woff = 0;
    for (int i = 0; i < w; ++i) woff += ws[i];
    if (tid < nb) part[tid] = woff + x - v;  // exclusive
}

// ---- pass C: row_off[i+1] = incl[i]+part; cursor[i] = row_off[i] ----
__global__ void k_scan_add(const int* __restrict__ incl, const int* __restrict__ part,
                           const int* __restrict__ deg, int* __restrict__ roff,
                           int* __restrict__ curs, int n) {
    int i = blockIdx.x * blockDim.x + threadIdx.x;
    if (i >= n) return;
    int inc = incl[i] + part[i >> 10];
    roff[i + 1] = inc;
    curs[i] = inc - deg[i];
    if (i == 0) roff[0] = 0;
}

__global__ void k_scatter(const int* __restrict__ dst, const int* __restrict__ src,
                          int* __restrict__ cursor, int* __restrict__ srcs, int e) {
    int t = blockIdx.x * blockDim.x + threadIdx.x;
    if (t < e) { int p = atomicAdd(&cursor[dst[t]], 1); srcs[p] = src[t]; }
}

// ---------------- weight prep: transpose + pad + bf16 ----------------
__global__ void k_prep_w1(const float* __restrict__ W1, unsigned short* __restrict__ W1T, int total) {
    int t = blockIdx.x * blockDim.x + threadIdx.x;
    if (t >= total) return;
    int k = t % FS, n = (t / FS) % HS, l = t / (FS * HS);
    W1T[t] = (n < HID && k < EMB) ? f2bf(W1[l * (EMB * HID) + k * HID + n]) : 0;
}

__global__ void k_prep_w2(const float* __restrict__ W2, unsigned short* __restrict__ W2T, int total) {
    int t = blockIdx.x * blockDim.x + threadIdx.x;
    if (t >= total) return;
    int k = t % HS, n = (t / HS) % W2ROWS, l = t / (HS * W2ROWS);
    W2T[t] = (n < EMB && k < HID) ? f2bf(W2[l * (HID * EMB) + k * EMB + n]) : 0;
}

__global__ void k_prep_params(const float* __restrict__ b1, const float* __restrict__ b2,
                              const float* __restrict__ g, const float* __restrict__ be,
                              const float* __restrict__ mu, const float* __restrict__ va,
                              float* __restrict__ b1p, float* __restrict__ scp,
                              float* __restrict__ shp, int total) {
    int t = blockIdx.x * blockDim.x + threadIdx.x;
    if (t >= total) return;
    int n = t % HS, l = t / HS;
    b1p[t] = (n < HID) ? b1[l * HID + n] : 0.f;
    if (n < FS) {
        float sc = 0.f, sh = 0.f;
        if (n < EMB) {
            sc = g[l * EMB + n] * rsqrtf(va[l * EMB + n] + BN_EPS);
            sh = be[l * EMB + n] + (b2[l * EMB + n] - mu[l * EMB + n]) * sc;
        }
        scp[l * FS + n] = sc;
        shp[l * FS + n] = sh;
    }
}

// ---------------- aggregation: 4-deep pipelined us4 gather, fp32 accum, bf16 out ----------------
// lane l owns cols [4l,4l+4) (<256); lanes 0..15 additionally own cols [256+4l,..)
__global__ __launch_bounds__(256)
void k_aggregate(const unsigned short* __restrict__ fb,  // [M_pad][FS] bf16
                 const float* __restrict__ e0,           // [6][EMB]
                 const float* __restrict__ e1,           // [3][EMB]
                 const int* __restrict__ row_off, const int* __restrict__ srcs,
                 const int* __restrict__ cbt, const int* __restrict__ cbd,
                 unsigned short* __restrict__ agg,       // [M_pad][FS] bf16
                 int n) {
    int v = blockIdx.x * 4 + (threadIdx.x >> 6);
    if (v >= n) return;
    int lane = threadIdx.x & 63;
    int s = row_off[v], e = row_off[v + 1];
    const int deg = e - s;
    const int* sp = srcs + s;
    const bool lo = (lane < 16);
    float aA[4] = {0.f, 0.f, 0.f, 0.f};
    float aB[4] = {0.f, 0.f, 0.f, 0.f};
    int j = 0;
    for (; j + 4 <= deg; j += 4) {   // 4 rows in flight: 8 full-wave + 4 quarter-wave loads
        int i0 = sp[j], i1 = sp[j + 1], i2 = sp[j + 2], i3 = sp[j + 3];
        const us4* r0 = (const us4*)(fb + (size_t)i0 * FS);
        const us4* r1 = (const us4*)(fb + (size_t)i1 * FS);
        const us4* r2 = (const us4*)(fb + (size_t)i2 * FS);
        const us4* r3 = (const us4*)(fb + (size_t)i3 * FS);
        us4 x0 = r0[lane], x1 = r1[lane], x2 = r2[lane], x3 = r3[lane];
        us4 y0 = {}, y1 = {}, y2 = {}, y3 = {};
        if (lo) { y0 = r0[64 + lane]; y1 = r1[64 + lane]; y2 = r2[64 + lane]; y3 = r3[64 + lane]; }
#pragma unroll
        for (int c = 0; c < 4; ++c)
            aA[c] += (bf2f(x0[c]) + bf2f(x1[c])) + (bf2f(x2[c]) + bf2f(x3[c]));
        if (lo) {
#pragma unroll
            for (int c = 0; c < 4; ++c)
                aB[c] += (bf2f(y0[c]) + bf2f(y1[c])) + (bf2f(y2[c]) + bf2f(y3[c]));
        }
    }
    for (; j < deg; ++j) {
        const us4* r0 = (const us4*)(fb + (size_t)sp[j] * FS);
        us4 x0 = r0[lane];
#pragma unroll
        for (int c = 0; c < 4; ++c) aA[c] += bf2f(x0[c]);
        if (lo) {
            us4 y0 = r0[64 + lane];
#pragma unroll
            for (int c = 0; c < 4; ++c) aB[c] += bf2f(y0[c]);
        }
    }
#pragma unroll
    for (int t = 0; t < 6; ++t) {
        int c = cbt[v * 6 + t];
        if (c) {
            float fc = (float)c;
            f32x4 ea = *(const f32x4*)(e0 + t * EMB + 4 * lane);        // cols < 256 < EMB
#pragma unroll
            for (int q = 0; q < 4; ++q) aA[q] += fc * ea[q];
            if (lane < 11) {                                            // cols 256..299 valid
                f32x4 eb = *(const f32x4*)(e0 + t * EMB + 256 + 4 * lane);
#pragma unroll
                for (int q = 0; q < 4; ++q) aB[q] += fc * eb[q];
            }
        }
    }
#pragma unroll
    for (int t = 0; t < 3; ++t) {
        int c = cbd[v * 3 + t];
        if (c) {
            float fc = (float)c;
            f32x4 ea = *(const f32x4*)(e1 + t * EMB + 4 * lane);
#pragma unroll
            for (int q = 0; q < 4; ++q) aA[q] += fc * ea[q];
            if (lane < 11) {
                f32x4 eb = *(const f32x4*)(e1 + t * EMB + 256 + 4 * lane);
#pragma unroll
                for (int q = 0; q < 4; ++q) aB[q] += fc * eb[q];
            }
        }
    }
    us4* ar = (us4*)(agg + (size_t)v * FS);
    us4 h;
#pragma unroll
    for (int c = 0; c < 4; ++c) h[c] = f2bf(aA[c]);
    ar[lane] = h;
    if (lo) {  // lanes >= 11 hold zeros (feats pad is zero) -> pad stays zero
        us4 hb;
#pragma unroll
        for (int c = 0; c < 4; ++c) hb[c] = f2bf(aB[c]);
        ar[64 + lane] = hb;
    }
}

// ---------------- bf16 MFMA GEMM, 128x128 tile, BK=32, 4 waves ----------------
// 3-buffer LDS ring (48 KB -> 3 blocks/CU), counted vmcnt, raw s_barrier,
// setprio around MFMA cluster, XCD-chunked 1-D grid decode (panel L2 locality).
template <int EPI>
__global__ __launch_bounds__(256)
void k_mm(const unsigned short* __restrict__ A, int lda,
          const unsigned short* __restrict__ Bt, int ldb,
          const float* __restrict__ p0, const float* __restrict__ p1,
          unsigned short* __restrict__ Cb, int ldc, int K, int Nlim,
          int MT, int NT) {
    const int d = blockIdx.x;
    const int xcd = d & 7, slot = d >> 3;
    const int pi = slot / NT, in = slot - pi * NT;
    const int im = pi * 8 + xcd;
    if (im >= MT) return;

    __shared__ unsigned short As[3][128 * 32];
    __shared__ unsigned short Bs[3][128 * 32];
    const int tid = threadIdx.x;
    const int lane = tid & 63, wid = tid >> 6;
    const int wm = wid >> 1, wn = wid & 1;
    const size_t bm = (size_t)im * 128;
    const int bn = in * 128;
    const int lr = lane & 15, lk = lane >> 4;
    const int srow = lane >> 2;          // staging: row within 16-row chunk
    const int scol = (lane & 3) * 8;     // staging: k-element offset
    f32x4 acc[4][4] = {};                // acc[i = n-frag][j = m-frag]

    const unsigned short* gA  = A + (bm + (size_t)(wid * 16 + srow)) * lda + scol;
    const unsigned short* gA2 = A + (bm + (size_t)((wid + 4) * 16 + srow)) * lda + scol;
    const unsigned short* gB  = Bt + (size_t)(bn + wid * 16 + srow) * ldb + scol;
    const unsigned short* gB2 = Bt + (size_t)(bn + (wid + 4) * 16 + srow) * ldb + scol;

    auto STAGE = [&](int buf, int k0) {   // 4 loads per wave
        GLDS16(gA  + k0, &As[buf][(wid * 16) * 32]);
        GLDS16(gA2 + k0, &As[buf][((wid + 4) * 16) * 32]);
        GLDS16(gB  + k0, &Bs[buf][(wid * 16) * 32]);
        GLDS16(gB2 + k0, &Bs[buf][((wid + 4) * 16) * 32]);
    };

    const int nt = K >> 5;
    STAGE(0, 0);
    if (nt > 1) STAGE(1, 32);

    for (int t = 0; t < nt; ++t) {
        // complete tile t's 4 loads; keep tile t+1's 4 in flight
        if (t + 1 < nt) asm volatile("s_waitcnt vmcnt(4)" ::: "memory");
        else            asm volatile("s_waitcnt vmcnt(0)" ::: "memory");
        __builtin_amdgcn_s_barrier();
        const int cur = t % 3;
        short8 a[4], b[4];
#pragma unroll
        for (int j = 0; j < 4; ++j)
            a[j] = *(const short8*)&As[cur][(wm * 64 + j * 16 + lr) * 32 + lk * 8];
#pragma unroll
        for (int i = 0; i < 4; ++i)
            b[i] = *(const short8*)&Bs[cur][(wn * 64 + i * 16 + lr) * 32 + lk * 8];
        // overwrites buf[(t-1)%3]: its readers' ds_reads completed before barrier t
        if (t + 2 < nt) STAGE((t + 2) % 3, (t + 2) * 32);
        __builtin_amdgcn_s_setprio(1);
#pragma unroll
        for (int i = 0; i < 4; ++i)
#pragma unroll
            for (int j = 0; j < 4; ++j)
                acc[i][j] = __builtin_amdgcn_mfma_f32_16x16x32_bf16(b[i], a[j], acc[i][j], 0, 0, 0);
        __builtin_amdgcn_s_setprio(0);
    }

    const int rgrp = (lane >> 4) * 4;
#pragma unroll
    for (int i = 0; i < 4; ++i) {
        const int n0 = bn + wn * 64 + i * 16 + rgrp;   // 4 consecutive n per lane
        if (EPI != 0 && n0 >= Nlim) continue;
        const f32x4 q0 = *(const f32x4*)&p0[n0];
        f32x4 q1 = {};
        if (EPI != 0) q1 = *(const f32x4*)&p1[n0];
#pragma unroll
        for (int j = 0; j < 4; ++j) {
            const size_t m = bm + (size_t)(wm * 64 + j * 16 + lr);
            us4 h;
#pragma unroll
            for (int p = 0; p < 4; ++p) {
                float x = (EPI == 0) ? (acc[i][j][p] + q0[p]) : (acc[i][j][p] * q0[p] + q1[p]);
                if (EPI != 2) x = fmaxf(x, 0.f);
                h[p] = f2bf(x);
            }
            *(us4*)(Cb + m * ldc + n0) = h;
        }
    }
}

// ---------------- per-graph pooling (one wave per graph, 4-deep us4 loads) ----------------
__global__ __launch_bounds__(256)
void k_pool(const unsigned short* __restrict__ feats, const int* __restrict__ gids,
            float* __restrict__ out, int n_nodes, int G, int l) {
    int g = blockIdx.x * 4 + (threadIdx.x >> 6);
    if (g >= G) return;
    int lane = threadIdx.x & 63;
    int lo = 0, hi = n_nodes;
    while (lo < hi) { int mid = (lo + hi) >> 1; if (gids[mid] < g) lo = mid + 1; else hi = mid; }
    int s = lo;
    hi = n_nodes;
    while (lo < hi) { int mid = (lo + hi) >> 1; if (gids[mid] < g + 1) lo = mid + 1; else hi = mid; }
    int e = lo;
    const bool lo16 = (lane < 11);
    float aA[4] = {0.f, 0.f, 0.f, 0.f};
    float aB[4] = {0.f, 0.f, 0.f, 0.f};
    int v = s;
    for (; v + 4 <= e; v += 4) {
        const us4* r0 = (const us4*)(feats + (size_t)v * FS);
        const us4* r1 = (const us4*)(feats + (size_t)(v + 1) * FS);
        const us4* r2 = (const us4*)(feats + (size_t)(v + 2) * FS);
        const us4* r3 = (const us4*)(feats + (size_t)(v + 3) * FS);
        us4 x0 = r0[lane], x1 = r1[lane], x2 = r2[lane], x3 = r3[lane];
        us4 y0 = {}, y1 = {}, y2 = {}, y3 = {};
        if (lo16) { y0 = r0[64 + lane]; y1 = r1[64 + lane]; y2 = r2[64 + lane]; y3 = r3[64 + lane]; }
#pragma unroll
        for (int c = 0; c < 4; ++c)
            aA[c] += (bf2f(x0[c]) + bf2f(x1[c])) + (bf2f(x2[c]) + bf2f(x3[c]));
        if (lo16) {
#pragma unroll
            for (int c = 0; c < 4; ++c)
                aB[c] += (bf2f(y0[c]) + bf2f(y1[c])) + (bf2f(y2[c]) + bf2f(y3[c]));
        }
    }
    for (; v < e; ++v) {
        const us4* r0 = (const us4*)(feats + (size_t)v * FS);
        us4 x0 = r0[lane];
#pragma unroll
        for (int c = 0; c < 4; ++c) aA[c] += bf2f(x0[c]);
        if (lo16) {
            us4 y0 = r0[64 + lane];
#pragma unroll
            for (int c = 0; c < 4; ++c) aB[c] += bf2f(y0[c]);
        }
    }
    float inv = 1.0f / (float)((e - s) > 0 ? (e - s) : 1);
    float* oavg = out + (size_t)g * (12 * EMB) + l * EMB;
    float* osum = oavg + 6 * EMB;
    f32x4 va, vs;
#pragma unroll
    for (int c = 0; c < 4; ++c) { vs[c] = aA[c]; va[c] = aA[c] * inv; }
    *(f32x4*)(oavg + 4 * lane) = va;   // cols 0..255, 16B-aligned
    *(f32x4*)(osum + 4 * lane) = vs;
    if (lo16) {                         // cols 256..299
#pragma unroll
        for (int c = 0; c < 4; ++c) { vs[c] = aB[c]; va[c] = aB[c] * inv; }
        *(f32x4*)(oavg + 256 + 4 * lane) = va;
        *(f32x4*)(osum + 256 + 4 * lane) = vs;
    }
}

extern "C" void kernel_launch(void* const* d_in, const int* in_sizes, int n_in,
                              void* d_out, int out_size, void* d_ws, size_t ws_size,
                              hipStream_t stream) {
    const int*   an  = (const int*)d_in[0];
    const int*   ch  = (const int*)d_in[1];
    const int*   bt  = (const int*)d_in[2];
    const int*   bd  = (const int*)d_in[3];
    const int*   src = (const int*)d_in[4];
    const int*   dst = (const int*)d_in[5];
    const int*   gid = (const int*)d_in[6];
    const float* ne0 = (const float*)d_in[8];
    const float* ne1 = (const float*)d_in[9];
    const float* ee0 = (const float*)d_in[10];
    const float* ee1 = (const float*)d_in[11];
    const float* W1  = (const float*)d_in[12];
    const float* b1  = (const float*)d_in[13];
    const float* W2  = (const float*)d_in[14];
    const float* b2  = (const float*)d_in[15];
    const float* bng = (const float*)d_in[16];
    const float* bnb = (const float*)d_in[17];
    const float* bnm = (const float*)d_in[18];
    const float* bnv = (const float*)d_in[19];

    const int N = in_sizes[0];
    const int E = in_sizes[2];
    const int G = out_size / (12 * EMB);
    const int M_pad = ((N + 127) / 128) * 128;
    const int MT = M_pad / 128;
    const int MT8 = ((MT + 7) / 8) * 8;     // panels padded to multiple of 8
    const int nb = (N + 1023) / 1024;

    char* ws = (char*)d_ws;
    size_t off = 0;
    auto alloc = [&](size_t bytes) -> void* {
        void* p = (void*)(ws + off);
        off += (bytes + 255) & ~(size_t)255;
        return p;
    };
    unsigned short* Fb0  = (unsigned short*)alloc((size_t)M_pad * FS * 2);  // bf16 feats ping
    unsigned short* Fb1  = (unsigned short*)alloc((size_t)M_pad * FS * 2);  // bf16 feats pong
    unsigned short* A1   = (unsigned short*)alloc((size_t)M_pad * FS * 2);  // agg (GEMM1 A)
    unsigned short* Hb   = (unsigned short*)alloc((size_t)M_pad * HS * 2);  // hidden (GEMM2 A)
    unsigned short* W1T  = (unsigned short*)alloc((size_t)NL * HS * FS * 2);
    unsigned short* W2T  = (unsigned short*)alloc((size_t)NL * W2ROWS * HS * 2);
    float*          b1p  = (float*)alloc((size_t)NL * HS * 4);
    float*          scp  = (float*)alloc((size_t)NL * FS * 4);
    float*          shp  = (float*)alloc((size_t)NL * FS * 4);
    int*            deg  = (int*)alloc((size_t)N * 4);
    int*            roff = (int*)alloc(((size_t)N + 1) * 4);
    int*            curs = (int*)alloc((size_t)N * 4);
    int*            srcs = (int*)alloc((size_t)E * 4);
    int*            cbt  = (int*)alloc((size_t)N * 6 * 4);
    int*            cbd  = (int*)alloc((size_t)N * 3 * 4);
    int*            incl = (int*)alloc((size_t)N * 4);
    int*            part = (int*)alloc((size_t)1024 * 4);

    // weight / param prep
    {
        int t1 = NL * HS * FS;
        k_prep_w1<<<(t1 + 255) / 256, 256, 0, stream>>>(W1, W1T, t1);
        int t2 = NL * W2ROWS * HS;
        k_prep_w2<<<(t2 + 255) / 256, 256, 0, stream>>>(W2, W2T, t2);
        int t3 = NL * HS;
        k_prep_params<<<(t3 + 255) / 256, 256, 0, stream>>>(b1, b2, bng, bnb, bnm, bnv,
                                                            b1p, scp, shp, t3);
    }

    // h0 (bf16)
    {
        int tt = N * (FS / 4);
        k_init_h0<<<(tt + 255) / 256, 256, 0, stream>>>(an, ch, ne0, ne1, Fb0, N);
    }

    // CSR by dst + categorical counts (hierarchical scan)
    hipMemsetAsync(deg, 0, (size_t)N * 4, stream);
    hipMemsetAsync(cbt, 0, (size_t)N * 6 * 4, stream);
    hipMemsetAsync(cbd, 0, (size_t)N * 3 * 4, stream);
    k_hist<<<(E + 255) / 256, 256, 0, stream>>>(dst, bt, bd, deg, cbt, cbd, E);
    k_scan_blk<<<nb, 256, 0, stream>>>(deg, incl, part, N);
    k_scan_part<<<1, 1024, 0, stream>>>(part, nb);
    k_scan_add<<<(N + 255) / 256, 256, 0, stream>>>(incl, part, deg, roff, curs, N);
    k_scatter<<<(E + 255) / 256, 256, 0, stream>>>(dst, src, curs, srcs, E);

    const int NT1 = HS / 128;       // 5
    const int NT2 = W2ROWS / 128;   // 3

    unsigned short* Fbc = Fb0;
    unsigned short* Fbo = Fb1;
    for (int l = 0; l < NL; ++l) {
        k_pool<<<(G + 3) / 4, 256, 0, stream>>>(Fbc, gid, (float*)d_out, N, G, l);
        k_aggregate<<<(N + 3) / 4, 256, 0, stream>>>(Fbc,
                                                     ee0 + (size_t)l * 6 * EMB,
                                                     ee1 + (size_t)l * 3 * EMB,
                                                     roff, srcs, cbt, cbd, A1, N);
        k_mm<0><<<MT8 * NT1, 256, 0, stream>>>(A1, FS, W1T + (size_t)l * HS * FS, FS,
                                               b1p + (size_t)l * HS, nullptr, Hb, HS,
                                               FS, HS, MT, NT1);
        if (l < NL - 1)
            k_mm<1><<<MT8 * NT2, 256, 0, stream>>>(Hb, HS, W2T + (size_t)l * W2ROWS * HS, HS,
                                                   scp + (size_t)l * FS, shp + (size_t)l * FS,
                                                   Fbo, FS, HS, FS, MT, NT2);
        else
            k_mm<2><<<MT8 * NT2, 256, 0, stream>>>(Hb, HS, W2T + (size_t)l * W2ROWS * HS, HS,
                                                   scp + (size_t)l * FS, shp + (size_t)l * FS,
                                                   Fbo, FS, HS, FS, MT, NT2);
        unsigned short* t = Fbc; Fbc = Fbo; Fbo = t;
    }
    k_pool<<<(G + 3) / 4, 256, 0, stream>>>(Fbc, gid, (float*)d_out, N, G, NL);
}

// Round 7
// 767.486 us; speedup vs baseline: 4.4901x; 1.1143x over previous
//
#include <hip/hip_runtime.h>

#define EMB 300
#define HID 600
#define NL 5
#define BN_EPS 1e-5f

#define FS 320          // padded feature stride (300 -> 320)
#define HS 640          // padded hidden stride (600 -> 640)
#define W2ROWS 384      // padded n-rows for W2T (3 tiles of 128)
#define NPW 8           // nodes per wave in k_aggregate

typedef __attribute__((ext_vector_type(8))) short short8;
typedef __attribute__((ext_vector_type(4))) float f32x4;
typedef __attribute__((ext_vector_type(4))) unsigned short us4;

__device__ __forceinline__ unsigned short f2bf(float x) {
    unsigned u = __float_as_uint(x);
    unsigned r = (u + 0x7FFFu + ((u >> 16) & 1u)) >> 16;   // RNE
    return (unsigned short)r;
}
__device__ __forceinline__ float bf2f(unsigned short h) {
    return __uint_as_float(((unsigned)h) << 16);
}

#define GLDS16(gsrc, ldst)                                                     \
    __builtin_amdgcn_global_load_lds(                                          \
        (const __attribute__((address_space(1))) unsigned int*)(gsrc),         \
        (__attribute__((address_space(3))) unsigned int*)(ldst), 16, 0, 0)

// ---------------- h0 = node_emb0[an] + node_emb1[ch] -> bf16, stride FS ----------------
__global__ void k_init_h0(const int* __restrict__ an, const int* __restrict__ ch,
                          const float* __restrict__ ne0, const float* __restrict__ ne1,
                          unsigned short* __restrict__ Fb, int n) {
    int t = blockIdx.x * blockDim.x + threadIdx.x;
    int i = t / (FS / 4), f4 = t - i * (FS / 4);
    if (i >= n) return;
    int f = f4 * 4;
    us4 h = {0, 0, 0, 0};
    if (f < EMB) {  // EMB=300 is a multiple of 4; rows are 16B-aligned
        const float4 a = *(const float4*)(ne0 + (size_t)an[i] * EMB + f);
        const float4 b = *(const float4*)(ne1 + (size_t)ch[i] * EMB + f);
        h[0] = f2bf(a.x + b.x); h[1] = f2bf(a.y + b.y);
        h[2] = f2bf(a.z + b.z); h[3] = f2bf(a.w + b.w);
    }
    *(us4*)(Fb + (size_t)i * FS + f) = h;
}

// ---------------- CSR build (by dst) + per-node categorical counts [N][9] ----------------
__global__ void k_hist(const int* __restrict__ dst, const int* __restrict__ bt,
                       const int* __restrict__ bd, int* __restrict__ deg,
                       int* __restrict__ cnt9, int e) {
    int t = blockIdx.x * blockDim.x + threadIdx.x;
    if (t >= e) return;
    int d = dst[t];
    atomicAdd(&deg[d], 1);
    atomicAdd(&cnt9[d * 9 + bt[t]], 1);
    atomicAdd(&cnt9[d * 9 + 6 + bd[t]], 1);
}

// ---- hierarchical scan: pass A (per-1024 block inclusive scan + block totals) ----
__global__ __launch_bounds__(256)
void k_scan_blk(const int* __restrict__ deg, int* __restrict__ incl,
                int* __restrict__ part, int n) {
    int tid = threadIdx.x;
    int base = blockIdx.x * 1024 + tid * 4;
    int v0 = (base + 0 < n) ? deg[base + 0] : 0;
    int v1 = (base + 1 < n) ? deg[base + 1] : 0;
    int v2 = (base + 2 < n) ? deg[base + 2] : 0;
    int v3 = (base + 3 < n) ? deg[base + 3] : 0;
    int ts = v0 + v1 + v2 + v3;
    int lane = tid & 63, w = tid >> 6;
    int x = ts;
#pragma unroll
    for (int off = 1; off < 64; off <<= 1) {
        int y = __shfl_up(x, off);
        if (lane >= off) x += y;
    }
    __shared__ int ws[4];
    if (lane == 63) ws[w] = x;
    __syncthreads();
    int woff = 0;
    for (int i = 0; i < w; ++i) woff += ws[i];
    int r = woff + x - ts;  // exclusive prefix for this thread
    r += v0; if (base + 0 < n) incl[base + 0] = r;
    r += v1; if (base + 1 < n) incl[base + 1] = r;
    r += v2; if (base + 2 < n) incl[base + 2] = r;
    r += v3; if (base + 3 < n) incl[base + 3] = r;
    if (tid == 255) part[blockIdx.x] = woff + x;  // block total
}

// ---- pass B: exclusive scan of block totals (single block, nb <= 1024) ----
__global__ __launch_bounds__(1024)
void k_scan_part(int* __restrict__ part, int nb) {
    int tid = threadIdx.x;
    int v = (tid < nb) ? part[tid] : 0;
    int lane = tid & 63, w = tid >> 6;
    int x = v;
#pragma unroll
    for (int off = 1; off < 64; off <<= 1) {
        int y = __shfl_up(x, off);
        if (lane >= off) x += y;
    }
    __shared__ int ws[16];
    if (lane == 63) ws[w] = x;
    __syncthreads();
    int woff = 0;
    for (int i = 0; i < w; ++i) woff += ws[i];
    if (tid < nb) part[tid] = woff + x - v;  // exclusive
}

// ---- pass C: row_off[i+1] = incl[i]+part; cursor[i] = row_off[i] ----
__global__ void k_scan_add(const int* __restrict__ incl, const int* __restrict__ part,
                           const int* __restrict__ deg, int* __restrict__ roff,
                           int* __restrict__ curs, int n) {
    int i = blockIdx.x * blockDim.x + threadIdx.x;
    if (i >= n) return;
    int inc = incl[i] + part[i >> 10];
    roff[i + 1] = inc;
    curs[i] = inc - deg[i];
    if (i == 0) roff[0] = 0;
}

__global__ void k_scatter(const int* __restrict__ dst, const int* __restrict__ src,
                          int* __restrict__ cursor, int* __restrict__ srcs, int e) {
    int t = blockIdx.x * blockDim.x + threadIdx.x;
    if (t < e) { int p = atomicAdd(&cursor[dst[t]], 1); srcs[p] = src[t]; }
}

// ---- graph boundaries: gstart[g] = first node index with gids >= g; gstart[G] = n ----
__global__ void k_gbound(const int* __restrict__ gids, int* __restrict__ gstart,
                         int n, int G) {
    int i = blockIdx.x * blockDim.x + threadIdx.x;
    if (i >= n) return;
    int g = gids[i];
    int gp = (i == 0) ? -1 : gids[i - 1];
    for (int q = gp + 1; q <= g; ++q) gstart[q] = i;
    if (i == n - 1)
        for (int q = g + 1; q <= G; ++q) gstart[q] = n;
}

// ---------------- weight prep: transpose + pad + bf16 ----------------
__global__ void k_prep_w1(const float* __restrict__ W1, unsigned short* __restrict__ W1T, int total) {
    int t = blockIdx.x * blockDim.x + threadIdx.x;
    if (t >= total) return;
    int k = t % FS, n = (t / FS) % HS, l = t / (FS * HS);
    W1T[t] = (n < HID && k < EMB) ? f2bf(W1[l * (EMB * HID) + k * HID + n]) : 0;
}

__global__ void k_prep_w2(const float* __restrict__ W2, unsigned short* __restrict__ W2T, int total) {
    int t = blockIdx.x * blockDim.x + threadIdx.x;
    if (t >= total) return;
    int k = t % HS, n = (t / HS) % W2ROWS, l = t / (HS * W2ROWS);
    W2T[t] = (n < EMB && k < HID) ? f2bf(W2[l * (HID * EMB) + k * EMB + n]) : 0;
}

__global__ void k_prep_params(const float* __restrict__ b1, const float* __restrict__ b2,
                              const float* __restrict__ g, const float* __restrict__ be,
                              const float* __restrict__ mu, const float* __restrict__ va,
                              float* __restrict__ b1p, float* __restrict__ scp,
                              float* __restrict__ shp, int total) {
    int t = blockIdx.x * blockDim.x + threadIdx.x;
    if (t >= total) return;
    int n = t % HS, l = t / HS;
    b1p[t] = (n < HID) ? b1[l * HID + n] : 0.f;
    if (n < FS) {
        float sc = 0.f, sh = 0.f;
        if (n < EMB) {
            sc = g[l * EMB + n] * rsqrtf(va[l * EMB + n] + BN_EPS);
            sh = be[l * EMB + n] + (b2[l * EMB + n] - mu[l * EMB + n]) * sc;
        }
        scp[l * FS + n] = sc;
        shp[l * FS + n] = sh;
    }
}

// ---------------- aggregation: 8 nodes/wave, batched CSR via lane loads + shfl ----------------
// lane l owns cols [4l,4l+4) (<256); lanes 0..10 additionally own cols [256+4l,..) (<300)
__global__ __launch_bounds__(256)
void k_aggregate(const unsigned short* __restrict__ fb,  // [M_pad][FS] bf16
                 const float* __restrict__ e0,           // [6][EMB]
                 const float* __restrict__ e1,           // [3][EMB]
                 const int* __restrict__ roff, const int* __restrict__ srcs,
                 const int* __restrict__ cnt9,           // [N][9]
                 unsigned short* __restrict__ agg,       // [M_pad][FS] bf16
                 int n) {
    const int v0 = (blockIdx.x * 4 + (threadIdx.x >> 6)) * NPW;
    if (v0 >= n) return;
    const int lane = threadIdx.x & 63;
    const int nv = min(NPW, n - v0);

    // batched row offsets for 8 nodes (9 values, lane-parallel)
    int rv = 0;
    {
        int idx = v0 + lane;
        if (lane <= NPW && idx <= n) rv = roff[idx];
    }
    const int base = __shfl(rv, 0);
    const int total = __shfl(rv, nv) - base;

    // batched categorical counts (72 ints, lane-parallel)
    const int n9 = n * 9;
    const int base9 = v0 * 9;
    int c0 = (base9 + lane < n9) ? cnt9[base9 + lane] : 0;
    int c1 = (lane < 8 && base9 + 64 + lane < n9) ? cnt9[base9 + 64 + lane] : 0;

    int c = 0;        // edge cursor over [0,total), uniform
    int chunk = 0;    // 64 edge indices, refilled when (c&63)==0
    auto nextIdx = [&]() -> int {
        if ((c & 63) == 0)
            chunk = (c + lane < total) ? srcs[base + c + lane] : 0;
        int r = __shfl(chunk, c & 63);
        ++c;
        return r;
    };

#pragma unroll
    for (int i = 0; i < NPW; ++i) {
        if (i < nv) {
            const int di = __shfl(rv, i + 1) - __shfl(rv, i);
            float aA[4] = {0.f, 0.f, 0.f, 0.f};
            float aB[4] = {0.f, 0.f, 0.f, 0.f};
            int k = 0;
            for (; k + 4 <= di; k += 4) {   // 4 rows in flight
                int i0 = nextIdx(), i1 = nextIdx(), i2 = nextIdx(), i3 = nextIdx();
                const us4* r0 = (const us4*)(fb + (size_t)i0 * FS);
                const us4* r1 = (const us4*)(fb + (size_t)i1 * FS);
                const us4* r2 = (const us4*)(fb + (size_t)i2 * FS);
                const us4* r3 = (const us4*)(fb + (size_t)i3 * FS);
                us4 x0 = r0[lane], x1 = r1[lane], x2 = r2[lane], x3 = r3[lane];
                us4 y0 = {}, y1 = {}, y2 = {}, y3 = {};
                if (lane < 11) { y0 = r0[64 + lane]; y1 = r1[64 + lane];
                                 y2 = r2[64 + lane]; y3 = r3[64 + lane]; }
#pragma unroll
                for (int q = 0; q < 4; ++q)
                    aA[q] += (bf2f(x0[q]) + bf2f(x1[q])) + (bf2f(x2[q]) + bf2f(x3[q]));
                if (lane < 11) {
#pragma unroll
                    for (int q = 0; q < 4; ++q)
                        aB[q] += (bf2f(y0[q]) + bf2f(y1[q])) + (bf2f(y2[q]) + bf2f(y3[q]));
                }
            }
            for (; k < di; ++k) {
                int i0 = nextIdx();
                const us4* r0 = (const us4*)(fb + (size_t)i0 * FS);
                us4 x0 = r0[lane];
#pragma unroll
                for (int q = 0; q < 4; ++q) aA[q] += bf2f(x0[q]);
                if (lane < 11) {
                    us4 y0 = r0[64 + lane];
#pragma unroll
                    for (int q = 0; q < 4; ++q) aB[q] += bf2f(y0[q]);
                }
            }
            // edge-embedding: 9 rows, shfl-broadcast counts, uniform branch
#pragma unroll
            for (int t = 0; t < 9; ++t) {
                const int pos = i * 9 + t;
                int cv = __shfl(pos < 64 ? c0 : c1, pos & 63);
                if (cv) {
                    float fc = (float)cv;
                    const float* row = (t < 6) ? (e0 + t * EMB) : (e1 + (t - 6) * EMB);
                    f32x4 ea = *(const f32x4*)(row + 4 * lane);
#pragma unroll
                    for (int q = 0; q < 4; ++q) aA[q] += fc * ea[q];
                    if (lane < 11) {
                        f32x4 eb = *(const f32x4*)(row + 256 + 4 * lane);
#pragma unroll
                        for (int q = 0; q < 4; ++q) aB[q] += fc * eb[q];
                    }
                }
            }
            us4* ar = (us4*)(agg + (size_t)(v0 + i) * FS);
            us4 h;
#pragma unroll
            for (int q = 0; q < 4; ++q) h[q] = f2bf(aA[q]);
            ar[lane] = h;
            if (lane < 11) {   // cols 300..319 of A1 never read meaningfully (W1T rows zeroed)
                us4 hb;
#pragma unroll
                for (int q = 0; q < 4; ++q) hb[q] = f2bf(aB[q]);
                ar[64 + lane] = hb;
            }
        }
    }
}

// ---------------- bf16 MFMA GEMM, 128x128 tile, BK=32, 4 waves ----------------
// 3-buffer LDS ring (48 KB -> 3 blocks/CU), counted vmcnt, raw s_barrier,
// setprio around MFMA cluster, XCD-chunked 1-D grid decode (panel L2 locality).
template <int EPI>
__global__ __launch_bounds__(256)
void k_mm(const unsigned short* __restrict__ A, int lda,
          const unsigned short* __restrict__ Bt, int ldb,
          const float* __restrict__ p0, const float* __restrict__ p1,
          unsigned short* __restrict__ Cb, int ldc, int K, int Nlim,
          int MT, int NT) {
    const int d = blockIdx.x;
    const int xcd = d & 7, slot = d >> 3;
    const int pi = slot / NT, in = slot - pi * NT;
    const int im = pi * 8 + xcd;
    if (im >= MT) return;

    __shared__ unsigned short As[3][128 * 32];
    __shared__ unsigned short Bs[3][128 * 32];
    const int tid = threadIdx.x;
    const int lane = tid & 63, wid = tid >> 6;
    const int wm = wid >> 1, wn = wid & 1;
    const size_t bm = (size_t)im * 128;
    const int bn = in * 128;
    const int lr = lane & 15, lk = lane >> 4;
    const int srow = lane >> 2;          // staging: row within 16-row chunk
    const int scol = (lane & 3) * 8;     // staging: k-element offset
    f32x4 acc[4][4] = {};                // acc[i = n-frag][j = m-frag]

    const unsigned short* gA  = A + (bm + (size_t)(wid * 16 + srow)) * lda + scol;
    const unsigned short* gA2 = A + (bm + (size_t)((wid + 4) * 16 + srow)) * lda + scol;
    const unsigned short* gB  = Bt + (size_t)(bn + wid * 16 + srow) * ldb + scol;
    const unsigned short* gB2 = Bt + (size_t)(bn + (wid + 4) * 16 + srow) * ldb + scol;

    auto STAGE = [&](int buf, int k0) {   // 4 loads per wave
        GLDS16(gA  + k0, &As[buf][(wid * 16) * 32]);
        GLDS16(gA2 + k0, &As[buf][((wid + 4) * 16) * 32]);
        GLDS16(gB  + k0, &Bs[buf][(wid * 16) * 32]);
        GLDS16(gB2 + k0, &Bs[buf][((wid + 4) * 16) * 32]);
    };

    const int nt = K >> 5;
    STAGE(0, 0);
    if (nt > 1) STAGE(1, 32);

    for (int t = 0; t < nt; ++t) {
        // complete tile t's 4 loads; keep tile t+1's 4 in flight
        if (t + 1 < nt) asm volatile("s_waitcnt vmcnt(4)" ::: "memory");
        else            asm volatile("s_waitcnt vmcnt(0)" ::: "memory");
        __builtin_amdgcn_s_barrier();
        const int cur = t % 3;
        short8 a[4], b[4];
#pragma unroll
        for (int j = 0; j < 4; ++j)
            a[j] = *(const short8*)&As[cur][(wm * 64 + j * 16 + lr) * 32 + lk * 8];
#pragma unroll
        for (int i = 0; i < 4; ++i)
            b[i] = *(const short8*)&Bs[cur][(wn * 64 + i * 16 + lr) * 32 + lk * 8];
        // overwrites buf[(t-1)%3]: its readers' ds_reads completed before barrier t
        if (t + 2 < nt) STAGE((t + 2) % 3, (t + 2) * 32);
        __builtin_amdgcn_s_setprio(1);
#pragma unroll
        for (int i = 0; i < 4; ++i)
#pragma unroll
            for (int j = 0; j < 4; ++j)
                acc[i][j] = __builtin_amdgcn_mfma_f32_16x16x32_bf16(b[i], a[j], acc[i][j], 0, 0, 0);
        __builtin_amdgcn_s_setprio(0);
    }

    const int rgrp = (lane >> 4) * 4;
#pragma unroll
    for (int i = 0; i < 4; ++i) {
        const int n0 = bn + wn * 64 + i * 16 + rgrp;   // 4 consecutive n per lane
        if (EPI != 0 && n0 >= Nlim) continue;
        const f32x4 q0 = *(const f32x4*)&p0[n0];
        f32x4 q1 = {};
        if (EPI != 0) q1 = *(const f32x4*)&p1[n0];
#pragma unroll
        for (int j = 0; j < 4; ++j) {
            const size_t m = bm + (size_t)(wm * 64 + j * 16 + lr);
            us4 h;
#pragma unroll
            for (int p = 0; p < 4; ++p) {
                float x = (EPI == 0) ? (acc[i][j][p] + q0[p]) : (acc[i][j][p] * q0[p] + q1[p]);
                if (EPI != 2) x = fmaxf(x, 0.f);
                h[p] = f2bf(x);
            }
            *(us4*)(Cb + m * ldc + n0) = h;
        }
    }
}

// ---------------- per-graph pooling: one block (4 waves) per graph ----------------
__global__ __launch_bounds__(256)
void k_pool(const unsigned short* __restrict__ feats, const int* __restrict__ gstart,
            float* __restrict__ out, int l) {
    const int g = blockIdx.x;
    const int tid = threadIdx.x;
    const int w = tid >> 6, lane = tid & 63;
    const int s = gstart[g], e = gstart[g + 1];
    float aA[4] = {0.f, 0.f, 0.f, 0.f};
    float aB[4] = {0.f, 0.f, 0.f, 0.f};
    int v = s + w;                       // waves stride by 4 rows
    for (; v + 4 < e; v += 8) {          // 2 rows in flight per wave
        const us4* r0 = (const us4*)(feats + (size_t)v * FS);
        const us4* r1 = (const us4*)(feats + (size_t)(v + 4) * FS);
        us4 x0 = r0[lane], x1 = r1[lane];
        us4 y0 = {}, y1 = {};
        if (lane < 11) { y0 = r0[64 + lane]; y1 = r1[64 + lane]; }
#pragma unroll
        for (int q = 0; q < 4; ++q) aA[q] += bf2f(x0[q]) + bf2f(x1[q]);
        if (lane < 11) {
#pragma unroll
            for (int q = 0; q < 4; ++q) aB[q] += bf2f(y0[q]) + bf2f(y1[q]);
        }
    }
    if (v < e) {
        const us4* r0 = (const us4*)(feats + (size_t)v * FS);
        us4 x0 = r0[lane];
#pragma unroll
        for (int q = 0; q < 4; ++q) aA[q] += bf2f(x0[q]);
        if (lane < 11) {
            us4 y0 = r0[64 + lane];
#pragma unroll
            for (int q = 0; q < 4; ++q) aB[q] += bf2f(y0[q]);
        }
    }
    __shared__ f32x4 smA[4][64];
    __shared__ f32x4 smB[4][16];
    f32x4 xa;
#pragma unroll
    for (int q = 0; q < 4; ++q) xa[q] = aA[q];
    smA[w][lane] = xa;
    if (lane < 16) {
        f32x4 xb;
#pragma unroll
        for (int q = 0; q < 4; ++q) xb[q] = aB[q];
        smB[w][lane] = xb;
    }
    __syncthreads();
    if (w == 0) {
        f32x4 t = smA[0][lane] + smA[1][lane] + smA[2][lane] + smA[3][lane];
        float inv = 1.0f / fmaxf((float)(e - s), 1.0f);
        float* oavg = out + (size_t)g * (12 * EMB) + l * EMB;
        float* osum = oavg + 6 * EMB;
        *(f32x4*)(oavg + 4 * lane) = t * inv;
        *(f32x4*)(osum + 4 * lane) = t;
        if (lane < 11) {
            f32x4 tb = smB[0][lane] + smB[1][lane] + smB[2][lane] + smB[3][lane];
            *(f32x4*)(oavg + 256 + 4 * lane) = tb * inv;
            *(f32x4*)(osum + 256 + 4 * lane) = tb;
        }
    }
}

extern "C" void kernel_launch(void* const* d_in, const int* in_sizes, int n_in,
                              void* d_out, int out_size, void* d_ws, size_t ws_size,
                              hipStream_t stream) {
    const int*   an  = (const int*)d_in[0];
    const int*   ch  = (const int*)d_in[1];
    const int*   bt  = (const int*)d_in[2];
    const int*   bd  = (const int*)d_in[3];
    const int*   src = (const int*)d_in[4];
    const int*   dst = (const int*)d_in[5];
    const int*   gid = (const int*)d_in[6];
    const float* ne0 = (const float*)d_in[8];
    const float* ne1 = (const float*)d_in[9];
    const float* ee0 = (const float*)d_in[10];
    const float* ee1 = (const float*)d_in[11];
    const float* W1  = (const float*)d_in[12];
    const float* b1  = (const float*)d_in[13];
    const float* W2  = (const float*)d_in[14];
    const float* b2  = (const float*)d_in[15];
    const float* bng = (const float*)d_in[16];
    const float* bnb = (const float*)d_in[17];
    const float* bnm = (const float*)d_in[18];
    const float* bnv = (const float*)d_in[19];

    const int N = in_sizes[0];
    const int E = in_sizes[2];
    const int G = out_size / (12 * EMB);
    const int M_pad = ((N + 127) / 128) * 128;
    const int MT = M_pad / 128;
    const int MT8 = ((MT + 7) / 8) * 8;     // panels padded to multiple of 8
    const int nb = (N + 1023) / 1024;

    char* ws = (char*)d_ws;
    size_t off = 0;
    auto alloc = [&](size_t bytes) -> void* {
        void* p = (void*)(ws + off);
        off += (bytes + 255) & ~(size_t)255;
        return p;
    };
    unsigned short* Fb0  = (unsigned short*)alloc((size_t)M_pad * FS * 2);  // bf16 feats ping
    unsigned short* Fb1  = (unsigned short*)alloc((size_t)M_pad * FS * 2);  // bf16 feats pong
    unsigned short* A1   = (unsigned short*)alloc((size_t)M_pad * FS * 2);  // agg (GEMM1 A)
    unsigned short* Hb   = (unsigned short*)alloc((size_t)M_pad * HS * 2);  // hidden (GEMM2 A)
    unsigned short* W1T  = (unsigned short*)alloc((size_t)NL * HS * FS * 2);
    unsigned short* W2T  = (unsigned short*)alloc((size_t)NL * W2ROWS * HS * 2);
    float*          b1p  = (float*)alloc((size_t)NL * HS * 4);
    float*          scp  = (float*)alloc((size_t)NL * FS * 4);
    float*          shp  = (float*)alloc((size_t)NL * FS * 4);
    int*            deg  = (int*)alloc((size_t)N * 4);
    int*            roff = (int*)alloc(((size_t)N + 1) * 4);
    int*            curs = (int*)alloc((size_t)N * 4);
    int*            srcs = (int*)alloc((size_t)E * 4);
    int*            cnt9 = (int*)alloc((size_t)N * 9 * 4);
    int*            incl = (int*)alloc((size_t)N * 4);
    int*            part = (int*)alloc((size_t)1024 * 4);
    int*            gst  = (int*)alloc(((size_t)G + 1) * 4);

    // weight / param prep
    {
        int t1 = NL * HS * FS;
        k_prep_w1<<<(t1 + 255) / 256, 256, 0, stream>>>(W1, W1T, t1);
        int t2 = NL * W2ROWS * HS;
        k_prep_w2<<<(t2 + 255) / 256, 256, 0, stream>>>(W2, W2T, t2);
        int t3 = NL * HS;
        k_prep_params<<<(t3 + 255) / 256, 256, 0, stream>>>(b1, b2, bng, bnb, bnm, bnv,
                                                            b1p, scp, shp, t3);
    }

    // h0 (bf16)
    {
        int tt = N * (FS / 4);
        k_init_h0<<<(tt + 255) / 256, 256, 0, stream>>>(an, ch, ne0, ne1, Fb0, N);
    }

    // CSR by dst + categorical counts (hierarchical scan) + graph bounds
    hipMemsetAsync(deg, 0, (size_t)N * 4, stream);
    hipMemsetAsync(cnt9, 0, (size_t)N * 9 * 4, stream);
    k_hist<<<(E + 255) / 256, 256, 0, stream>>>(dst, bt, bd, deg, cnt9, E);
    k_scan_blk<<<nb, 256, 0, stream>>>(deg, incl, part, N);
    k_scan_part<<<1, 1024, 0, stream>>>(part, nb);
    k_scan_add<<<(N + 255) / 256, 256, 0, stream>>>(incl, part, deg, roff, curs, N);
    k_scatter<<<(E + 255) / 256, 256, 0, stream>>>(dst, src, curs, srcs, E);
    k_gbound<<<(N + 255) / 256, 256, 0, stream>>>(gid, gst, N, G);

    const int NT1 = HS / 128;       // 5
    const int NT2 = W2ROWS / 128;   // 3
    const int aggBlocks = (N + 4 * NPW - 1) / (4 * NPW);

    unsigned short* Fbc = Fb0;
    unsigned short* Fbo = Fb1;
    for (int l = 0; l < NL; ++l) {
        k_pool<<<G, 256, 0, stream>>>(Fbc, gst, (float*)d_out, l);
        k_aggregate<<<aggBlocks, 256, 0, stream>>>(Fbc,
                                                   ee0 + (size_t)l * 6 * EMB,
                                                   ee1 + (size_t)l * 3 * EMB,
                                                   roff, srcs, cnt9, A1, N);
        k_mm<0><<<MT8 * NT1, 256, 0, stream>>>(A1, FS, W1T + (size_t)l * HS * FS, FS,
                                               b1p + (size_t)l * HS, nullptr, Hb, HS,
                                               FS, HS, MT, NT1);
        if (l < NL - 1)
            k_mm<1><<<MT8 * NT2, 256, 0, stream>>>(Hb, HS, W2T + (size_t)l * W2ROWS * HS, HS,
                                                   scp + (size_t)l * FS, shp + (size_t)l * FS,
                                                   Fbo, FS, HS, FS, MT, NT2);
        else
            k_mm<2><<<MT8 * NT2, 256, 0, stream>>>(Hb, HS, W2T + (size_t)l * W2ROWS * HS, HS,
                                                   scp + (size_t)l * FS, shp + (size_t)l * FS,
                                                   Fbo, FS, HS, FS, MT, NT2);
        unsigned short* t = Fbc; Fbc = Fbo; Fbo = t;
    }
    k_pool<<<G, 256, 0, stream>>>(Fbc, gst, (float*)d_out, NL);
}

// Round 8
// 760.785 us; speedup vs baseline: 4.5297x; 1.0088x over previous
//
#include <hip/hip_runtime.h>

#define EMB 300
#define HID 600
#define NL 5
#define BN_EPS 1e-5f

#define FS 320          // padded feature stride (300 -> 320)
#define HS 640          // padded hidden stride (600 -> 640)
#define W2ROWS 384      // padded n-rows for W2T (3 tiles of 128)
#define NPW 8           // nodes per wave in k_aggregate

typedef __attribute__((ext_vector_type(8))) short short8;
typedef __attribute__((ext_vector_type(4))) float f32x4;
typedef __attribute__((ext_vector_type(4))) unsigned short us4;

__device__ __forceinline__ unsigned short f2bf(float x) {
    unsigned u = __float_as_uint(x);
    unsigned r = (u + 0x7FFFu + ((u >> 16) & 1u)) >> 16;   // RNE
    return (unsigned short)r;
}
__device__ __forceinline__ float bf2f(unsigned short h) {
    return __uint_as_float(((unsigned)h) << 16);
}

#define GLDS16(gsrc, ldst)                                                     \
    __builtin_amdgcn_global_load_lds(                                          \
        (const __attribute__((address_space(1))) unsigned int*)(gsrc),         \
        (__attribute__((address_space(3))) unsigned int*)(ldst), 16, 0, 0)

// ---------------- h0 = node_emb0[an] + node_emb1[ch] -> bf16, stride FS ----------------
__global__ void k_init_h0(const int* __restrict__ an, const int* __restrict__ ch,
                          const float* __restrict__ ne0, const float* __restrict__ ne1,
                          unsigned short* __restrict__ Fb, int n) {
    int t = blockIdx.x * blockDim.x + threadIdx.x;
    int i = t / (FS / 4), f4 = t - i * (FS / 4);
    if (i >= n) return;
    int f = f4 * 4;
    us4 h = {0, 0, 0, 0};
    if (f < EMB) {  // EMB=300 is a multiple of 4; rows are 16B-aligned
        const float4 a = *(const float4*)(ne0 + (size_t)an[i] * EMB + f);
        const float4 b = *(const float4*)(ne1 + (size_t)ch[i] * EMB + f);
        h[0] = f2bf(a.x + b.x); h[1] = f2bf(a.y + b.y);
        h[2] = f2bf(a.z + b.z); h[3] = f2bf(a.w + b.w);
    }
    *(us4*)(Fb + (size_t)i * FS + f) = h;
}

// ---------------- CSR build (by dst) + per-node categorical counts [N][9] ----------------
__global__ void k_hist(const int* __restrict__ dst, const int* __restrict__ bt,
                       const int* __restrict__ bd, int* __restrict__ deg,
                       int* __restrict__ cnt9, int e) {
    int t = blockIdx.x * blockDim.x + threadIdx.x;
    if (t >= e) return;
    int d = dst[t];
    atomicAdd(&deg[d], 1);
    atomicAdd(&cnt9[d * 9 + bt[t]], 1);
    atomicAdd(&cnt9[d * 9 + 6 + bd[t]], 1);
}

// ---- hierarchical scan: pass A (per-1024 block inclusive scan + block totals) ----
__global__ __launch_bounds__(256)
void k_scan_blk(const int* __restrict__ deg, int* __restrict__ incl,
                int* __restrict__ part, int n) {
    int tid = threadIdx.x;
    int base = blockIdx.x * 1024 + tid * 4;
    int v0 = (base + 0 < n) ? deg[base + 0] : 0;
    int v1 = (base + 1 < n) ? deg[base + 1] : 0;
    int v2 = (base + 2 < n) ? deg[base + 2] : 0;
    int v3 = (base + 3 < n) ? deg[base + 3] : 0;
    int ts = v0 + v1 + v2 + v3;
    int lane = tid & 63, w = tid >> 6;
    int x = ts;
#pragma unroll
    for (int off = 1; off < 64; off <<= 1) {
        int y = __shfl_up(x, off);
        if (lane >= off) x += y;
    }
    __shared__ int ws[4];
    if (lane == 63) ws[w] = x;
    __syncthreads();
    int woff = 0;
    for (int i = 0; i < w; ++i) woff += ws[i];
    int r = woff + x - ts;  // exclusive prefix for this thread
    r += v0; if (base + 0 < n) incl[base + 0] = r;
    r += v1; if (base + 1 < n) incl[base + 1] = r;
    r += v2; if (base + 2 < n) incl[base + 2] = r;
    r += v3; if (base + 3 < n) incl[base + 3] = r;
    if (tid == 255) part[blockIdx.x] = woff + x;  // block total
}

// ---- pass B: exclusive scan of block totals (single block, nb <= 1024) ----
__global__ __launch_bounds__(1024)
void k_scan_part(int* __restrict__ part, int nb) {
    int tid = threadIdx.x;
    int v = (tid < nb) ? part[tid] : 0;
    int lane = tid & 63, w = tid >> 6;
    int x = v;
#pragma unroll
    for (int off = 1; off < 64; off <<= 1) {
        int y = __shfl_up(x, off);
        if (lane >= off) x += y;
    }
    __shared__ int ws[16];
    if (lane == 63) ws[w] = x;
    __syncthreads();
    int woff = 0;
    for (int i = 0; i < w; ++i) woff += ws[i];
    if (tid < nb) part[tid] = woff + x - v;  // exclusive
}

// ---- pass C: row_off[i+1] = incl[i]+part; cursor[i] = row_off[i] ----
__global__ void k_scan_add(const int* __restrict__ incl, const int* __restrict__ part,
                           const int* __restrict__ deg, int* __restrict__ roff,
                           int* __restrict__ curs, int n) {
    int i = blockIdx.x * blockDim.x + threadIdx.x;
    if (i >= n) return;
    int inc = incl[i] + part[i >> 10];
    roff[i + 1] = inc;
    curs[i] = inc - deg[i];
    if (i == 0) roff[0] = 0;
}

__global__ void k_scatter(const int* __restrict__ dst, const int* __restrict__ src,
                          int* __restrict__ cursor, int* __restrict__ srcs, int e) {
    int t = blockIdx.x * blockDim.x + threadIdx.x;
    if (t < e) { int p = atomicAdd(&cursor[dst[t]], 1); srcs[p] = src[t]; }
}

// ---- graph boundaries: gstart[g] = first node index with gids >= g; gstart[G] = n ----
__global__ void k_gbound(const int* __restrict__ gids, int* __restrict__ gstart,
                         int n, int G) {
    int i = blockIdx.x * blockDim.x + threadIdx.x;
    if (i >= n) return;
    int g = gids[i];
    int gp = (i == 0) ? -1 : gids[i - 1];
    for (int q = gp + 1; q <= g; ++q) gstart[q] = i;
    if (i == n - 1)
        for (int q = g + 1; q <= G; ++q) gstart[q] = n;
}

// ---------------- weight prep: transpose + pad + bf16 ----------------
__global__ void k_prep_w1(const float* __restrict__ W1, unsigned short* __restrict__ W1T, int total) {
    int t = blockIdx.x * blockDim.x + threadIdx.x;
    if (t >= total) return;
    int k = t % FS, n = (t / FS) % HS, l = t / (FS * HS);
    W1T[t] = (n < HID && k < EMB) ? f2bf(W1[l * (EMB * HID) + k * HID + n]) : 0;
}

__global__ void k_prep_w2(const float* __restrict__ W2, unsigned short* __restrict__ W2T, int total) {
    int t = blockIdx.x * blockDim.x + threadIdx.x;
    if (t >= total) return;
    int k = t % HS, n = (t / HS) % W2ROWS, l = t / (HS * W2ROWS);
    W2T[t] = (n < EMB && k < HID) ? f2bf(W2[l * (HID * EMB) + k * EMB + n]) : 0;
}

__global__ void k_prep_params(const float* __restrict__ b1, const float* __restrict__ b2,
                              const float* __restrict__ g, const float* __restrict__ be,
                              const float* __restrict__ mu, const float* __restrict__ va,
                              float* __restrict__ b1p, float* __restrict__ scp,
                              float* __restrict__ shp, int total) {
    int t = blockIdx.x * blockDim.x + threadIdx.x;
    if (t >= total) return;
    int n = t % HS, l = t / HS;
    b1p[t] = (n < HID) ? b1[l * HID + n] : 0.f;
    if (n < FS) {
        float sc = 0.f, sh = 0.f;
        if (n < EMB) {
            sc = g[l * EMB + n] * rsqrtf(va[l * EMB + n] + BN_EPS);
            sh = be[l * EMB + n] + (b2[l * EMB + n] - mu[l * EMB + n]) * sc;
        }
        scp[l * FS + n] = sc;
        shp[l * FS + n] = sh;
    }
}

// ---------------- aggregation: 8 nodes/wave, batched CSR via lane loads + shfl ----------------
// lane l owns cols [4l,4l+4) (<256); lanes 0..10 additionally own cols [256+4l,..) (<300)
__global__ __launch_bounds__(256)
void k_aggregate(const unsigned short* __restrict__ fb,  // [M_pad][FS] bf16
                 const float* __restrict__ e0,           // [6][EMB]
                 const float* __restrict__ e1,           // [3][EMB]
                 const int* __restrict__ roff, const int* __restrict__ srcs,
                 const int* __restrict__ cnt9,           // [N][9]
                 unsigned short* __restrict__ agg,       // [M_pad][FS] bf16
                 int n) {
    const int v0 = (blockIdx.x * 4 + (threadIdx.x >> 6)) * NPW;
    if (v0 >= n) return;
    const int lane = threadIdx.x & 63;
    const int nv = min(NPW, n - v0);

    // batched row offsets for 8 nodes (9 values, lane-parallel)
    int rv = 0;
    {
        int idx = v0 + lane;
        if (lane <= NPW && idx <= n) rv = roff[idx];
    }
    const int base = __shfl(rv, 0);
    const int total = __shfl(rv, nv) - base;

    // batched categorical counts (72 ints, lane-parallel)
    const int n9 = n * 9;
    const int base9 = v0 * 9;
    int c0 = (base9 + lane < n9) ? cnt9[base9 + lane] : 0;
    int c1 = (lane < 8 && base9 + 64 + lane < n9) ? cnt9[base9 + 64 + lane] : 0;

    int c = 0;        // edge cursor over [0,total), uniform
    int chunk = 0;    // 64 edge indices, refilled when (c&63)==0
    auto nextIdx = [&]() -> int {
        if ((c & 63) == 0)
            chunk = (c + lane < total) ? srcs[base + c + lane] : 0;
        int r = __shfl(chunk, c & 63);
        ++c;
        return r;
    };

#pragma unroll
    for (int i = 0; i < NPW; ++i) {
        if (i < nv) {
            const int di = __shfl(rv, i + 1) - __shfl(rv, i);
            float aA[4] = {0.f, 0.f, 0.f, 0.f};
            float aB[4] = {0.f, 0.f, 0.f, 0.f};
            int k = 0;
            for (; k + 4 <= di; k += 4) {   // 4 rows in flight
                int i0 = nextIdx(), i1 = nextIdx(), i2 = nextIdx(), i3 = nextIdx();
                const us4* r0 = (const us4*)(fb + (size_t)i0 * FS);
                const us4* r1 = (const us4*)(fb + (size_t)i1 * FS);
                const us4* r2 = (const us4*)(fb + (size_t)i2 * FS);
                const us4* r3 = (const us4*)(fb + (size_t)i3 * FS);
                us4 x0 = r0[lane], x1 = r1[lane], x2 = r2[lane], x3 = r3[lane];
                us4 y0 = {}, y1 = {}, y2 = {}, y3 = {};
                if (lane < 11) { y0 = r0[64 + lane]; y1 = r1[64 + lane];
                                 y2 = r2[64 + lane]; y3 = r3[64 + lane]; }
#pragma unroll
                for (int q = 0; q < 4; ++q)
                    aA[q] += (bf2f(x0[q]) + bf2f(x1[q])) + (bf2f(x2[q]) + bf2f(x3[q]));
                if (lane < 11) {
#pragma unroll
                    for (int q = 0; q < 4; ++q)
                        aB[q] += (bf2f(y0[q]) + bf2f(y1[q])) + (bf2f(y2[q]) + bf2f(y3[q]));
                }
            }
            for (; k < di; ++k) {
                int i0 = nextIdx();
                const us4* r0 = (const us4*)(fb + (size_t)i0 * FS);
                us4 x0 = r0[lane];
#pragma unroll
                for (int q = 0; q < 4; ++q) aA[q] += bf2f(x0[q]);
                if (lane < 11) {
                    us4 y0 = r0[64 + lane];
#pragma unroll
                    for (int q = 0; q < 4; ++q) aB[q] += bf2f(y0[q]);
                }
            }
            // edge-embedding: 9 rows, shfl-broadcast counts, uniform branch
#pragma unroll
            for (int t = 0; t < 9; ++t) {
                const int pos = i * 9 + t;
                int cv = __shfl(pos < 64 ? c0 : c1, pos & 63);
                if (cv) {
                    float fc = (float)cv;
                    const float* row = (t < 6) ? (e0 + t * EMB) : (e1 + (t - 6) * EMB);
                    f32x4 ea = *(const f32x4*)(row + 4 * lane);
#pragma unroll
                    for (int q = 0; q < 4; ++q) aA[q] += fc * ea[q];
                    if (lane < 11) {
                        f32x4 eb = *(const f32x4*)(row + 256 + 4 * lane);
#pragma unroll
                        for (int q = 0; q < 4; ++q) aB[q] += fc * eb[q];
                    }
                }
            }
            us4* ar = (us4*)(agg + (size_t)(v0 + i) * FS);
            us4 h;
#pragma unroll
            for (int q = 0; q < 4; ++q) h[q] = f2bf(aA[q]);
            ar[lane] = h;
            if (lane < 11) {   // cols 300..319 of A1 never read meaningfully (W1T rows zeroed)
                us4 hb;
#pragma unroll
                for (int q = 0; q < 4; ++q) hb[q] = f2bf(aB[q]);
                ar[64 + lane] = hb;
            }
        }
    }
}

// ---------------- bf16 MFMA GEMM, 256x128 tile, BK=32, 8 waves (512 thr) ----------------
// 3-buffer LDS ring (72 KB -> 2 blocks/CU = 16 waves/CU), counted vmcnt(3),
// raw s_barrier, setprio around MFMA cluster, XCD-chunked 1-D grid decode.
// Staging: 3 x 1KB global_load_lds per wave per K-step (2 A-chunks + 1 B-chunk).
template <int EPI>
__global__ __launch_bounds__(512)
void k_mm(const unsigned short* __restrict__ A, int lda,
          const unsigned short* __restrict__ Bt, int ldb,
          const float* __restrict__ p0, const float* __restrict__ p1,
          unsigned short* __restrict__ Cb, int ldc, int K, int Nlim,
          int MT, int NT) {
    const int d = blockIdx.x;
    const int xcd = d & 7, slot = d >> 3;
    const int pi = slot / NT, in = slot - pi * NT;
    const int im = pi * 8 + xcd;
    if (im >= MT) return;

    __shared__ unsigned short As[3][256 * 32];
    __shared__ unsigned short Bs[3][128 * 32];
    const int tid = threadIdx.x;
    const int lane = tid & 63, wid = tid >> 6;       // 8 waves
    const int wm = wid >> 1, wn = wid & 1;           // 4 x 2 wave grid (64x64 out each)
    const size_t bm = (size_t)im * 256;
    const int bn = in * 128;
    const int lr = lane & 15, lk = lane >> 4;
    const int srow = lane >> 2;          // staging: row within 16-row chunk
    const int scol = (lane & 3) * 8;     // staging: k-element offset
    f32x4 acc[4][4] = {};                // acc[i = n-frag][j = m-frag]

    const unsigned short* gA  = A + (bm + (size_t)(wid * 16 + srow)) * lda + scol;
    const unsigned short* gA2 = A + (bm + (size_t)((wid + 8) * 16 + srow)) * lda + scol;
    const unsigned short* gB  = Bt + (size_t)(bn + wid * 16 + srow) * ldb + scol;

    auto STAGE = [&](int buf, int k0) {   // 3 loads per wave (16KB A + 8KB B per block)
        GLDS16(gA  + k0, &As[buf][(wid * 16) * 32]);
        GLDS16(gA2 + k0, &As[buf][((wid + 8) * 16) * 32]);
        GLDS16(gB  + k0, &Bs[buf][(wid * 16) * 32]);
    };

    const int nt = K >> 5;
    STAGE(0, 0);
    if (nt > 1) STAGE(1, 32);

    for (int t = 0; t < nt; ++t) {
        // complete tile t's 3 loads; keep tile t+1's 3 in flight
        if (t + 1 < nt) asm volatile("s_waitcnt vmcnt(3)" ::: "memory");
        else            asm volatile("s_waitcnt vmcnt(0)" ::: "memory");
        __builtin_amdgcn_s_barrier();
        const int cur = t % 3;
        short8 a[4], b[4];
#pragma unroll
        for (int j = 0; j < 4; ++j)
            a[j] = *(const short8*)&As[cur][(wm * 64 + j * 16 + lr) * 32 + lk * 8];
#pragma unroll
        for (int i = 0; i < 4; ++i)
            b[i] = *(const short8*)&Bs[cur][(wn * 64 + i * 16 + lr) * 32 + lk * 8];
        // overwrites buf[(t-1)%3]: its readers' ds_reads completed before barrier t
        if (t + 2 < nt) STAGE((t + 2) % 3, (t + 2) * 32);
        __builtin_amdgcn_s_setprio(1);
#pragma unroll
        for (int i = 0; i < 4; ++i)
#pragma unroll
            for (int j = 0; j < 4; ++j)
                acc[i][j] = __builtin_amdgcn_mfma_f32_16x16x32_bf16(b[i], a[j], acc[i][j], 0, 0, 0);
        __builtin_amdgcn_s_setprio(0);
    }

    const int rgrp = (lane >> 4) * 4;
#pragma unroll
    for (int i = 0; i < 4; ++i) {
        const int n0 = bn + wn * 64 + i * 16 + rgrp;   // 4 consecutive n per lane
        if (EPI != 0 && n0 >= Nlim) continue;
        const f32x4 q0 = *(const f32x4*)&p0[n0];
        f32x4 q1 = {};
        if (EPI != 0) q1 = *(const f32x4*)&p1[n0];
#pragma unroll
        for (int j = 0; j < 4; ++j) {
            const size_t m = bm + (size_t)(wm * 64 + j * 16 + lr);
            us4 h;
#pragma unroll
            for (int p = 0; p < 4; ++p) {
                float x = (EPI == 0) ? (acc[i][j][p] + q0[p]) : (acc[i][j][p] * q0[p] + q1[p]);
                if (EPI != 2) x = fmaxf(x, 0.f);
                h[p] = f2bf(x);
            }
            *(us4*)(Cb + m * ldc + n0) = h;
        }
    }
}

// ---------------- per-graph pooling: one block (4 waves) per graph ----------------
__global__ __launch_bounds__(256)
void k_pool(const unsigned short* __restrict__ feats, const int* __restrict__ gstart,
            float* __restrict__ out, int l) {
    const int g = blockIdx.x;
    const int tid = threadIdx.x;
    const int w = tid >> 6, lane = tid & 63;
    const int s = gstart[g], e = gstart[g + 1];
    float aA[4] = {0.f, 0.f, 0.f, 0.f};
    float aB[4] = {0.f, 0.f, 0.f, 0.f};
    int v = s + w;                       // waves stride by 4 rows
    for (; v + 4 < e; v += 8) {          // 2 rows in flight per wave
        const us4* r0 = (const us4*)(feats + (size_t)v * FS);
        const us4* r1 = (const us4*)(feats + (size_t)(v + 4) * FS);
        us4 x0 = r0[lane], x1 = r1[lane];
        us4 y0 = {}, y1 = {};
        if (lane < 11) { y0 = r0[64 + lane]; y1 = r1[64 + lane]; }
#pragma unroll
        for (int q = 0; q < 4; ++q) aA[q] += bf2f(x0[q]) + bf2f(x1[q]);
        if (lane < 11) {
#pragma unroll
            for (int q = 0; q < 4; ++q) aB[q] += bf2f(y0[q]) + bf2f(y1[q]);
        }
    }
    if (v < e) {
        const us4* r0 = (const us4*)(feats + (size_t)v * FS);
        us4 x0 = r0[lane];
#pragma unroll
        for (int q = 0; q < 4; ++q) aA[q] += bf2f(x0[q]);
        if (lane < 11) {
            us4 y0 = r0[64 + lane];
#pragma unroll
            for (int q = 0; q < 4; ++q) aB[q] += bf2f(y0[q]);
        }
    }
    __shared__ f32x4 smA[4][64];
    __shared__ f32x4 smB[4][16];
    f32x4 xa;
#pragma unroll
    for (int q = 0; q < 4; ++q) xa[q] = aA[q];
    smA[w][lane] = xa;
    if (lane < 16) {
        f32x4 xb;
#pragma unroll
        for (int q = 0; q < 4; ++q) xb[q] = aB[q];
        smB[w][lane] = xb;
    }
    __syncthreads();
    if (w == 0) {
        f32x4 t = smA[0][lane] + smA[1][lane] + smA[2][lane] + smA[3][lane];
        float inv = 1.0f / fmaxf((float)(e - s), 1.0f);
        float* oavg = out + (size_t)g * (12 * EMB) + l * EMB;
        float* osum = oavg + 6 * EMB;
        *(f32x4*)(oavg + 4 * lane) = t * inv;
        *(f32x4*)(osum + 4 * lane) = t;
        if (lane < 11) {
            f32x4 tb = smB[0][lane] + smB[1][lane] + smB[2][lane] + smB[3][lane];
            *(f32x4*)(oavg + 256 + 4 * lane) = tb * inv;
            *(f32x4*)(osum + 256 + 4 * lane) = tb;
        }
    }
}

extern "C" void kernel_launch(void* const* d_in, const int* in_sizes, int n_in,
                              void* d_out, int out_size, void* d_ws, size_t ws_size,
                              hipStream_t stream) {
    const int*   an  = (const int*)d_in[0];
    const int*   ch  = (const int*)d_in[1];
    const int*   bt  = (const int*)d_in[2];
    const int*   bd  = (const int*)d_in[3];
    const int*   src = (const int*)d_in[4];
    const int*   dst = (const int*)d_in[5];
    const int*   gid = (const int*)d_in[6];
    const float* ne0 = (const float*)d_in[8];
    const float* ne1 = (const float*)d_in[9];
    const float* ee0 = (const float*)d_in[10];
    const float* ee1 = (const float*)d_in[11];
    const float* W1  = (const float*)d_in[12];
    const float* b1  = (const float*)d_in[13];
    const float* W2  = (const float*)d_in[14];
    const float* b2  = (const float*)d_in[15];
    const float* bng = (const float*)d_in[16];
    const float* bnb = (const float*)d_in[17];
    const float* bnm = (const float*)d_in[18];
    const float* bnv = (const float*)d_in[19];

    const int N = in_sizes[0];
    const int E = in_sizes[2];
    const int G = out_size / (12 * EMB);
    const int M_pad = ((N + 255) / 256) * 256;
    const int MT = M_pad / 256;
    const int MT8 = ((MT + 7) / 8) * 8;     // panels padded to multiple of 8
    const int nb = (N + 1023) / 1024;

    char* ws = (char*)d_ws;
    size_t off = 0;
    auto alloc = [&](size_t bytes) -> void* {
        void* p = (void*)(ws + off);
        off += (bytes + 255) & ~(size_t)255;
        return p;
    };
    unsigned short* Fb0  = (unsigned short*)alloc((size_t)M_pad * FS * 2);  // bf16 feats ping
    unsigned short* Fb1  = (unsigned short*)alloc((size_t)M_pad * FS * 2);  // bf16 feats pong
    unsigned short* A1   = (unsigned short*)alloc((size_t)M_pad * FS * 2);  // agg (GEMM1 A)
    unsigned short* Hb   = (unsigned short*)alloc((size_t)M_pad * HS * 2);  // hidden (GEMM2 A)
    unsigned short* W1T  = (unsigned short*)alloc((size_t)NL * HS * FS * 2);
    unsigned short* W2T  = (unsigned short*)alloc((size_t)NL * W2ROWS * HS * 2);
    float*          b1p  = (float*)alloc((size_t)NL * HS * 4);
    float*          scp  = (float*)alloc((size_t)NL * FS * 4);
    float*          shp  = (float*)alloc((size_t)NL * FS * 4);
    int*            deg  = (int*)alloc((size_t)N * 4);
    int*            roff = (int*)alloc(((size_t)N + 1) * 4);
    int*            curs = (int*)alloc((size_t)N * 4);
    int*            srcs = (int*)alloc((size_t)E * 4);
    int*            cnt9 = (int*)alloc((size_t)N * 9 * 4);
    int*            incl = (int*)alloc((size_t)N * 4);
    int*            part = (int*)alloc((size_t)1024 * 4);
    int*            gst  = (int*)alloc(((size_t)G + 1) * 4);

    // weight / param prep
    {
        int t1 = NL * HS * FS;
        k_prep_w1<<<(t1 + 255) / 256, 256, 0, stream>>>(W1, W1T, t1);
        int t2 = NL * W2ROWS * HS;
        k_prep_w2<<<(t2 + 255) / 256, 256, 0, stream>>>(W2, W2T, t2);
        int t3 = NL * HS;
        k_prep_params<<<(t3 + 255) / 256, 256, 0, stream>>>(b1, b2, bng, bnb, bnm, bnv,
                                                            b1p, scp, shp, t3);
    }

    // h0 (bf16)
    {
        int tt = N * (FS / 4);
        k_init_h0<<<(tt + 255) / 256, 256, 0, stream>>>(an, ch, ne0, ne1, Fb0, N);
    }

    // CSR by dst + categorical counts (hierarchical scan) + graph bounds
    hipMemsetAsync(deg, 0, (size_t)N * 4, stream);
    hipMemsetAsync(cnt9, 0, (size_t)N * 9 * 4, stream);
    k_hist<<<(E + 255) / 256, 256, 0, stream>>>(dst, bt, bd, deg, cnt9, E);
    k_scan_blk<<<nb, 256, 0, stream>>>(deg, incl, part, N);
    k_scan_part<<<1, 1024, 0, stream>>>(part, nb);
    k_scan_add<<<(N + 255) / 256, 256, 0, stream>>>(incl, part, deg, roff, curs, N);
    k_scatter<<<(E + 255) / 256, 256, 0, stream>>>(dst, src, curs, srcs, E);
    k_gbound<<<(N + 255) / 256, 256, 0, stream>>>(gid, gst, N, G);

    const int NT1 = HS / 128;       // 5
    const int NT2 = W2ROWS / 128;   // 3
    const int aggBlocks = (N + 4 * NPW - 1) / (4 * NPW);

    unsigned short* Fbc = Fb0;
    unsigned short* Fbo = Fb1;
    for (int l = 0; l < NL; ++l) {
        k_pool<<<G, 256, 0, stream>>>(Fbc, gst, (float*)d_out, l);
        k_aggregate<<<aggBlocks, 256, 0, stream>>>(Fbc,
                                                   ee0 + (size_t)l * 6 * EMB,
                                                   ee1 + (size_t)l * 3 * EMB,
                                                   roff, srcs, cnt9, A1, N);
        k_mm<0><<<MT8 * NT1, 512, 0, stream>>>(A1, FS, W1T + (size_t)l * HS * FS, FS,
                                               b1p + (size_t)l * HS, nullptr, Hb, HS,
                                               FS, HS, MT, NT1);
        if (l < NL - 1)
            k_mm<1><<<MT8 * NT2, 512, 0, stream>>>(Hb, HS, W2T + (size_t)l * W2ROWS * HS, HS,
                                                   scp + (size_t)l * FS, shp + (size_t)l * FS,
                                                   Fbo, FS, HS, FS, MT, NT2);
        else
            k_mm<2><<<MT8 * NT2, 512, 0, stream>>>(Hb, HS, W2T + (size_t)l * W2ROWS * HS, HS,
                                                   scp + (size_t)l * FS, shp + (size_t)l * FS,
                                                   Fbo, FS, HS, FS, MT, NT2);
        unsigned short* t = Fbc; Fbc = Fbo; Fbo = t;
    }
    k_pool<<<G, 256, 0, stream>>>(Fbc, gst, (float*)d_out, NL);
}

// Round 9
// 755.301 us; speedup vs baseline: 4.5626x; 1.0073x over previous
//
#include <hip/hip_runtime.h>

#define EMB 300
#define HID 600
#define NL 5
#define BN_EPS 1e-5f

#define FS 320          // padded feature stride (300 -> 320); row = 640 B
#define HS 640          // padded hidden stride (600 -> 640); row = 1280 B
#define NPW 8           // nodes per wave in k_aggregate
#define KS1 10          // GEMM1 K-steps (320/32)
#define KS2 20          // GEMM2 K-steps (640/32)

typedef __attribute__((ext_vector_type(8))) short short8;
typedef __attribute__((ext_vector_type(4))) float f32x4;
typedef __attribute__((ext_vector_type(4))) unsigned short us4;

__device__ __forceinline__ unsigned short f2bf(float x) {
    unsigned u = __float_as_uint(x);
    unsigned r = (u + 0x7FFFu + ((u >> 16) & 1u)) >> 16;   // RNE
    return (unsigned short)r;
}
__device__ __forceinline__ float bf2f(unsigned short h) {
    return __uint_as_float(((unsigned)h) << 16);
}

#define GLDS16(gsrc, ldst)                                                     \
    __builtin_amdgcn_global_load_lds(                                          \
        (const __attribute__((address_space(1))) unsigned int*)(gsrc),         \
        (__attribute__((address_space(3))) unsigned int*)(ldst), 16, 0, 0)

// ---------------- h0 = node_emb0[an] + node_emb1[ch] -> bf16, stride FS ----------------
__global__ void k_init_h0(const int* __restrict__ an, const int* __restrict__ ch,
                          const float* __restrict__ ne0, const float* __restrict__ ne1,
                          unsigned short* __restrict__ Fb, int n) {
    int t = blockIdx.x * blockDim.x + threadIdx.x;
    int i = t / (FS / 4), f4 = t - i * (FS / 4);
    if (i >= n) return;
    int f = f4 * 4;
    us4 h = {0, 0, 0, 0};
    if (f < EMB) {  // EMB=300 is a multiple of 4; rows are 16B-aligned
        const float4 a = *(const float4*)(ne0 + (size_t)an[i] * EMB + f);
        const float4 b = *(const float4*)(ne1 + (size_t)ch[i] * EMB + f);
        h[0] = f2bf(a.x + b.x); h[1] = f2bf(a.y + b.y);
        h[2] = f2bf(a.z + b.z); h[3] = f2bf(a.w + b.w);
    }
    *(us4*)(Fb + (size_t)i * FS + f) = h;
}

// ---------------- CSR build (by dst) + per-node categorical counts [N][9] ----------------
__global__ void k_hist(const int* __restrict__ dst, const int* __restrict__ bt,
                       const int* __restrict__ bd, int* __restrict__ deg,
                       int* __restrict__ cnt9, int e) {
    int t = blockIdx.x * blockDim.x + threadIdx.x;
    if (t >= e) return;
    int d = dst[t];
    atomicAdd(&deg[d], 1);
    atomicAdd(&cnt9[d * 9 + bt[t]], 1);
    atomicAdd(&cnt9[d * 9 + 6 + bd[t]], 1);
}

// ---- hierarchical scan: pass A ----
__global__ __launch_bounds__(256)
void k_scan_blk(const int* __restrict__ deg, int* __restrict__ incl,
                int* __restrict__ part, int n) {
    int tid = threadIdx.x;
    int base = blockIdx.x * 1024 + tid * 4;
    int v0 = (base + 0 < n) ? deg[base + 0] : 0;
    int v1 = (base + 1 < n) ? deg[base + 1] : 0;
    int v2 = (base + 2 < n) ? deg[base + 2] : 0;
    int v3 = (base + 3 < n) ? deg[base + 3] : 0;
    int ts = v0 + v1 + v2 + v3;
    int lane = tid & 63, w = tid >> 6;
    int x = ts;
#pragma unroll
    for (int off = 1; off < 64; off <<= 1) {
        int y = __shfl_up(x, off);
        if (lane >= off) x += y;
    }
    __shared__ int ws[4];
    if (lane == 63) ws[w] = x;
    __syncthreads();
    int woff = 0;
    for (int i = 0; i < w; ++i) woff += ws[i];
    int r = woff + x - ts;
    r += v0; if (base + 0 < n) incl[base + 0] = r;
    r += v1; if (base + 1 < n) incl[base + 1] = r;
    r += v2; if (base + 2 < n) incl[base + 2] = r;
    r += v3; if (base + 3 < n) incl[base + 3] = r;
    if (tid == 255) part[blockIdx.x] = woff + x;
}

// ---- pass B ----
__global__ __launch_bounds__(1024)
void k_scan_part(int* __restrict__ part, int nb) {
    int tid = threadIdx.x;
    int v = (tid < nb) ? part[tid] : 0;
    int lane = tid & 63, w = tid >> 6;
    int x = v;
#pragma unroll
    for (int off = 1; off < 64; off <<= 1) {
        int y = __shfl_up(x, off);
        if (lane >= off) x += y;
    }
    __shared__ int ws[16];
    if (lane == 63) ws[w] = x;
    __syncthreads();
    int woff = 0;
    for (int i = 0; i < w; ++i) woff += ws[i];
    if (tid < nb) part[tid] = woff + x - v;
}

// ---- pass C ----
__global__ void k_scan_add(const int* __restrict__ incl, const int* __restrict__ part,
                           const int* __restrict__ deg, int* __restrict__ roff,
                           int* __restrict__ curs, int n) {
    int i = blockIdx.x * blockDim.x + threadIdx.x;
    if (i >= n) return;
    int inc = incl[i] + part[i >> 10];
    roff[i + 1] = inc;
    curs[i] = inc - deg[i];
    if (i == 0) roff[0] = 0;
}

__global__ void k_scatter(const int* __restrict__ dst, const int* __restrict__ src,
                          int* __restrict__ cursor, int* __restrict__ srcs, int e) {
    int t = blockIdx.x * blockDim.x + threadIdx.x;
    if (t < e) { int p = atomicAdd(&cursor[dst[t]], 1); srcs[p] = src[t]; }
}

// ---- graph boundaries ----
__global__ void k_gbound(const int* __restrict__ gids, int* __restrict__ gstart,
                         int n, int G) {
    int i = blockIdx.x * blockDim.x + threadIdx.x;
    if (i >= n) return;
    int g = gids[i];
    int gp = (i == 0) ? -1 : gids[i - 1];
    for (int q = gp + 1; q <= g; ++q) gstart[q] = i;
    if (i == n - 1)
        for (int q = g + 1; q <= G; ++q) gstart[q] = n;
}

// ---------------- weight prep: MFMA-fragment-packed bf16 weights ----------------
// W1P[l][nf=0..39][ks=0..KS1-1][lane][8]: frag elem = W1[l][ks*32+(lane>>4)*8+e][nf*16+(lane&15)]
__global__ void k_prep_w1p(const float* __restrict__ W1, unsigned short* __restrict__ W1P,
                           int total) {
    int t = blockIdx.x * blockDim.x + threadIdx.x;
    if (t >= total) return;
    int lane = t & 63;
    int r = t >> 6;
    int ks = r % KS1; r /= KS1;
    int nf = r % 40;
    int l = r / 40;
    int n = nf * 16 + (lane & 15);
    int kb = ks * 32 + (lane >> 4) * 8;
    unsigned short v[8];
#pragma unroll
    for (int e = 0; e < 8; ++e) {
        int k = kb + e;
        v[e] = (n < HID && k < EMB) ? f2bf(W1[(size_t)l * EMB * HID + (size_t)k * HID + n]) : 0;
    }
    *(short8*)(W1P + (size_t)t * 8) = *(short8*)v;
}

// W2P[l][nf=0..19][ks=0..KS2-1][lane][8]: frag elem = W2[l][ks*32+(lane>>4)*8+e][nf*16+(lane&15)]
__global__ void k_prep_w2p(const float* __restrict__ W2, unsigned short* __restrict__ W2P,
                           int total) {
    int t = blockIdx.x * blockDim.x + threadIdx.x;
    if (t >= total) return;
    int lane = t & 63;
    int r = t >> 6;
    int ks = r % KS2; r /= KS2;
    int nf = r % 20;
    int l = r / 20;
    int n = nf * 16 + (lane & 15);
    int kb = ks * 32 + (lane >> 4) * 8;
    unsigned short v[8];
#pragma unroll
    for (int e = 0; e < 8; ++e) {
        int k = kb + e;
        v[e] = (n < EMB && k < HID) ? f2bf(W2[(size_t)l * HID * EMB + (size_t)k * EMB + n]) : 0;
    }
    *(short8*)(W2P + (size_t)t * 8) = *(short8*)v;
}

__global__ void k_prep_params(const float* __restrict__ b1, const float* __restrict__ b2,
                              const float* __restrict__ g, const float* __restrict__ be,
                              const float* __restrict__ mu, const float* __restrict__ va,
                              float* __restrict__ b1p, float* __restrict__ scp,
                              float* __restrict__ shp, int total) {
    int t = blockIdx.x * blockDim.x + threadIdx.x;
    if (t >= total) return;
    int n = t % HS, l = t / HS;
    b1p[t] = (n < HID) ? b1[l * HID + n] : 0.f;
    if (n < FS) {
        float sc = 0.f, sh = 0.f;
        if (n < EMB) {
            sc = g[l * EMB + n] * rsqrtf(va[l * EMB + n] + BN_EPS);
            sh = be[l * EMB + n] + (b2[l * EMB + n] - mu[l * EMB + n]) * sc;
        }
        scp[l * FS + n] = sc;
        shp[l * FS + n] = sh;
    }
}

// ---------------- aggregation: 8 nodes/wave, batched CSR via lane loads + shfl ----------------
__global__ __launch_bounds__(256)
void k_aggregate(const unsigned short* __restrict__ fb,
                 const float* __restrict__ e0, const float* __restrict__ e1,
                 const int* __restrict__ roff, const int* __restrict__ srcs,
                 const int* __restrict__ cnt9,
                 unsigned short* __restrict__ agg, int n) {
    const int v0 = (blockIdx.x * 4 + (threadIdx.x >> 6)) * NPW;
    if (v0 >= n) return;
    const int lane = threadIdx.x & 63;
    const int nv = min(NPW, n - v0);

    int rv = 0;
    {
        int idx = v0 + lane;
        if (lane <= NPW && idx <= n) rv = roff[idx];
    }
    const int base = __shfl(rv, 0);
    const int total = __shfl(rv, nv) - base;

    const int n9 = n * 9;
    const int base9 = v0 * 9;
    int c0 = (base9 + lane < n9) ? cnt9[base9 + lane] : 0;
    int c1 = (lane < 8 && base9 + 64 + lane < n9) ? cnt9[base9 + 64 + lane] : 0;

    int c = 0;
    int chunk = 0;
    auto nextIdx = [&]() -> int {
        if ((c & 63) == 0)
            chunk = (c + lane < total) ? srcs[base + c + lane] : 0;
        int r = __shfl(chunk, c & 63);
        ++c;
        return r;
    };

#pragma unroll
    for (int i = 0; i < NPW; ++i) {
        if (i < nv) {
            const int di = __shfl(rv, i + 1) - __shfl(rv, i);
            float aA[4] = {0.f, 0.f, 0.f, 0.f};
            float aB[4] = {0.f, 0.f, 0.f, 0.f};
            int k = 0;
            for (; k + 4 <= di; k += 4) {
                int i0 = nextIdx(), i1 = nextIdx(), i2 = nextIdx(), i3 = nextIdx();
                const us4* r0 = (const us4*)(fb + (size_t)i0 * FS);
                const us4* r1 = (const us4*)(fb + (size_t)i1 * FS);
                const us4* r2 = (const us4*)(fb + (size_t)i2 * FS);
                const us4* r3 = (const us4*)(fb + (size_t)i3 * FS);
                us4 x0 = r0[lane], x1 = r1[lane], x2 = r2[lane], x3 = r3[lane];
                us4 y0 = {}, y1 = {}, y2 = {}, y3 = {};
                if (lane < 11) { y0 = r0[64 + lane]; y1 = r1[64 + lane];
                                 y2 = r2[64 + lane]; y3 = r3[64 + lane]; }
#pragma unroll
                for (int q = 0; q < 4; ++q)
                    aA[q] += (bf2f(x0[q]) + bf2f(x1[q])) + (bf2f(x2[q]) + bf2f(x3[q]));
                if (lane < 11) {
#pragma unroll
                    for (int q = 0; q < 4; ++q)
                        aB[q] += (bf2f(y0[q]) + bf2f(y1[q])) + (bf2f(y2[q]) + bf2f(y3[q]));
                }
            }
            for (; k < di; ++k) {
                int i0 = nextIdx();
                const us4* r0 = (const us4*)(fb + (size_t)i0 * FS);
                us4 x0 = r0[lane];
#pragma unroll
                for (int q = 0; q < 4; ++q) aA[q] += bf2f(x0[q]);
                if (lane < 11) {
                    us4 y0 = r0[64 + lane];
#pragma unroll
                    for (int q = 0; q < 4; ++q) aB[q] += bf2f(y0[q]);
                }
            }
#pragma unroll
            for (int t = 0; t < 9; ++t) {
                const int pos = i * 9 + t;
                int cv = __shfl(pos < 64 ? c0 : c1, pos & 63);
                if (cv) {
                    float fc = (float)cv;
                    const float* row = (t < 6) ? (e0 + t * EMB) : (e1 + (t - 6) * EMB);
                    f32x4 ea = *(const f32x4*)(row + 4 * lane);
#pragma unroll
                    for (int q = 0; q < 4; ++q) aA[q] += fc * ea[q];
                    if (lane < 11) {
                        f32x4 eb = *(const f32x4*)(row + 256 + 4 * lane);
#pragma unroll
                        for (int q = 0; q < 4; ++q) aB[q] += fc * eb[q];
                    }
                }
            }
            us4* ar = (us4*)(agg + (size_t)(v0 + i) * FS);
            us4 h;
#pragma unroll
            for (int q = 0; q < 4; ++q) h[q] = f2bf(aA[q]);
            ar[lane] = h;
            if (lane < 11) {
                us4 hb;
#pragma unroll
                for (int q = 0; q < 4; ++q) hb[q] = f2bf(aB[q]);
                ar[64 + lane] = hb;
            }
        }
    }
}

// ---------------- fused MLP: H = relu(A W1 + b1); F' = BN(H W2 + b2) [+relu] ----------------
// One block per 64-row strip; 512 threads (8 waves). A-strip in XOR-swizzled LDS
// (loaded once via pre-swizzled-source global_load_lds); H in XOR-swizzled LDS;
// weight fragments streamed L2->VGPR from pre-packed W1P/W2P with 1-step prefetch.
// No barriers in K-loops. Swizzle: byte ^= ((row&7)<<4) -> frag reads ~conflict-free.
// EPI 1: BN + relu; EPI 2: BN only (last layer).
template <int EPI>
__global__ __launch_bounds__(512)
void k_mlp(const unsigned short* __restrict__ A,     // [M_pad][FS] bf16 (row = 640 B)
           const unsigned short* __restrict__ W1P,   // [40][KS1][64][8]
           const unsigned short* __restrict__ W2P,   // [20][KS2][64][8]
           const float* __restrict__ b1p,            // [HS]
           const float* __restrict__ scp, const float* __restrict__ shp,  // [FS]
           unsigned short* __restrict__ Cout) {      // [M_pad][FS] bf16
    __shared__ unsigned short Ash[64 * 320];   // 40 KB, swizzled
    __shared__ unsigned short Hsh[64 * 640];   // 80 KB, swizzled
    const int tid = threadIdx.x;
    const int lane = tid & 63, wid = tid >> 6;
    const int lr = lane & 15, lk = lane >> 4, rgrp = lk * 4;
    const size_t m0s = (size_t)blockIdx.x * 64;

    // ---- load A strip (contiguous 40960 B in global: row stride FS*2 = 640 B) ----
    // LDS linear dest; source pre-swizzled so LDS holds the swizzled layout.
#pragma unroll
    for (int cch = 0; cch < 5; ++cch) {
        const int sbase = wid * 5120 + cch * 1024;
        const int s = sbase + lane * 16;
        const int row = s / 640;
        const int u = s ^ ((row & 7) << 4);   // involution within the row
        GLDS16((const char*)A + m0s * 640 + u, (char*)Ash + sbase);
    }
    asm volatile("s_waitcnt vmcnt(0)" ::: "memory");
    __syncthreads();

    // ---- GEMM1: H[64][640] = relu(A[64][320] x W1 + b1); wave wid owns cols [wid*80, +80) ----
    {
        f32x4 acc1[5][4] = {};
        short8 bw[5], bn_[5];
#pragma unroll
        for (int i = 0; i < 5; ++i)
            bw[i] = *(const short8*)(W1P + (((size_t)(wid * 5 + i) * KS1 + 0) * 64 + lane) * 8);
        for (int ks = 0; ks < KS1; ++ks) {
            if (ks + 1 < KS1) {
#pragma unroll
                for (int i = 0; i < 5; ++i)
                    bn_[i] = *(const short8*)(W1P + (((size_t)(wid * 5 + i) * KS1 + ks + 1) * 64 + lane) * 8);
            }
            short8 a[4];
#pragma unroll
            for (int j = 0; j < 4; ++j) {
                const int row = j * 16 + lr;
                const int o = (row * 640 + ks * 64 + lk * 16) ^ ((lr & 7) << 4);
                a[j] = *(const short8*)((const char*)Ash + o);
            }
#pragma unroll
            for (int i = 0; i < 5; ++i)
#pragma unroll
                for (int j = 0; j < 4; ++j)
                    acc1[i][j] = __builtin_amdgcn_mfma_f32_16x16x32_bf16(bw[i], a[j], acc1[i][j], 0, 0, 0);
#pragma unroll
            for (int i = 0; i < 5; ++i) bw[i] = bn_[i];
        }
        // epilogue 1 -> Hsh (swizzled)
#pragma unroll
        for (int i = 0; i < 5; ++i) {
            const int n0 = wid * 80 + i * 16 + rgrp;
            const f32x4 q0 = *(const f32x4*)&b1p[n0];
#pragma unroll
            for (int j = 0; j < 4; ++j) {
                const int m = j * 16 + lr;
                us4 h;
#pragma unroll
                for (int p = 0; p < 4; ++p)
                    h[p] = f2bf(fmaxf(acc1[i][j][p] + q0[p], 0.f));
                const int o = (m * 1280 + n0 * 2) ^ ((lr & 7) << 4);
                *(us4*)((char*)Hsh + o) = h;
            }
        }
    }
    __syncthreads();

    // ---- GEMM2: F'[64][320] = BN(H[64][640] x W2) ; wave (wm2, wn2) = (wid>>2, wid&3) ----
    {
        const int wm2 = wid >> 2, wn2 = wid & 3;   // 2 x 4: 32 rows x 80 cols per wave
        f32x4 acc2[5][2] = {};
        short8 cw[5], cn_[5];
#pragma unroll
        for (int i = 0; i < 5; ++i)
            cw[i] = *(const short8*)(W2P + (((size_t)(wn2 * 5 + i) * KS2 + 0) * 64 + lane) * 8);
        for (int ks = 0; ks < KS2; ++ks) {
            if (ks + 1 < KS2) {
#pragma unroll
                for (int i = 0; i < 5; ++i)
                    cn_[i] = *(const short8*)(W2P + (((size_t)(wn2 * 5 + i) * KS2 + ks + 1) * 64 + lane) * 8);
            }
            short8 a[2];
#pragma unroll
            for (int j = 0; j < 2; ++j) {
                const int row = wm2 * 32 + j * 16 + lr;
                const int o = (row * 1280 + ks * 64 + lk * 16) ^ ((lr & 7) << 4);
                a[j] = *(const short8*)((const char*)Hsh + o);
            }
#pragma unroll
            for (int i = 0; i < 5; ++i)
#pragma unroll
                for (int j = 0; j < 2; ++j)
                    acc2[i][j] = __builtin_amdgcn_mfma_f32_16x16x32_bf16(cw[i], a[j], acc2[i][j], 0, 0, 0);
#pragma unroll
            for (int i = 0; i < 5; ++i) cw[i] = cn_[i];
        }
        // epilogue 2 -> global
#pragma unroll
        for (int i = 0; i < 5; ++i) {
            const int n0 = wn2 * 80 + i * 16 + rgrp;    // < 320
            const f32x4 q0 = *(const f32x4*)&scp[n0];
            const f32x4 q1 = *(const f32x4*)&shp[n0];
#pragma unroll
            for (int j = 0; j < 2; ++j) {
                const size_t m = m0s + (size_t)(wm2 * 32 + j * 16 + lr);
                us4 h;
#pragma unroll
                for (int p = 0; p < 4; ++p) {
                    float x = acc2[i][j][p] * q0[p] + q1[p];
                    if (EPI == 1) x = fmaxf(x, 0.f);
                    h[p] = f2bf(x);
                }
                *(us4*)(Cout + m * FS + n0) = h;
            }
        }
    }
}

// ---------------- per-graph pooling: one block (4 waves) per graph ----------------
__global__ __launch_bounds__(256)
void k_pool(const unsigned short* __restrict__ feats, const int* __restrict__ gstart,
            float* __restrict__ out, int l) {
    const int g = blockIdx.x;
    const int tid = threadIdx.x;
    const int w = tid >> 6, lane = tid & 63;
    const int s = gstart[g], e = gstart[g + 1];
    float aA[4] = {0.f, 0.f, 0.f, 0.f};
    float aB[4] = {0.f, 0.f, 0.f, 0.f};
    int v = s + w;
    for (; v + 4 < e; v += 8) {
        const us4* r0 = (const us4*)(feats + (size_t)v * FS);
        const us4* r1 = (const us4*)(feats + (size_t)(v + 4) * FS);
        us4 x0 = r0[lane], x1 = r1[lane];
        us4 y0 = {}, y1 = {};
        if (lane < 11) { y0 = r0[64 + lane]; y1 = r1[64 + lane]; }
#pragma unroll
        for (int q = 0; q < 4; ++q) aA[q] += bf2f(x0[q]) + bf2f(x1[q]);
        if (lane < 11) {
#pragma unroll
            for (int q = 0; q < 4; ++q) aB[q] += bf2f(y0[q]) + bf2f(y1[q]);
        }
    }
    if (v < e) {
        const us4* r0 = (const us4*)(feats + (size_t)v * FS);
        us4 x0 = r0[lane];
#pragma unroll
        for (int q = 0; q < 4; ++q) aA[q] += bf2f(x0[q]);
        if (lane < 11) {
            us4 y0 = r0[64 + lane];
#pragma unroll
            for (int q = 0; q < 4; ++q) aB[q] += bf2f(y0[q]);
        }
    }
    __shared__ f32x4 smA[4][64];
    __shared__ f32x4 smB[4][16];
    f32x4 xa;
#pragma unroll
    for (int q = 0; q < 4; ++q) xa[q] = aA[q];
    smA[w][lane] = xa;
    if (lane < 16) {
        f32x4 xb;
#pragma unroll
        for (int q = 0; q < 4; ++q) xb[q] = aB[q];
        smB[w][lane] = xb;
    }
    __syncthreads();
    if (w == 0) {
        f32x4 t = smA[0][lane] + smA[1][lane] + smA[2][lane] + smA[3][lane];
        float inv = 1.0f / fmaxf((float)(e - s), 1.0f);
        float* oavg = out + (size_t)g * (12 * EMB) + l * EMB;
        float* osum = oavg + 6 * EMB;
        *(f32x4*)(oavg + 4 * lane) = t * inv;
        *(f32x4*)(osum + 4 * lane) = t;
        if (lane < 11) {
            f32x4 tb = smB[0][lane] + smB[1][lane] + smB[2][lane] + smB[3][lane];
            *(f32x4*)(oavg + 256 + 4 * lane) = tb * inv;
            *(f32x4*)(osum + 256 + 4 * lane) = tb;
        }
    }
}

extern "C" void kernel_launch(void* const* d_in, const int* in_sizes, int n_in,
                              void* d_out, int out_size, void* d_ws, size_t ws_size,
                              hipStream_t stream) {
    const int*   an  = (const int*)d_in[0];
    const int*   ch  = (const int*)d_in[1];
    const int*   bt  = (const int*)d_in[2];
    const int*   bd  = (const int*)d_in[3];
    const int*   src = (const int*)d_in[4];
    const int*   dst = (const int*)d_in[5];
    const int*   gid = (const int*)d_in[6];
    const float* ne0 = (const float*)d_in[8];
    const float* ne1 = (const float*)d_in[9];
    const float* ee0 = (const float*)d_in[10];
    const float* ee1 = (const float*)d_in[11];
    const float* W1  = (const float*)d_in[12];
    const float* b1  = (const float*)d_in[13];
    const float* W2  = (const float*)d_in[14];
    const float* b2  = (const float*)d_in[15];
    const float* bng = (const float*)d_in[16];
    const float* bnb = (const float*)d_in[17];
    const float* bnm = (const float*)d_in[18];
    const float* bnv = (const float*)d_in[19];

    const int N = in_sizes[0];
    const int E = in_sizes[2];
    const int G = out_size / (12 * EMB);
    const int M_pad = ((N + 63) / 64) * 64;
    const int MT = M_pad / 64;
    const int nb = (N + 1023) / 1024;

    char* ws = (char*)d_ws;
    size_t off = 0;
    auto alloc = [&](size_t bytes) -> void* {
        void* p = (void*)(ws + off);
        off += (bytes + 255) & ~(size_t)255;
        return p;
    };
    unsigned short* Fb0  = (unsigned short*)alloc((size_t)M_pad * FS * 2);  // bf16 feats ping
    unsigned short* Fb1  = (unsigned short*)alloc((size_t)M_pad * FS * 2);  // bf16 feats pong
    unsigned short* A1   = (unsigned short*)alloc((size_t)M_pad * FS * 2);  // agg (MLP input)
    unsigned short* W1P  = (unsigned short*)alloc((size_t)NL * 40 * KS1 * 64 * 8 * 2);
    unsigned short* W2P  = (unsigned short*)alloc((size_t)NL * 20 * KS2 * 64 * 8 * 2);
    float*          b1p  = (float*)alloc((size_t)NL * HS * 4);
    float*          scp  = (float*)alloc((size_t)NL * FS * 4);
    float*          shp  = (float*)alloc((size_t)NL * FS * 4);
    int*            deg  = (int*)alloc((size_t)N * 4);
    int*            roff = (int*)alloc(((size_t)N + 1) * 4);
    int*            curs = (int*)alloc((size_t)N * 4);
    int*            srcs = (int*)alloc((size_t)E * 4);
    int*            cnt9 = (int*)alloc((size_t)N * 9 * 4);
    int*            incl = (int*)alloc((size_t)N * 4);
    int*            part = (int*)alloc((size_t)1024 * 4);
    int*            gst  = (int*)alloc(((size_t)G + 1) * 4);

    // weight / param prep (fragment-packed)
    {
        int t1 = NL * 40 * KS1 * 64;
        k_prep_w1p<<<(t1 + 255) / 256, 256, 0, stream>>>(W1, W1P, t1);
        int t2 = NL * 20 * KS2 * 64;
        k_prep_w2p<<<(t2 + 255) / 256, 256, 0, stream>>>(W2, W2P, t2);
        int t3 = NL * HS;
        k_prep_params<<<(t3 + 255) / 256, 256, 0, stream>>>(b1, b2, bng, bnb, bnm, bnv,
                                                            b1p, scp, shp, t3);
    }

    // h0 (bf16)
    {
        int tt = N * (FS / 4);
        k_init_h0<<<(tt + 255) / 256, 256, 0, stream>>>(an, ch, ne0, ne1, Fb0, N);
    }

    // CSR by dst + categorical counts (hierarchical scan) + graph bounds
    hipMemsetAsync(deg, 0, (size_t)N * 4, stream);
    hipMemsetAsync(cnt9, 0, (size_t)N * 9 * 4, stream);
    k_hist<<<(E + 255) / 256, 256, 0, stream>>>(dst, bt, bd, deg, cnt9, E);
    k_scan_blk<<<nb, 256, 0, stream>>>(deg, incl, part, N);
    k_scan_part<<<1, 1024, 0, stream>>>(part, nb);
    k_scan_add<<<(N + 255) / 256, 256, 0, stream>>>(incl, part, deg, roff, curs, N);
    k_scatter<<<(E + 255) / 256, 256, 0, stream>>>(dst, src, curs, srcs, E);
    k_gbound<<<(N + 255) / 256, 256, 0, stream>>>(gid, gst, N, G);

    const int aggBlocks = (N + 4 * NPW - 1) / (4 * NPW);

    unsigned short* Fbc = Fb0;
    unsigned short* Fbo = Fb1;
    for (int l = 0; l < NL; ++l) {
        k_pool<<<G, 256, 0, stream>>>(Fbc, gst, (float*)d_out, l);
        k_aggregate<<<aggBlocks, 256, 0, stream>>>(Fbc,
                                                   ee0 + (size_t)l * 6 * EMB,
                                                   ee1 + (size_t)l * 3 * EMB,
                                                   roff, srcs, cnt9, A1, N);
        const unsigned short* W1Pl = W1P + (size_t)l * 40 * KS1 * 64 * 8;
        const unsigned short* W2Pl = W2P + (size_t)l * 20 * KS2 * 64 * 8;
        if (l < NL - 1)
            k_mlp<1><<<MT, 512, 0, stream>>>(A1, W1Pl, W2Pl,
                                             b1p + (size_t)l * HS,
                                             scp + (size_t)l * FS, shp + (size_t)l * FS,
                                             Fbo);
        else
            k_mlp<2><<<MT, 512, 0, stream>>>(A1, W1Pl, W2Pl,
                                             b1p + (size_t)l * HS,
                                             scp + (size_t)l * FS, shp + (size_t)l * FS,
                                             Fbo);
        unsigned short* t = Fbc; Fbc = Fbo; Fbo = t;
    }
    k_pool<<<G, 256, 0, stream>>>(Fbc, gst, (float*)d_out, NL);
}